// Round 9
// baseline (800.991 us; speedup 1.0000x reference)
//
#include <hip/hip_runtime.h>

#define DEV __device__ __forceinline__
DEV float relu_(float x) { return fmaxf(x, 0.0f); }

typedef __attribute__((ext_vector_type(4))) float f32x4;
typedef __attribute__((ext_vector_type(8))) __bf16 bf16x8;

// branchless EXACT top-5 insert: strict-< bubble (keeps 5 smallest, sorted)
DEV void knn_insert_bl(float (&bd)[5], int (&bi)[5], float d, int j) {
#pragma unroll
  for (int p = 0; p < 5; ++p) {
    bool lt = d < bd[p];
    float nd = lt ? d : bd[p];
    float cd = lt ? bd[p] : d;
    int ni = lt ? j : bi[p];
    int ci = lt ? bi[p] : j;
    bd[p] = nd; d = cd;
    bi[p] = ni; j = ci;
  }
}

// ---------------- Kernel 1: kNN on pos (F=3), 8-way candidate split ----------------
// grid 2048 (32 b x 64 query-chunks of 32), block 256 = 32 queries x 8 cand-subranges
__global__ __launch_bounds__(256) void k_knn1(const float* __restrict__ pos,
                                              int* __restrict__ idx1) {
  __shared__ float ps[6144];
  __shared__ float sqs[2048];
  __shared__ float md[640];
  __shared__ int mi[640];
  int tid = threadIdx.x;
  int b = blockIdx.x >> 6, qc = blockIdx.x & 63;
  const float* src = pos + b * 6144;
  for (int u = tid; u < 6144; u += 256) ps[u] = src[u];
  __syncthreads();
  for (int u = tid; u < 2048; u += 256) {
    float x = ps[u * 3], y = ps[u * 3 + 1], z = ps[u * 3 + 2];
    sqs[u] = fmaf(z, z, fmaf(y, y, x * x));
  }
  __syncthreads();
  int q = tid & 31, sub = tid >> 5;
  int qi = qc * 32 + q;
  float qx = ps[qi * 3], qy = ps[qi * 3 + 1], qz = ps[qi * 3 + 2];
  float qsq = sqs[qi];
  float bd[5] = {1e30f, 1e30f, 1e30f, 1e30f, 1e30f};
  int bi[5] = {0, 0, 0, 0, 0};
  int j0 = sub * 256;
  for (int j = j0; j < j0 + 256; ++j) {
    float px = ps[j * 3], py = ps[j * 3 + 1], pz = ps[j * 3 + 2];
    float dot = fmaf(qz, pz, fmaf(qy, py, qx * px));
    float d = (qsq + sqs[j]) - 2.0f * dot;
    knn_insert_bl(bd, bi, d, j);
  }
  // tree-merge 8 partial lists -> 1
  for (int half = 4; half >= 1; half >>= 1) {
    __syncthreads();
    if (sub >= half && sub < 2 * half) {
      int slot = (q * 4 + (sub - half)) * 5;
#pragma unroll
      for (int k = 0; k < 5; ++k) { md[slot + k] = bd[k]; mi[slot + k] = bi[k]; }
    }
    __syncthreads();
    if (sub < half) {
      int slot = (q * 4 + sub) * 5;
#pragma unroll
      for (int k = 0; k < 5; ++k) knn_insert_bl(bd, bi, md[slot + k], mi[slot + k]);
    }
  }
  if (sub == 0) {
    int* op = idx1 + (b * 2048 + qi) * 5;
#pragma unroll
    for (int k = 0; k < 5; ++k) op[k] = bi[k];
  }
}

// ---------------- Kernel 1b: per-point u/v for EdgeConv1 layer-1 ----------------
__global__ __launch_bounds__(256) void k_uv(const float* __restrict__ pos,
                                            const float* __restrict__ w1a,
                                            const float* __restrict__ b1a,
                                            float* __restrict__ ut,
                                            float* __restrict__ v) {
  __shared__ float wAs[384];
  __shared__ float bs[64];
  int tid = threadIdx.x;
  for (int u = tid; u < 384; u += 256) wAs[u] = w1a[u];
  if (tid < 64) bs[tid] = b1a[tid];
  __syncthreads();
  int lane = tid & 63, fq = tid >> 6;
  int p = blockIdx.x * 64 + lane;
  int b = p >> 11, nloc = p & 2047;
  float x0 = pos[p * 3], x1 = pos[p * 3 + 1], x2 = pos[p * 3 + 2];
  float uu[16], vv[16];
#pragma unroll
  for (int m = 0; m < 16; ++m) {
    int f = fq * 16 + m;
    float wt0 = wAs[f], wt1 = wAs[64 + f], wt2 = wAs[128 + f];
    float wb0 = wAs[192 + f], wb1 = wAs[256 + f], wb2 = wAs[320 + f];
    float uval = bs[f];
    uval = fmaf(x0, wt0 - wb0, uval);
    uval = fmaf(x1, wt1 - wb1, uval);
    uval = fmaf(x2, wt2 - wb2, uval);
    uu[m] = uval;
    vv[m] = fmaf(x2, wb2, fmaf(x1, wb1, x0 * wb0));
  }
#pragma unroll
  for (int m = 0; m < 16; ++m)
    ut[((size_t)b * 64 + fq * 16 + m) * 2048 + nloc] = uu[m];
#pragma unroll
  for (int it = 0; it < 4; ++it)
    *(float4*)(v + (size_t)p * 64 + fq * 16 + it * 4) = *(const float4*)(vv + it * 4);
}

// ---------------- Kernel 2: EdgeConv1 layers 2/3 as 4x4-blocked GEMM ----------------
__global__ __launch_bounds__(256) void k_edge1(
    const int* __restrict__ idx1, const float* __restrict__ ut,
    const float* __restrict__ v,
    const float* __restrict__ s1a, const float* __restrict__ h1a,
    const float* __restrict__ w1b, const float* __restrict__ b1b,
    const float* __restrict__ s1b, const float* __restrict__ h1b,
    const float* __restrict__ w1c, const float* __restrict__ b1c,
    const float* __restrict__ s1c, const float* __restrict__ h1c,
    __bf16* __restrict__ xh, __bf16* __restrict__ xl,
    float* __restrict__ sqo, __bf16* __restrict__ xb) {
  __shared__ __align__(16) float h1t[64 * 68];
  __shared__ __align__(16) float h2t[64 * 68];
  __shared__ __align__(16) float wB[4096], wC[4096];
  __shared__ float cA[128], cB[192], cC[192];
  __shared__ float red[64 * 17];
  int tid = threadIdx.x;
  for (int u = tid; u < 4096; u += 256) { wB[u] = w1b[u]; wC[u] = w1c[u]; }
  if (tid < 64) {
    cA[tid] = s1a[tid]; cA[64 + tid] = h1a[tid];
    cB[tid] = b1b[tid]; cB[64 + tid] = s1b[tid]; cB[128 + tid] = h1b[tid];
    cC[tid] = b1c[tid]; cC[64 + tid] = s1c[tid]; cC[128 + tid] = h1c[tid];
  }
  int p0 = blockIdx.x * 64;
  int b = p0 >> 11, nloc0 = p0 & 2047;
  size_t bb = (size_t)b * 2048;
  int e = tid & 63, fq = tid >> 6;
  int cg = tid >> 4, pg = tid & 15;
  float amax[4][4];
#pragma unroll
  for (int i = 0; i < 4; ++i)
#pragma unroll
    for (int j = 0; j < 4; ++j) amax[i][j] = -3.4e38f;
  __syncthreads();
  for (int k = 0; k < 5; ++k) {
    {
      int j = idx1[(p0 + e) * 5 + k];
      const float* vrow = v + (bb + j) * 64 + fq * 16;
#pragma unroll
      for (int it = 0; it < 4; ++it) {
        float4 vv = *(const float4*)(vrow + it * 4);
        float vr[4] = {vv.x, vv.y, vv.z, vv.w};
#pragma unroll
        for (int m = 0; m < 4; ++m) {
          int f = fq * 16 + it * 4 + m;
          float uval = ut[((size_t)b * 64 + f) * 2048 + nloc0 + e];
          h1t[f * 68 + e] = relu_(uval + vr[m]) * cA[f] + cA[64 + f];
        }
      }
    }
    __syncthreads();
    {
      float acc[4][4] = {{0, 0, 0, 0}, {0, 0, 0, 0}, {0, 0, 0, 0}, {0, 0, 0, 0}};
#pragma unroll 4
      for (int f = 0; f < 64; ++f) {
        float4 av = *(const float4*)(h1t + f * 68 + pg * 4);
        float4 wv = *(const float4*)(wB + f * 64 + cg * 4);
        float a[4] = {av.x, av.y, av.z, av.w};
        float w[4] = {wv.x, wv.y, wv.z, wv.w};
#pragma unroll
        for (int ii = 0; ii < 4; ++ii)
#pragma unroll
          for (int jj = 0; jj < 4; ++jj)
            acc[ii][jj] = fmaf(a[ii], w[jj], acc[ii][jj]);
      }
#pragma unroll
      for (int jj = 0; jj < 4; ++jj) {
        int c = cg * 4 + jj;
        float bv = cB[c], sv = cB[64 + c], hv = cB[128 + c];
#pragma unroll
        for (int ii = 0; ii < 4; ++ii)
          h2t[c * 68 + pg * 4 + ii] = relu_(acc[ii][jj] + bv) * sv + hv;
      }
    }
    __syncthreads();
    {
      float acc[4][4] = {{0, 0, 0, 0}, {0, 0, 0, 0}, {0, 0, 0, 0}, {0, 0, 0, 0}};
#pragma unroll 4
      for (int f = 0; f < 64; ++f) {
        float4 av = *(const float4*)(h2t + f * 68 + pg * 4);
        float4 wv = *(const float4*)(wC + f * 64 + cg * 4);
        float a[4] = {av.x, av.y, av.z, av.w};
        float w[4] = {wv.x, wv.y, wv.z, wv.w};
#pragma unroll
        for (int ii = 0; ii < 4; ++ii)
#pragma unroll
          for (int jj = 0; jj < 4; ++jj)
            acc[ii][jj] = fmaf(a[ii], w[jj], acc[ii][jj]);
      }
#pragma unroll
      for (int ii = 0; ii < 4; ++ii)
#pragma unroll
        for (int jj = 0; jj < 4; ++jj)
          amax[ii][jj] = fmaxf(amax[ii][jj], acc[ii][jj]);
    }
    __syncthreads();
  }
#pragma unroll
  for (int ii = 0; ii < 4; ++ii) {
    int n = p0 + pg * 4 + ii;
    float sqp = 0.f;
    __bf16 oh[4], ol[4], ob[4];
#pragma unroll
    for (int jj = 0; jj < 4; ++jj) {
      int c = cg * 4 + jj;
      float val = relu_(amax[ii][jj] + cC[c]) * cC[64 + c] + cC[128 + c];
      sqp = fmaf(val, val, sqp);
      __bf16 h = (__bf16)val;
      oh[jj] = h;
      ol[jj] = (__bf16)(val - (float)h);
      ob[jj] = h;
    }
    *(uint2*)(xh + (size_t)n * 64 + cg * 4) = *(const uint2*)oh;
    *(uint2*)(xl + (size_t)n * 64 + cg * 4) = *(const uint2*)ol;
    *(uint2*)(xb + (size_t)n * 192 + cg * 4) = *(const uint2*)ob;
    red[(pg * 4 + ii) * 17 + cg] = sqp;
  }
  __syncthreads();
  if (tid < 64) {
    float s = 0.f;
#pragma unroll
    for (int g = 0; g < 16; ++g) s += red[tid * 17 + g];
    sqo[p0 + tid] = s;
  }
}

// ---------------- Kernel 3: kNN on x1 — MFMA hi/lo, global frags, no staging ----------------
// grid 2048 (32 b x 64 q-chunks of 32), block 256 = 4 waves:
// wave w: qg=w&1 (16-query group), ch=w>>1 (candidate half, 1024 cands each)
__global__ __launch_bounds__(256) void k_knn2(const __bf16* __restrict__ xh,
                                              const __bf16* __restrict__ xl,
                                              const float* __restrict__ sq,
                                              int* __restrict__ idx2) {
  __shared__ float sqs[2048];
  __shared__ float mdf[2560];
  __shared__ int mdi[2560];
  int tid = threadIdx.x;
  int w = tid >> 6, lane = tid & 63;
  int quad = lane >> 4, lm = lane & 15;
  int qg = w & 1, ch = w >> 1;
  int b = blockIdx.x >> 6, qc = blockIdx.x & 63;
  int q0 = qc * 32;
  size_t bb = (size_t)b * 2048;
  for (int u = tid; u < 512; u += 256)
    *(float4*)(sqs + u * 4) = *(const float4*)(sq + bb + u * 4);
  // A-frags (queries) straight from global, held in regs all tiles
  const __bf16* qh = xh + (bb + q0 + qg * 16 + lm) * 64 + quad * 8;
  const __bf16* ql = xl + (bb + q0 + qg * 16 + lm) * 64 + quad * 8;
  bf16x8 Ah0 = *(const bf16x8*)(qh);
  bf16x8 Ah1 = *(const bf16x8*)(qh + 32);
  bf16x8 Al0 = *(const bf16x8*)(ql);
  bf16x8 Al1 = *(const bf16x8*)(ql + 32);
  __syncthreads();
  float bd[4][5];
  int bi[4][5];
#pragma unroll
  for (int r = 0; r < 4; ++r)
#pragma unroll
    for (int k = 0; k < 5; ++k) { bd[r][k] = 1e30f; bi[r][k] = 0; }
  int ct0 = ch * 16;
  for (int ct = ct0; ct < ct0 + 16; ++ct) {
#pragma unroll
    for (int nt = 0; nt < 4; ++nt) {
      // B-frag (candidates) = contiguous 16B chunks of the cand row in global
      const __bf16* crh = xh + (bb + ct * 64 + nt * 16 + lm) * 64 + quad * 8;
      const __bf16* crl = xl + (bb + ct * 64 + nt * 16 + lm) * 64 + quad * 8;
      bf16x8 Bh0 = *(const bf16x8*)(crh);
      bf16x8 Bh1 = *(const bf16x8*)(crh + 32);
      bf16x8 Bl0 = *(const bf16x8*)(crl);
      bf16x8 Bl1 = *(const bf16x8*)(crl + 32);
      f32x4 acc = {0.f, 0.f, 0.f, 0.f};
      acc = __builtin_amdgcn_mfma_f32_16x16x32_bf16(Ah0, Bh0, acc, 0, 0, 0);
      acc = __builtin_amdgcn_mfma_f32_16x16x32_bf16(Ah1, Bh1, acc, 0, 0, 0);
      acc = __builtin_amdgcn_mfma_f32_16x16x32_bf16(Ah0, Bl0, acc, 0, 0, 0);
      acc = __builtin_amdgcn_mfma_f32_16x16x32_bf16(Ah1, Bl1, acc, 0, 0, 0);
      acc = __builtin_amdgcn_mfma_f32_16x16x32_bf16(Al0, Bh0, acc, 0, 0, 0);
      acc = __builtin_amdgcn_mfma_f32_16x16x32_bf16(Al1, Bh1, acc, 0, 0, 0);
      int cid = ct * 64 + nt * 16 + lm;
      float csq = sqs[cid];
#pragma unroll
      for (int r = 0; r < 4; ++r) {
        // rank by csq - 2*dot (qsq is per-query constant: selection-invariant)
        float d = fmaf(-2.0f, acc[r], csq);
        knn_insert_bl(bd[r], bi[r], d, cid);
      }
    }
  }
  // pair-merge across candidate halves via LDS (ch1 -> ch0)
  if (ch == 1) {
#pragma unroll
    for (int r = 0; r < 4; ++r)
#pragma unroll
      for (int k = 0; k < 5; ++k) {
        int slot = ((((qg * 4 + quad) * 16 + lm) * 4 + r) * 5) + k;
        mdf[slot] = bd[r][k];
        mdi[slot] = bi[r][k];
      }
  }
  __syncthreads();
  if (ch == 0) {
#pragma unroll
    for (int r = 0; r < 4; ++r)
#pragma unroll
      for (int k = 0; k < 5; ++k) {
        int slot = ((((qg * 4 + quad) * 16 + lm) * 4 + r) * 5) + k;
        knn_insert_bl(bd[r], bi[r], mdf[slot], mdi[slot]);
      }
    // butterfly over the 16 lm-partials per query row
    for (int m = 1; m <= 8; m <<= 1) {
#pragma unroll
      for (int r = 0; r < 4; ++r) {
        float od[5]; int oi[5];
#pragma unroll
        for (int k = 0; k < 5; ++k) {
          od[k] = __shfl_xor(bd[r][k], m);
          oi[k] = __shfl_xor(bi[r][k], m);
        }
#pragma unroll
        for (int k = 0; k < 5; ++k) knn_insert_bl(bd[r], bi[r], od[k], oi[k]);
      }
    }
    if (lm == 0) {
#pragma unroll
      for (int r = 0; r < 4; ++r) {
        int qi = q0 + qg * 16 + quad * 4 + r;
        int* op = idx2 + (bb + qi) * 5;
#pragma unroll
        for (int k = 0; k < 5; ++k) op[k] = bi[r][k];
      }
    }
  }
}

// ---------------- Kernel 4a: P = x1@(W1-W2), Q = x1@W2 (x1 = hi+lo) ----------------
__global__ __launch_bounds__(256) void k_pq(const __bf16* __restrict__ xh,
                                            const __bf16* __restrict__ xl,
                                            const float* __restrict__ w2,
                                            __bf16* __restrict__ Pb,
                                            __bf16* __restrict__ Qb) {
  __shared__ __align__(16) float ins[4096];
  int tid = threadIdx.x;
  int pt = blockIdx.x >> 2, oc = blockIdx.x & 3;
  int n0 = pt * 64;
#pragma unroll
  for (int pass = 0; pass < 2; ++pass) {
    int unit = pass * 256 + tid;
    int n = unit >> 3, cc = unit & 7;
    bf16x8 h = *(const bf16x8*)(xh + ((size_t)(n0 + n)) * 64 + cc * 8);
    bf16x8 l = *(const bf16x8*)(xl + ((size_t)(n0 + n)) * 64 + cc * 8);
#pragma unroll
    for (int j = 0; j < 8; ++j)
      ins[(cc * 8 + j) * 64 + n] = (float)h[j] + (float)l[j];
  }
  __syncthreads();
  int cg = tid >> 4, pg = tid & 15;
  int vcol = oc * 64 + cg * 4;
  bool isP = (oc < 2);
  int col = isP ? vcol : (vcol - 128);
  float acc[4][4] = {{0, 0, 0, 0}, {0, 0, 0, 0}, {0, 0, 0, 0}, {0, 0, 0, 0}};
#pragma unroll 4
  for (int k = 0; k < 64; ++k) {
    float4 av = *(const float4*)(ins + k * 64 + pg * 4);
    float a[4] = {av.x, av.y, av.z, av.w};
    float4 wBv = *(const float4*)(w2 + (64 + k) * 128 + col);
    float wv[4];
    if (isP) {
      float4 wAv = *(const float4*)(w2 + k * 128 + col);
      wv[0] = wAv.x - wBv.x; wv[1] = wAv.y - wBv.y;
      wv[2] = wAv.z - wBv.z; wv[3] = wAv.w - wBv.w;
    } else {
      wv[0] = wBv.x; wv[1] = wBv.y; wv[2] = wBv.z; wv[3] = wBv.w;
    }
#pragma unroll
    for (int ii = 0; ii < 4; ++ii)
#pragma unroll
      for (int jj = 0; jj < 4; ++jj)
        acc[ii][jj] = fmaf(a[ii], wv[jj], acc[ii][jj]);
  }
  __bf16* base = (isP ? Pb : Qb);
#pragma unroll
  for (int ii = 0; ii < 4; ++ii) {
    int n = n0 + pg * 4 + ii;
    __bf16 o[4];
#pragma unroll
    for (int jj = 0; jj < 4; ++jj) o[jj] = (__bf16)acc[ii][jj];
    *(uint2*)(base + (size_t)n * 128 + col) = *(const uint2*)o;
  }
}

// ---------------- Kernel 4p: repack wl -> MFMA-B frag order bf16 ----------------
__global__ __launch_bounds__(256) void k_prep(const float* __restrict__ wl,
                                              __bf16* __restrict__ wlb) {
  int t = blockIdx.x * 256 + threadIdx.x;
  int nt = t / 3072;
  int rem = t - nt * 3072;
  int ks = rem / 512;
  int rem2 = rem - ks * 512;
  int nb = rem2 >> 6, lane = rem2 & 63;
  int k0 = ks * 32 + (lane >> 4) * 8;
  int n = nt * 128 + nb * 16 + (lane & 15);
  __bf16 o[8];
#pragma unroll
  for (int j = 0; j < 8; ++j) o[j] = (__bf16)wl[(k0 + j) * 1024 + n];
  *(uint4*)(wlb + (size_t)t * 8) = *(const uint4*)o;
}

// ---------------- Kernel 4b: gather-max + activation -> xb bf16 [n][64:192] ----------------
__global__ __launch_bounds__(256) void k_gmax(const __bf16* __restrict__ Pb,
                                              const __bf16* __restrict__ Qb,
                                              const int* __restrict__ idx2,
                                              const float* __restrict__ b2,
                                              const float* __restrict__ s2,
                                              const float* __restrict__ h2v,
                                              __bf16* __restrict__ xb) {
  int tid = threadIdx.x;
  int c = tid & 127, p = tid >> 7;
  int n = blockIdx.x * 2 + p;
  int b = n >> 11;
  const int* ip = idx2 + n * 5;
  float m = -3.4e38f;
#pragma unroll
  for (int k = 0; k < 5; ++k) {
    int j = ip[k];
    m = fmaxf(m, (float)Qb[((size_t)(b * 2048 + j)) * 128 + c]);
  }
  float v = (float)Pb[(size_t)n * 128 + c] + m + b2[c];
  xb[(size_t)n * 192 + 64 + c] = (__bf16)(relu_(v) * s2[c] + h2v[c]);
}

// ---------------- Kernel 5: bf16 MFMA GEMM fused point-max ----------------
__global__ __launch_bounds__(256) void k_linl_mfma(const __bf16* __restrict__ xb,
                                                   const __bf16* __restrict__ wlb,
                                                   float* __restrict__ pool_part) {
  __shared__ __align__(16) __bf16 Al[4096];
  __shared__ __align__(16) __bf16 Bl[4096];
  __shared__ float red[256];
  int tid = threadIdx.x;
  int w = tid >> 6, lane = tid & 63;
  int mt = blockIdx.x >> 3, nt = blockIdx.x & 7;
  int n0 = mt << 7;
  int wm = w & 1, wn = w >> 1;
  int quad = lane >> 4, lm = lane & 15;
  f32x4 acc[4][4];
#pragma unroll
  for (int i = 0; i < 4; ++i)
#pragma unroll
    for (int j = 0; j < 4; ++j) acc[i][j] = (f32x4){0.f, 0.f, 0.f, 0.f};
  for (int ks = 0; ks < 6; ++ks) {
    __syncthreads();
#pragma unroll
    for (int u = 0; u < 2; ++u) {
      int mb = w * 2 + u;
      const uint4* ga = (const uint4*)(xb + (size_t)(n0 + mb * 16 + lm) * 192 + ks * 32 + quad * 8);
      *(uint4*)(Al + (mb * 64 + lane) * 8) = *ga;
      const uint4* gb = (const uint4*)(wlb + ((((size_t)nt * 6 + ks) * 8 + mb) * 64 + lane) * 8);
      *(uint4*)(Bl + (mb * 64 + lane) * 8) = *gb;
    }
    __syncthreads();
    bf16x8 af[4], bfr[4];
#pragma unroll
    for (int i = 0; i < 4; ++i) {
      af[i] = *(const bf16x8*)(Al + ((wm * 4 + i) * 64 + lane) * 8);
      bfr[i] = *(const bf16x8*)(Bl + ((wn * 4 + i) * 64 + lane) * 8);
    }
#pragma unroll
    for (int i = 0; i < 4; ++i)
#pragma unroll
      for (int j = 0; j < 4; ++j)
        acc[i][j] = __builtin_amdgcn_mfma_f32_16x16x32_bf16(af[i], bfr[j], acc[i][j], 0, 0, 0);
  }
  float pm[4];
#pragma unroll
  for (int j = 0; j < 4; ++j) {
    float m = -3.4e38f;
#pragma unroll
    for (int i = 0; i < 4; ++i)
#pragma unroll
      for (int r = 0; r < 4; ++r) m = fmaxf(m, acc[i][j][r]);
    m = fmaxf(m, __shfl_xor(m, 16));
    m = fmaxf(m, __shfl_xor(m, 32));
    pm[j] = m;
  }
  __syncthreads();
  if (quad == 0) {
#pragma unroll
    for (int j = 0; j < 4; ++j) red[w * 64 + j * 16 + lm] = pm[j];
  }
  __syncthreads();
  if (tid < 128) {
    int wn2 = tid >> 6, cc = tid & 63;
    float v = fmaxf(red[(wn2 * 2) * 64 + cc], red[(wn2 * 2 + 1) * 64 + cc]);
    pool_part[(size_t)mt * 1024 + nt * 128 + wn2 * 64 + cc] = v;
  }
}

// ---------------- Kernel 6: head MLP ----------------
__global__ __launch_bounds__(256) void k_head(
    const float* __restrict__ pool_part, const float* __restrict__ bl,
    const float* __restrict__ sl, const float* __restrict__ hl,
    const float* __restrict__ wm1, const float* __restrict__ bm1,
    const float* __restrict__ sm1, const float* __restrict__ hm1,
    const float* __restrict__ wm2, const float* __restrict__ bm2,
    const float* __restrict__ sm2, const float* __restrict__ hm2,
    const float* __restrict__ wout, const float* __restrict__ bout,
    float* __restrict__ out) {
  __shared__ float p_s[1024], h1_s[512], h2_s[256];
  int b = blockIdx.x, tid = threadIdx.x;
  for (int c = tid; c < 1024; c += 256) {
    float m = -3.4e38f;
#pragma unroll 4
    for (int t = 0; t < 16; ++t)
      m = fmaxf(m, pool_part[(size_t)(b * 16 + t) * 1024 + c]);
    p_s[c] = relu_(m + bl[c]) * sl[c] + hl[c];
  }
  __syncthreads();
  for (int c = tid; c < 512; c += 256) {
    float a0 = 0, a1 = 0, a2 = 0, a3 = 0;
    for (int f = 0; f < 1024; f += 4) {
      a0 = fmaf(p_s[f], wm1[f * 512 + c], a0);
      a1 = fmaf(p_s[f + 1], wm1[(f + 1) * 512 + c], a1);
      a2 = fmaf(p_s[f + 2], wm1[(f + 2) * 512 + c], a2);
      a3 = fmaf(p_s[f + 3], wm1[(f + 3) * 512 + c], a3);
    }
    float a = (a0 + a1) + (a2 + a3);
    h1_s[c] = relu_(a + bm1[c]) * sm1[c] + hm1[c];
  }
  __syncthreads();
  if (tid < 256) {
    float a0 = 0, a1 = 0, a2 = 0, a3 = 0;
    for (int f = 0; f < 512; f += 4) {
      a0 = fmaf(h1_s[f], wm2[f * 256 + tid], a0);
      a1 = fmaf(h1_s[f + 1], wm2[(f + 1) * 256 + tid], a1);
      a2 = fmaf(h1_s[f + 2], wm2[(f + 2) * 256 + tid], a2);
      a3 = fmaf(h1_s[f + 3], wm2[(f + 3) * 256 + tid], a3);
    }
    float a = (a0 + a1) + (a2 + a3);
    h2_s[tid] = relu_(a + bm2[tid]) * sm2[tid] + hm2[tid];
  }
  __syncthreads();
  if (tid < 2) {
    float a0 = 0, a1 = 0;
    for (int f = 0; f < 256; f += 2) {
      a0 = fmaf(h2_s[f], wout[f * 2 + tid], a0);
      a1 = fmaf(h2_s[f + 1], wout[(f + 1) * 2 + tid], a1);
    }
    out[b * 2 + tid] = (a0 + a1) + bout[tid];
  }
}

extern "C" void kernel_launch(void* const* d_in, const int* in_sizes, int n_in,
                              void* d_out, int out_size, void* d_ws, size_t ws_size,
                              hipStream_t stream) {
  const float* pos = (const float*)d_in[0];
  const float* w1a = (const float*)d_in[1];
  const float* b1a = (const float*)d_in[2];
  const float* s1a = (const float*)d_in[3];
  const float* h1a = (const float*)d_in[4];
  const float* w1b = (const float*)d_in[5];
  const float* b1b = (const float*)d_in[6];
  const float* s1b = (const float*)d_in[7];
  const float* h1b = (const float*)d_in[8];
  const float* w1c = (const float*)d_in[9];
  const float* b1c = (const float*)d_in[10];
  const float* s1c = (const float*)d_in[11];
  const float* h1c = (const float*)d_in[12];
  const float* w2 = (const float*)d_in[13];
  const float* b2 = (const float*)d_in[14];
  const float* s2 = (const float*)d_in[15];
  const float* h2 = (const float*)d_in[16];
  const float* wl = (const float*)d_in[17];
  const float* bl = (const float*)d_in[18];
  const float* sl = (const float*)d_in[19];
  const float* hl = (const float*)d_in[20];
  const float* wm1 = (const float*)d_in[21];
  const float* bm1 = (const float*)d_in[22];
  const float* sm1 = (const float*)d_in[23];
  const float* hm1 = (const float*)d_in[24];
  const float* wm2 = (const float*)d_in[25];
  const float* bm2 = (const float*)d_in[26];
  const float* sm2 = (const float*)d_in[27];
  const float* hm2 = (const float*)d_in[28];
  const float* wout = (const float*)d_in[29];
  const float* bout = (const float*)d_in[30];
  float* out = (float*)d_out;

  float* base = (float*)d_ws;
  __bf16* xh = (__bf16*)base;
  __bf16* xl = (__bf16*)(base + 2097152);
  float* PbF = base + 4194304;
  float* QbF = PbF + 4194304;
  float* xbF = QbF + 4194304;
  int* idx = (int*)(xbF + 6291456);
  float* sq = (float*)(idx + 327680);
  __bf16* Pb = (__bf16*)PbF;
  __bf16* Qb = (__bf16*)QbF;
  __bf16* xb = (__bf16*)xbF;
  float* ut = PbF;
  float* vv = QbF;
  __bf16* wlb = (__bf16*)base;
  float* pool_part = base + 131072;

  k_knn1<<<2048, 256, 0, stream>>>(pos, idx);
  k_uv<<<1024, 256, 0, stream>>>(pos, w1a, b1a, ut, vv);
  k_edge1<<<1024, 256, 0, stream>>>(idx, ut, vv, s1a, h1a, w1b, b1b, s1b, h1b,
                                    w1c, b1c, s1c, h1c, xh, xl, sq, xb);
  k_knn2<<<2048, 256, 0, stream>>>(xh, xl, sq, idx);
  k_pq<<<4096, 256, 0, stream>>>(xh, xl, w2, Pb, Qb);
  k_prep<<<96, 256, 0, stream>>>(wl, wlb);
  k_gmax<<<32768, 256, 0, stream>>>(Pb, Qb, idx, b2, s2, h2, xb);
  k_linl_mfma<<<4096, 256, 0, stream>>>(xb, wlb, pool_part);
  k_head<<<32, 256, 0, stream>>>(pool_part, bl, sl, hl, wm1, bm1, sm1, hm1, wm2,
                                 bm2, sm2, hm2, wout, bout, out);
}

// Round 10
// 754.736 us; speedup vs baseline: 1.0613x; 1.0613x over previous
//
#include <hip/hip_runtime.h>

#define DEV __device__ __forceinline__
DEV float relu_(float x) { return fmaxf(x, 0.0f); }

typedef __attribute__((ext_vector_type(4))) float f32x4;
typedef __attribute__((ext_vector_type(8))) __bf16 bf16x8;

// branchless EXACT top-5 insert: strict-< bubble (keeps 5 smallest, sorted)
DEV void knn_insert_bl(float (&bd)[5], int (&bi)[5], float d, int j) {
#pragma unroll
  for (int p = 0; p < 5; ++p) {
    bool lt = d < bd[p];
    float nd = lt ? d : bd[p];
    float cd = lt ? bd[p] : d;
    int ni = lt ? j : bi[p];
    int ci = lt ? bi[p] : j;
    bd[p] = nd; d = cd;
    bi[p] = ni; j = ci;
  }
}

// ---------------- Kernel 1: kNN on pos (F=3), 8-way candidate split ----------------
__global__ __launch_bounds__(256) void k_knn1(const float* __restrict__ pos,
                                              int* __restrict__ idx1) {
  __shared__ float ps[6144];
  __shared__ float sqs[2048];
  __shared__ float md[640];
  __shared__ int mi[640];
  int tid = threadIdx.x;
  int b = blockIdx.x >> 6, qc = blockIdx.x & 63;
  const float* src = pos + b * 6144;
  for (int u = tid; u < 6144; u += 256) ps[u] = src[u];
  __syncthreads();
  for (int u = tid; u < 2048; u += 256) {
    float x = ps[u * 3], y = ps[u * 3 + 1], z = ps[u * 3 + 2];
    sqs[u] = fmaf(z, z, fmaf(y, y, x * x));
  }
  __syncthreads();
  int q = tid & 31, sub = tid >> 5;
  int qi = qc * 32 + q;
  float qx = ps[qi * 3], qy = ps[qi * 3 + 1], qz = ps[qi * 3 + 2];
  float qsq = sqs[qi];
  float bd[5] = {1e30f, 1e30f, 1e30f, 1e30f, 1e30f};
  int bi[5] = {0, 0, 0, 0, 0};
  int j0 = sub * 256;
  for (int j = j0; j < j0 + 256; ++j) {
    float px = ps[j * 3], py = ps[j * 3 + 1], pz = ps[j * 3 + 2];
    float dot = fmaf(qz, pz, fmaf(qy, py, qx * px));
    float d = (qsq + sqs[j]) - 2.0f * dot;
    knn_insert_bl(bd, bi, d, j);
  }
  for (int half = 4; half >= 1; half >>= 1) {
    __syncthreads();
    if (sub >= half && sub < 2 * half) {
      int slot = (q * 4 + (sub - half)) * 5;
#pragma unroll
      for (int k = 0; k < 5; ++k) { md[slot + k] = bd[k]; mi[slot + k] = bi[k]; }
    }
    __syncthreads();
    if (sub < half) {
      int slot = (q * 4 + sub) * 5;
#pragma unroll
      for (int k = 0; k < 5; ++k) knn_insert_bl(bd, bi, md[slot + k], mi[slot + k]);
    }
  }
  if (sub == 0) {
    int* op = idx1 + (b * 2048 + qi) * 5;
#pragma unroll
    for (int k = 0; k < 5; ++k) op[k] = bi[k];
  }
}

// ---------------- Kernel 1b: per-point u/v for EdgeConv1 layer-1 ----------------
__global__ __launch_bounds__(256) void k_uv(const float* __restrict__ pos,
                                            const float* __restrict__ w1a,
                                            const float* __restrict__ b1a,
                                            float* __restrict__ ut,
                                            float* __restrict__ v) {
  __shared__ float wAs[384];
  __shared__ float bs[64];
  int tid = threadIdx.x;
  for (int u = tid; u < 384; u += 256) wAs[u] = w1a[u];
  if (tid < 64) bs[tid] = b1a[tid];
  __syncthreads();
  int lane = tid & 63, fq = tid >> 6;
  int p = blockIdx.x * 64 + lane;
  int b = p >> 11, nloc = p & 2047;
  float x0 = pos[p * 3], x1 = pos[p * 3 + 1], x2 = pos[p * 3 + 2];
  float uu[16], vv[16];
#pragma unroll
  for (int m = 0; m < 16; ++m) {
    int f = fq * 16 + m;
    float wt0 = wAs[f], wt1 = wAs[64 + f], wt2 = wAs[128 + f];
    float wb0 = wAs[192 + f], wb1 = wAs[256 + f], wb2 = wAs[320 + f];
    float uval = bs[f];
    uval = fmaf(x0, wt0 - wb0, uval);
    uval = fmaf(x1, wt1 - wb1, uval);
    uval = fmaf(x2, wt2 - wb2, uval);
    uu[m] = uval;
    vv[m] = fmaf(x2, wb2, fmaf(x1, wb1, x0 * wb0));
  }
#pragma unroll
  for (int m = 0; m < 16; ++m)
    ut[((size_t)b * 64 + fq * 16 + m) * 2048 + nloc] = uu[m];
#pragma unroll
  for (int it = 0; it < 4; ++it)
    *(float4*)(v + (size_t)p * 64 + fq * 16 + it * 4) = *(const float4*)(vv + it * 4);
}

// ---------------- Kernel 2: EdgeConv1 layers 2/3 as 4x4-blocked GEMM ----------------
__global__ __launch_bounds__(256) void k_edge1(
    const int* __restrict__ idx1, const float* __restrict__ ut,
    const float* __restrict__ v,
    const float* __restrict__ s1a, const float* __restrict__ h1a,
    const float* __restrict__ w1b, const float* __restrict__ b1b,
    const float* __restrict__ s1b, const float* __restrict__ h1b,
    const float* __restrict__ w1c, const float* __restrict__ b1c,
    const float* __restrict__ s1c, const float* __restrict__ h1c,
    __bf16* __restrict__ xh, __bf16* __restrict__ xl,
    float* __restrict__ sqo, __bf16* __restrict__ xb) {
  __shared__ __align__(16) float h1t[64 * 68];
  __shared__ __align__(16) float h2t[64 * 68];
  __shared__ __align__(16) float wB[4096], wC[4096];
  __shared__ float cA[128], cB[192], cC[192];
  __shared__ float red[64 * 17];
  int tid = threadIdx.x;
  for (int u = tid; u < 4096; u += 256) { wB[u] = w1b[u]; wC[u] = w1c[u]; }
  if (tid < 64) {
    cA[tid] = s1a[tid]; cA[64 + tid] = h1a[tid];
    cB[tid] = b1b[tid]; cB[64 + tid] = s1b[tid]; cB[128 + tid] = h1b[tid];
    cC[tid] = b1c[tid]; cC[64 + tid] = s1c[tid]; cC[128 + tid] = h1c[tid];
  }
  int p0 = blockIdx.x * 64;
  int b = p0 >> 11, nloc0 = p0 & 2047;
  size_t bb = (size_t)b * 2048;
  int e = tid & 63, fq = tid >> 6;
  int cg = tid >> 4, pg = tid & 15;
  float amax[4][4];
#pragma unroll
  for (int i = 0; i < 4; ++i)
#pragma unroll
    for (int j = 0; j < 4; ++j) amax[i][j] = -3.4e38f;
  __syncthreads();
  for (int k = 0; k < 5; ++k) {
    {
      int j = idx1[(p0 + e) * 5 + k];
      const float* vrow = v + (bb + j) * 64 + fq * 16;
#pragma unroll
      for (int it = 0; it < 4; ++it) {
        float4 vv = *(const float4*)(vrow + it * 4);
        float vr[4] = {vv.x, vv.y, vv.z, vv.w};
#pragma unroll
        for (int m = 0; m < 4; ++m) {
          int f = fq * 16 + it * 4 + m;
          float uval = ut[((size_t)b * 64 + f) * 2048 + nloc0 + e];
          h1t[f * 68 + e] = relu_(uval + vr[m]) * cA[f] + cA[64 + f];
        }
      }
    }
    __syncthreads();
    {
      float acc[4][4] = {{0, 0, 0, 0}, {0, 0, 0, 0}, {0, 0, 0, 0}, {0, 0, 0, 0}};
#pragma unroll 4
      for (int f = 0; f < 64; ++f) {
        float4 av = *(const float4*)(h1t + f * 68 + pg * 4);
        float4 wv = *(const float4*)(wB + f * 64 + cg * 4);
        float a[4] = {av.x, av.y, av.z, av.w};
        float w[4] = {wv.x, wv.y, wv.z, wv.w};
#pragma unroll
        for (int ii = 0; ii < 4; ++ii)
#pragma unroll
          for (int jj = 0; jj < 4; ++jj)
            acc[ii][jj] = fmaf(a[ii], w[jj], acc[ii][jj]);
      }
#pragma unroll
      for (int jj = 0; jj < 4; ++jj) {
        int c = cg * 4 + jj;
        float bv = cB[c], sv = cB[64 + c], hv = cB[128 + c];
#pragma unroll
        for (int ii = 0; ii < 4; ++ii)
          h2t[c * 68 + pg * 4 + ii] = relu_(acc[ii][jj] + bv) * sv + hv;
      }
    }
    __syncthreads();
    {
      float acc[4][4] = {{0, 0, 0, 0}, {0, 0, 0, 0}, {0, 0, 0, 0}, {0, 0, 0, 0}};
#pragma unroll 4
      for (int f = 0; f < 64; ++f) {
        float4 av = *(const float4*)(h2t + f * 68 + pg * 4);
        float4 wv = *(const float4*)(wC + f * 64 + cg * 4);
        float a[4] = {av.x, av.y, av.z, av.w};
        float w[4] = {wv.x, wv.y, wv.z, wv.w};
#pragma unroll
        for (int ii = 0; ii < 4; ++ii)
#pragma unroll
          for (int jj = 0; jj < 4; ++jj)
            acc[ii][jj] = fmaf(a[ii], w[jj], acc[ii][jj]);
      }
#pragma unroll
      for (int ii = 0; ii < 4; ++ii)
#pragma unroll
        for (int jj = 0; jj < 4; ++jj)
          amax[ii][jj] = fmaxf(amax[ii][jj], acc[ii][jj]);
    }
    __syncthreads();
  }
#pragma unroll
  for (int ii = 0; ii < 4; ++ii) {
    int n = p0 + pg * 4 + ii;
    float sqp = 0.f;
    __bf16 oh[4], ol[4], ob[4];
#pragma unroll
    for (int jj = 0; jj < 4; ++jj) {
      int c = cg * 4 + jj;
      float val = relu_(amax[ii][jj] + cC[c]) * cC[64 + c] + cC[128 + c];
      sqp = fmaf(val, val, sqp);
      __bf16 h = (__bf16)val;
      oh[jj] = h;
      ol[jj] = (__bf16)(val - (float)h);
      ob[jj] = h;
    }
    *(uint2*)(xh + (size_t)n * 64 + cg * 4) = *(const uint2*)oh;
    *(uint2*)(xl + (size_t)n * 64 + cg * 4) = *(const uint2*)ol;
    *(uint2*)(xb + (size_t)n * 192 + cg * 4) = *(const uint2*)ob;
    red[(pg * 4 + ii) * 17 + cg] = sqp;
  }
  __syncthreads();
  if (tid < 64) {
    float s = 0.f;
#pragma unroll
    for (int g = 0; g < 16; ++g) s += red[tid * 17 + g];
    sqo[p0 + tid] = s;
  }
}

// ---------------- Kernel 3: kNN on x1 — MFMA hi/lo, staged, 8 waves, cand-split ----------------
// grid 1024 (32 b x 32 q-chunks of 64), block 512 = 8 waves: qg=w&3 (16 queries), ch=w>>2 (16 tiles)
__global__ __launch_bounds__(512) void k_knn2(const __bf16* __restrict__ xh,
                                              const __bf16* __restrict__ xl,
                                              const float* __restrict__ sq,
                                              int* __restrict__ idx2) {
  __shared__ __align__(16) __bf16 Bh[2][4608];  // [ch][64 cands * 72 pad]
  __shared__ __align__(16) __bf16 Bl[2][4608];
  __shared__ float csq_s[2][64];
  __shared__ float mf[4][80];  // cross-wave merge: [qg][quad*20 + r*5 + k]
  __shared__ int mi_s[4][80];
  int tid = threadIdx.x;
  int w = tid >> 6, lane = tid & 63;
  int quad = lane >> 4, lm = lane & 15;
  int qg = w & 3, ch = w >> 2;
  int ctid = tid & 255;  // index within ch-group
  int b = blockIdx.x >> 5, qc = blockIdx.x & 31;
  int q0 = qc * 64;
  size_t bb = (size_t)b * 2048;
  // A-frags (queries) from global, held in regs
  const __bf16* qhp = xh + (bb + q0 + qg * 16 + lm) * 64 + quad * 8;
  const __bf16* qlp = xl + (bb + q0 + qg * 16 + lm) * 64 + quad * 8;
  bf16x8 Ah0 = *(const bf16x8*)(qhp);
  bf16x8 Ah1 = *(const bf16x8*)(qhp + 32);
  bf16x8 Al0 = *(const bf16x8*)(qlp);
  bf16x8 Al1 = *(const bf16x8*)(qlp + 32);
  float bd[4][5];
  int bi[4][5];
#pragma unroll
  for (int r = 0; r < 4; ++r)
#pragma unroll
    for (int k = 0; k < 5; ++k) { bd[r][k] = 1e30f; bi[r][k] = 0; }
  for (int t = 0; t < 16; ++t) {
    int ct = ch * 16 + t;
    __syncthreads();  // prev round's frag reads done
#pragma unroll
    for (int pass = 0; pass < 2; ++pass) {
      int unit = pass * 256 + ctid;
      int n = unit >> 3, cc = unit & 7;
      const __bf16* gsrc = xh + (bb + ct * 64 + n) * 64 + cc * 8;
      const __bf16* gsrl = xl + (bb + ct * 64 + n) * 64 + cc * 8;
      *(uint4*)(&Bh[ch][n * 72 + cc * 8]) = *(const uint4*)gsrc;
      *(uint4*)(&Bl[ch][n * 72 + cc * 8]) = *(const uint4*)gsrl;
    }
    if (ctid < 16)
      *(float4*)(&csq_s[ch][ctid * 4]) = *(const float4*)(sq + bb + ct * 64 + ctid * 4);
    __syncthreads();
#pragma unroll
    for (int nt = 0; nt < 4; ++nt) {
      const __bf16* bph = &Bh[ch][(nt * 16 + lm) * 72 + quad * 8];
      const __bf16* bpl = &Bl[ch][(nt * 16 + lm) * 72 + quad * 8];
      bf16x8 Bh0 = *(const bf16x8*)(bph);
      bf16x8 Bh1 = *(const bf16x8*)(bph + 32);
      bf16x8 Bl0 = *(const bf16x8*)(bpl);
      bf16x8 Bl1 = *(const bf16x8*)(bpl + 32);
      f32x4 acc = {0.f, 0.f, 0.f, 0.f};
      acc = __builtin_amdgcn_mfma_f32_16x16x32_bf16(Ah0, Bh0, acc, 0, 0, 0);
      acc = __builtin_amdgcn_mfma_f32_16x16x32_bf16(Ah1, Bh1, acc, 0, 0, 0);
      acc = __builtin_amdgcn_mfma_f32_16x16x32_bf16(Ah0, Bl0, acc, 0, 0, 0);
      acc = __builtin_amdgcn_mfma_f32_16x16x32_bf16(Ah1, Bl1, acc, 0, 0, 0);
      acc = __builtin_amdgcn_mfma_f32_16x16x32_bf16(Al0, Bh0, acc, 0, 0, 0);
      acc = __builtin_amdgcn_mfma_f32_16x16x32_bf16(Al1, Bh1, acc, 0, 0, 0);
      int cid = ct * 64 + nt * 16 + lm;
      float csq = csq_s[ch][nt * 16 + lm];
#pragma unroll
      for (int r = 0; r < 4; ++r) {
        float d = fmaf(-2.0f, acc[r], csq);  // qsq const per query: selection-invariant
        knn_insert_bl(bd[r], bi[r], d, cid);
      }
    }
  }
  // in-wave butterfly over 16 lm-partials (all lanes converge to the merged list)
  for (int m = 1; m <= 8; m <<= 1) {
#pragma unroll
    for (int r = 0; r < 4; ++r) {
      float od[5]; int oi[5];
#pragma unroll
      for (int k = 0; k < 5; ++k) {
        od[k] = __shfl_xor(bd[r][k], m);
        oi[k] = __shfl_xor(bi[r][k], m);
      }
#pragma unroll
      for (int k = 0; k < 5; ++k) knn_insert_bl(bd[r], bi[r], od[k], oi[k]);
    }
  }
  __syncthreads();
  if (ch == 1 && lm == 0) {
#pragma unroll
    for (int r = 0; r < 4; ++r)
#pragma unroll
      for (int k = 0; k < 5; ++k) {
        mf[qg][quad * 20 + r * 5 + k] = bd[r][k];
        mi_s[qg][quad * 20 + r * 5 + k] = bi[r][k];
      }
  }
  __syncthreads();
  if (ch == 0) {
#pragma unroll
    for (int r = 0; r < 4; ++r)
#pragma unroll
      for (int k = 0; k < 5; ++k)
        knn_insert_bl(bd[r], bi[r], mf[qg][quad * 20 + r * 5 + k],
                      mi_s[qg][quad * 20 + r * 5 + k]);
    if (lm == 0) {
#pragma unroll
      for (int r = 0; r < 4; ++r) {
        int qi = q0 + qg * 16 + quad * 4 + r;
        int* op = idx2 + (bb + qi) * 5;
#pragma unroll
        for (int k = 0; k < 5; ++k) op[k] = bi[r][k];
      }
    }
  }
}

// ---------------- Kernel 4a: P = x1@(W1-W2), Q = x1@W2 (x1 = hi+lo) ----------------
__global__ __launch_bounds__(256) void k_pq(const __bf16* __restrict__ xh,
                                            const __bf16* __restrict__ xl,
                                            const float* __restrict__ w2,
                                            __bf16* __restrict__ Pb,
                                            __bf16* __restrict__ Qb) {
  __shared__ __align__(16) float ins[4096];
  int tid = threadIdx.x;
  int pt = blockIdx.x >> 2, oc = blockIdx.x & 3;
  int n0 = pt * 64;
#pragma unroll
  for (int pass = 0; pass < 2; ++pass) {
    int unit = pass * 256 + tid;
    int n = unit >> 3, cc = unit & 7;
    bf16x8 h = *(const bf16x8*)(xh + ((size_t)(n0 + n)) * 64 + cc * 8);
    bf16x8 l = *(const bf16x8*)(xl + ((size_t)(n0 + n)) * 64 + cc * 8);
#pragma unroll
    for (int j = 0; j < 8; ++j)
      ins[(cc * 8 + j) * 64 + n] = (float)h[j] + (float)l[j];
  }
  __syncthreads();
  int cg = tid >> 4, pg = tid & 15;
  int vcol = oc * 64 + cg * 4;
  bool isP = (oc < 2);
  int col = isP ? vcol : (vcol - 128);
  float acc[4][4] = {{0, 0, 0, 0}, {0, 0, 0, 0}, {0, 0, 0, 0}, {0, 0, 0, 0}};
#pragma unroll 4
  for (int k = 0; k < 64; ++k) {
    float4 av = *(const float4*)(ins + k * 64 + pg * 4);
    float a[4] = {av.x, av.y, av.z, av.w};
    float4 wBv = *(const float4*)(w2 + (64 + k) * 128 + col);
    float wv[4];
    if (isP) {
      float4 wAv = *(const float4*)(w2 + k * 128 + col);
      wv[0] = wAv.x - wBv.x; wv[1] = wAv.y - wBv.y;
      wv[2] = wAv.z - wBv.z; wv[3] = wAv.w - wBv.w;
    } else {
      wv[0] = wBv.x; wv[1] = wBv.y; wv[2] = wBv.z; wv[3] = wBv.w;
    }
#pragma unroll
    for (int ii = 0; ii < 4; ++ii)
#pragma unroll
      for (int jj = 0; jj < 4; ++jj)
        acc[ii][jj] = fmaf(a[ii], wv[jj], acc[ii][jj]);
  }
  __bf16* base = (isP ? Pb : Qb);
#pragma unroll
  for (int ii = 0; ii < 4; ++ii) {
    int n = n0 + pg * 4 + ii;
    __bf16 o[4];
#pragma unroll
    for (int jj = 0; jj < 4; ++jj) o[jj] = (__bf16)acc[ii][jj];
    *(uint2*)(base + (size_t)n * 128 + col) = *(const uint2*)o;
  }
}

// ---------------- Kernel 4p: repack wl -> MFMA-B frag order bf16 ----------------
__global__ __launch_bounds__(256) void k_prep(const float* __restrict__ wl,
                                              __bf16* __restrict__ wlb) {
  int t = blockIdx.x * 256 + threadIdx.x;
  int nt = t / 3072;
  int rem = t - nt * 3072;
  int ks = rem / 512;
  int rem2 = rem - ks * 512;
  int nb = rem2 >> 6, lane = rem2 & 63;
  int k0 = ks * 32 + (lane >> 4) * 8;
  int n = nt * 128 + nb * 16 + (lane & 15);
  __bf16 o[8];
#pragma unroll
  for (int j = 0; j < 8; ++j) o[j] = (__bf16)wl[(k0 + j) * 1024 + n];
  *(uint4*)(wlb + (size_t)t * 8) = *(const uint4*)o;
}

// ---------------- Kernel 4b: gather-max + activation -> xb bf16 [n][64:192] ----------------
__global__ __launch_bounds__(256) void k_gmax(const __bf16* __restrict__ Pb,
                                              const __bf16* __restrict__ Qb,
                                              const int* __restrict__ idx2,
                                              const float* __restrict__ b2,
                                              const float* __restrict__ s2,
                                              const float* __restrict__ h2v,
                                              __bf16* __restrict__ xb) {
  int tid = threadIdx.x;
  int c = tid & 127, p = tid >> 7;
  int n = blockIdx.x * 2 + p;
  int b = n >> 11;
  const int* ip = idx2 + n * 5;
  float m = -3.4e38f;
#pragma unroll
  for (int k = 0; k < 5; ++k) {
    int j = ip[k];
    m = fmaxf(m, (float)Qb[((size_t)(b * 2048 + j)) * 128 + c]);
  }
  float v = (float)Pb[(size_t)n * 128 + c] + m + b2[c];
  xb[(size_t)n * 192 + 64 + c] = (__bf16)(relu_(v) * s2[c] + h2v[c]);
}

// ---------------- Kernel 5: bf16 MFMA GEMM fused point-max ----------------
__global__ __launch_bounds__(256) void k_linl_mfma(const __bf16* __restrict__ xb,
                                                   const __bf16* __restrict__ wlb,
                                                   float* __restrict__ pool_part) {
  __shared__ __align__(16) __bf16 Al[4096];
  __shared__ __align__(16) __bf16 Bl[4096];
  __shared__ float red[256];
  int tid = threadIdx.x;
  int w = tid >> 6, lane = tid & 63;
  int mt = blockIdx.x >> 3, nt = blockIdx.x & 7;
  int n0 = mt << 7;
  int wm = w & 1, wn = w >> 1;
  int quad = lane >> 4, lm = lane & 15;
  f32x4 acc[4][4];
#pragma unroll
  for (int i = 0; i < 4; ++i)
#pragma unroll
    for (int j = 0; j < 4; ++j) acc[i][j] = (f32x4){0.f, 0.f, 0.f, 0.f};
  for (int ks = 0; ks < 6; ++ks) {
    __syncthreads();
#pragma unroll
    for (int u = 0; u < 2; ++u) {
      int mb = w * 2 + u;
      const uint4* ga = (const uint4*)(xb + (size_t)(n0 + mb * 16 + lm) * 192 + ks * 32 + quad * 8);
      *(uint4*)(Al + (mb * 64 + lane) * 8) = *ga;
      const uint4* gb = (const uint4*)(wlb + ((((size_t)nt * 6 + ks) * 8 + mb) * 64 + lane) * 8);
      *(uint4*)(Bl + (mb * 64 + lane) * 8) = *gb;
    }
    __syncthreads();
    bf16x8 af[4], bfr[4];
#pragma unroll
    for (int i = 0; i < 4; ++i) {
      af[i] = *(const bf16x8*)(Al + ((wm * 4 + i) * 64 + lane) * 8);
      bfr[i] = *(const bf16x8*)(Bl + ((wn * 4 + i) * 64 + lane) * 8);
    }
#pragma unroll
    for (int i = 0; i < 4; ++i)
#pragma unroll
      for (int j = 0; j < 4; ++j)
        acc[i][j] = __builtin_amdgcn_mfma_f32_16x16x32_bf16(af[i], bfr[j], acc[i][j], 0, 0, 0);
  }
  float pm[4];
#pragma unroll
  for (int j = 0; j < 4; ++j) {
    float m = -3.4e38f;
#pragma unroll
    for (int i = 0; i < 4; ++i)
#pragma unroll
      for (int r = 0; r < 4; ++r) m = fmaxf(m, acc[i][j][r]);
    m = fmaxf(m, __shfl_xor(m, 16));
    m = fmaxf(m, __shfl_xor(m, 32));
    pm[j] = m;
  }
  __syncthreads();
  if (quad == 0) {
#pragma unroll
    for (int j = 0; j < 4; ++j) red[w * 64 + j * 16 + lm] = pm[j];
  }
  __syncthreads();
  if (tid < 128) {
    int wn2 = tid >> 6, cc = tid & 63;
    float v = fmaxf(red[(wn2 * 2) * 64 + cc], red[(wn2 * 2 + 1) * 64 + cc]);
    pool_part[(size_t)mt * 1024 + nt * 128 + wn2 * 64 + cc] = v;
  }
}

// ---------------- Kernel 6: head MLP ----------------
__global__ __launch_bounds__(256) void k_head(
    const float* __restrict__ pool_part, const float* __restrict__ bl,
    const float* __restrict__ sl, const float* __restrict__ hl,
    const float* __restrict__ wm1, const float* __restrict__ bm1,
    const float* __restrict__ sm1, const float* __restrict__ hm1,
    const float* __restrict__ wm2, const float* __restrict__ bm2,
    const float* __restrict__ sm2, const float* __restrict__ hm2,
    const float* __restrict__ wout, const float* __restrict__ bout,
    float* __restrict__ out) {
  __shared__ float p_s[1024], h1_s[512], h2_s[256];
  int b = blockIdx.x, tid = threadIdx.x;
  for (int c = tid; c < 1024; c += 256) {
    float m = -3.4e38f;
#pragma unroll 4
    for (int t = 0; t < 16; ++t)
      m = fmaxf(m, pool_part[(size_t)(b * 16 + t) * 1024 + c]);
    p_s[c] = relu_(m + bl[c]) * sl[c] + hl[c];
  }
  __syncthreads();
  for (int c = tid; c < 512; c += 256) {
    float a0 = 0, a1 = 0, a2 = 0, a3 = 0;
    for (int f = 0; f < 1024; f += 4) {
      a0 = fmaf(p_s[f], wm1[f * 512 + c], a0);
      a1 = fmaf(p_s[f + 1], wm1[(f + 1) * 512 + c], a1);
      a2 = fmaf(p_s[f + 2], wm1[(f + 2) * 512 + c], a2);
      a3 = fmaf(p_s[f + 3], wm1[(f + 3) * 512 + c], a3);
    }
    float a = (a0 + a1) + (a2 + a3);
    h1_s[c] = relu_(a + bm1[c]) * sm1[c] + hm1[c];
  }
  __syncthreads();
  if (tid < 256) {
    float a0 = 0, a1 = 0, a2 = 0, a3 = 0;
    for (int f = 0; f < 512; f += 4) {
      a0 = fmaf(h1_s[f], wm2[f * 256 + tid], a0);
      a1 = fmaf(h1_s[f + 1], wm2[(f + 1) * 256 + tid], a1);
      a2 = fmaf(h1_s[f + 2], wm2[(f + 2) * 256 + tid], a2);
      a3 = fmaf(h1_s[f + 3], wm2[(f + 3) * 256 + tid], a3);
    }
    float a = (a0 + a1) + (a2 + a3);
    h2_s[tid] = relu_(a + bm2[tid]) * sm2[tid] + hm2[tid];
  }
  __syncthreads();
  if (tid < 2) {
    float a0 = 0, a1 = 0;
    for (int f = 0; f < 256; f += 2) {
      a0 = fmaf(h2_s[f], wout[f * 2 + tid], a0);
      a1 = fmaf(h2_s[f + 1], wout[(f + 1) * 2 + tid], a1);
    }
    out[b * 2 + tid] = (a0 + a1) + bout[tid];
  }
}

extern "C" void kernel_launch(void* const* d_in, const int* in_sizes, int n_in,
                              void* d_out, int out_size, void* d_ws, size_t ws_size,
                              hipStream_t stream) {
  const float* pos = (const float*)d_in[0];
  const float* w1a = (const float*)d_in[1];
  const float* b1a = (const float*)d_in[2];
  const float* s1a = (const float*)d_in[3];
  const float* h1a = (const float*)d_in[4];
  const float* w1b = (const float*)d_in[5];
  const float* b1b = (const float*)d_in[6];
  const float* s1b = (const float*)d_in[7];
  const float* h1b = (const float*)d_in[8];
  const float* w1c = (const float*)d_in[9];
  const float* b1c = (const float*)d_in[10];
  const float* s1c = (const float*)d_in[11];
  const float* h1c = (const float*)d_in[12];
  const float* w2 = (const float*)d_in[13];
  const float* b2 = (const float*)d_in[14];
  const float* s2 = (const float*)d_in[15];
  const float* h2 = (const float*)d_in[16];
  const float* wl = (const float*)d_in[17];
  const float* bl = (const float*)d_in[18];
  const float* sl = (const float*)d_in[19];
  const float* hl = (const float*)d_in[20];
  const float* wm1 = (const float*)d_in[21];
  const float* bm1 = (const float*)d_in[22];
  const float* sm1 = (const float*)d_in[23];
  const float* hm1 = (const float*)d_in[24];
  const float* wm2 = (const float*)d_in[25];
  const float* bm2 = (const float*)d_in[26];
  const float* sm2 = (const float*)d_in[27];
  const float* hm2 = (const float*)d_in[28];
  const float* wout = (const float*)d_in[29];
  const float* bout = (const float*)d_in[30];
  float* out = (float*)d_out;

  float* base = (float*)d_ws;
  __bf16* xh = (__bf16*)base;
  __bf16* xl = (__bf16*)(base + 2097152);
  float* PbF = base + 4194304;
  float* QbF = PbF + 4194304;
  float* xbF = QbF + 4194304;
  int* idx = (int*)(xbF + 6291456);
  float* sq = (float*)(idx + 327680);
  __bf16* Pb = (__bf16*)PbF;
  __bf16* Qb = (__bf16*)QbF;
  __bf16* xb = (__bf16*)xbF;
  float* ut = PbF;
  float* vv = QbF;
  __bf16* wlb = (__bf16*)base;
  float* pool_part = base + 131072;

  k_knn1<<<2048, 256, 0, stream>>>(pos, idx);
  k_uv<<<1024, 256, 0, stream>>>(pos, w1a, b1a, ut, vv);
  k_edge1<<<1024, 256, 0, stream>>>(idx, ut, vv, s1a, h1a, w1b, b1b, s1b, h1b,
                                    w1c, b1c, s1c, h1c, xh, xl, sq, xb);
  k_knn2<<<1024, 512, 0, stream>>>(xh, xl, sq, idx);
  k_pq<<<4096, 256, 0, stream>>>(xh, xl, w2, Pb, Qb);
  k_prep<<<96, 256, 0, stream>>>(wl, wlb);
  k_gmax<<<32768, 256, 0, stream>>>(Pb, Qb, idx, b2, s2, h2, xb);
  k_linl_mfma<<<4096, 256, 0, stream>>>(xb, wlb, pool_part);
  k_head<<<32, 256, 0, stream>>>(pool_part, bl, sl, hl, wm1, bm1, sm1, hm1, wm2,
                                 bm2, sm2, hm2, wout, bout, out);
}

// Round 11
// 667.239 us; speedup vs baseline: 1.2005x; 1.1311x over previous
//
#include <hip/hip_runtime.h>

#define DEV __device__ __forceinline__
DEV float relu_(float x) { return fmaxf(x, 0.0f); }

typedef __attribute__((ext_vector_type(4))) float f32x4;
typedef __attribute__((ext_vector_type(8))) __bf16 bf16x8;

// branchy top-5 insert (R6-measured best for knn2's wave-coherent stream)
DEV void knn_insert(float (&bd)[5], int (&bi)[5], float d, int j) {
  if (d >= bd[4]) return;
  bd[4] = d; bi[4] = j;
#pragma unroll
  for (int p = 4; p > 0; --p) {
    if (bd[p] < bd[p - 1]) {
      float td = bd[p]; bd[p] = bd[p - 1]; bd[p - 1] = td;
      int ti = bi[p]; bi[p] = bi[p - 1]; bi[p - 1] = ti;
    }
  }
}

// branchless EXACT top-5 insert (used in knn1)
DEV void knn_insert_bl(float (&bd)[5], int (&bi)[5], float d, int j) {
#pragma unroll
  for (int p = 0; p < 5; ++p) {
    bool lt = d < bd[p];
    float nd = lt ? d : bd[p];
    float cd = lt ? bd[p] : d;
    int ni = lt ? j : bi[p];
    int ci = lt ? bi[p] : j;
    bd[p] = nd; d = cd;
    bi[p] = ni; j = ci;
  }
}

// ---------------- Kernel 1: kNN on pos (F=3), 8-way candidate split ----------------
__global__ __launch_bounds__(256) void k_knn1(const float* __restrict__ pos,
                                              int* __restrict__ idx1) {
  __shared__ float ps[6144];
  __shared__ float sqs[2048];
  __shared__ float md[640];
  __shared__ int mi[640];
  int tid = threadIdx.x;
  int b = blockIdx.x >> 6, qc = blockIdx.x & 63;
  const float* src = pos + b * 6144;
  for (int u = tid; u < 6144; u += 256) ps[u] = src[u];
  __syncthreads();
  for (int u = tid; u < 2048; u += 256) {
    float x = ps[u * 3], y = ps[u * 3 + 1], z = ps[u * 3 + 2];
    sqs[u] = fmaf(z, z, fmaf(y, y, x * x));
  }
  __syncthreads();
  int q = tid & 31, sub = tid >> 5;
  int qi = qc * 32 + q;
  float qx = ps[qi * 3], qy = ps[qi * 3 + 1], qz = ps[qi * 3 + 2];
  float qsq = sqs[qi];
  float bd[5] = {1e30f, 1e30f, 1e30f, 1e30f, 1e30f};
  int bi[5] = {0, 0, 0, 0, 0};
  int j0 = sub * 256;
  for (int j = j0; j < j0 + 256; ++j) {
    float px = ps[j * 3], py = ps[j * 3 + 1], pz = ps[j * 3 + 2];
    float dot = fmaf(qz, pz, fmaf(qy, py, qx * px));
    float d = (qsq + sqs[j]) - 2.0f * dot;
    knn_insert_bl(bd, bi, d, j);
  }
  for (int half = 4; half >= 1; half >>= 1) {
    __syncthreads();
    if (sub >= half && sub < 2 * half) {
      int slot = (q * 4 + (sub - half)) * 5;
#pragma unroll
      for (int k = 0; k < 5; ++k) { md[slot + k] = bd[k]; mi[slot + k] = bi[k]; }
    }
    __syncthreads();
    if (sub < half) {
      int slot = (q * 4 + sub) * 5;
#pragma unroll
      for (int k = 0; k < 5; ++k) knn_insert_bl(bd, bi, md[slot + k], mi[slot + k]);
    }
  }
  if (sub == 0) {
    int* op = idx1 + (b * 2048 + qi) * 5;
#pragma unroll
    for (int k = 0; k < 5; ++k) op[k] = bi[k];
  }
}

// ---------------- Kernel 1b: per-point u/v for EdgeConv1 layer-1 ----------------
__global__ __launch_bounds__(256) void k_uv(const float* __restrict__ pos,
                                            const float* __restrict__ w1a,
                                            const float* __restrict__ b1a,
                                            float* __restrict__ ut,
                                            float* __restrict__ v) {
  __shared__ float wAs[384];
  __shared__ float bs[64];
  int tid = threadIdx.x;
  for (int u = tid; u < 384; u += 256) wAs[u] = w1a[u];
  if (tid < 64) bs[tid] = b1a[tid];
  __syncthreads();
  int lane = tid & 63, fq = tid >> 6;
  int p = blockIdx.x * 64 + lane;
  int b = p >> 11, nloc = p & 2047;
  float x0 = pos[p * 3], x1 = pos[p * 3 + 1], x2 = pos[p * 3 + 2];
  float uu[16], vv[16];
#pragma unroll
  for (int m = 0; m < 16; ++m) {
    int f = fq * 16 + m;
    float wt0 = wAs[f], wt1 = wAs[64 + f], wt2 = wAs[128 + f];
    float wb0 = wAs[192 + f], wb1 = wAs[256 + f], wb2 = wAs[320 + f];
    float uval = bs[f];
    uval = fmaf(x0, wt0 - wb0, uval);
    uval = fmaf(x1, wt1 - wb1, uval);
    uval = fmaf(x2, wt2 - wb2, uval);
    uu[m] = uval;
    vv[m] = fmaf(x2, wb2, fmaf(x1, wb1, x0 * wb0));
  }
#pragma unroll
  for (int m = 0; m < 16; ++m)
    ut[((size_t)b * 64 + fq * 16 + m) * 2048 + nloc] = uu[m];
#pragma unroll
  for (int it = 0; it < 4; ++it)
    *(float4*)(v + (size_t)p * 64 + fq * 16 + it * 4) = *(const float4*)(vv + it * 4);
}

// ---------------- Kernel 2: EdgeConv1 layers 2/3 as 4x4-blocked GEMM ----------------
__global__ __launch_bounds__(256) void k_edge1(
    const int* __restrict__ idx1, const float* __restrict__ ut,
    const float* __restrict__ v,
    const float* __restrict__ s1a, const float* __restrict__ h1a,
    const float* __restrict__ w1b, const float* __restrict__ b1b,
    const float* __restrict__ s1b, const float* __restrict__ h1b,
    const float* __restrict__ w1c, const float* __restrict__ b1c,
    const float* __restrict__ s1c, const float* __restrict__ h1c,
    __bf16* __restrict__ xh, __bf16* __restrict__ xl,
    float* __restrict__ sqo, __bf16* __restrict__ xb) {
  __shared__ __align__(16) float h1t[64 * 68];
  __shared__ __align__(16) float h2t[64 * 68];
  __shared__ __align__(16) float wB[4096], wC[4096];
  __shared__ float cA[128], cB[192], cC[192];
  __shared__ float red[64 * 17];
  int tid = threadIdx.x;
  for (int u = tid; u < 4096; u += 256) { wB[u] = w1b[u]; wC[u] = w1c[u]; }
  if (tid < 64) {
    cA[tid] = s1a[tid]; cA[64 + tid] = h1a[tid];
    cB[tid] = b1b[tid]; cB[64 + tid] = s1b[tid]; cB[128 + tid] = h1b[tid];
    cC[tid] = b1c[tid]; cC[64 + tid] = s1c[tid]; cC[128 + tid] = h1c[tid];
  }
  int p0 = blockIdx.x * 64;
  int b = p0 >> 11, nloc0 = p0 & 2047;
  size_t bb = (size_t)b * 2048;
  int e = tid & 63, fq = tid >> 6;
  int cg = tid >> 4, pg = tid & 15;
  float amax[4][4];
#pragma unroll
  for (int i = 0; i < 4; ++i)
#pragma unroll
    for (int j = 0; j < 4; ++j) amax[i][j] = -3.4e38f;
  __syncthreads();
  for (int k = 0; k < 5; ++k) {
    {
      int j = idx1[(p0 + e) * 5 + k];
      const float* vrow = v + (bb + j) * 64 + fq * 16;
#pragma unroll
      for (int it = 0; it < 4; ++it) {
        float4 vv = *(const float4*)(vrow + it * 4);
        float vr[4] = {vv.x, vv.y, vv.z, vv.w};
#pragma unroll
        for (int m = 0; m < 4; ++m) {
          int f = fq * 16 + it * 4 + m;
          float uval = ut[((size_t)b * 64 + f) * 2048 + nloc0 + e];
          h1t[f * 68 + e] = relu_(uval + vr[m]) * cA[f] + cA[64 + f];
        }
      }
    }
    __syncthreads();
    {
      float acc[4][4] = {{0, 0, 0, 0}, {0, 0, 0, 0}, {0, 0, 0, 0}, {0, 0, 0, 0}};
#pragma unroll 4
      for (int f = 0; f < 64; ++f) {
        float4 av = *(const float4*)(h1t + f * 68 + pg * 4);
        float4 wv = *(const float4*)(wB + f * 64 + cg * 4);
        float a[4] = {av.x, av.y, av.z, av.w};
        float w[4] = {wv.x, wv.y, wv.z, wv.w};
#pragma unroll
        for (int ii = 0; ii < 4; ++ii)
#pragma unroll
          for (int jj = 0; jj < 4; ++jj)
            acc[ii][jj] = fmaf(a[ii], w[jj], acc[ii][jj]);
      }
#pragma unroll
      for (int jj = 0; jj < 4; ++jj) {
        int c = cg * 4 + jj;
        float bv = cB[c], sv = cB[64 + c], hv = cB[128 + c];
#pragma unroll
        for (int ii = 0; ii < 4; ++ii)
          h2t[c * 68 + pg * 4 + ii] = relu_(acc[ii][jj] + bv) * sv + hv;
      }
    }
    __syncthreads();
    {
      float acc[4][4] = {{0, 0, 0, 0}, {0, 0, 0, 0}, {0, 0, 0, 0}, {0, 0, 0, 0}};
#pragma unroll 4
      for (int f = 0; f < 64; ++f) {
        float4 av = *(const float4*)(h2t + f * 68 + pg * 4);
        float4 wv = *(const float4*)(wC + f * 64 + cg * 4);
        float a[4] = {av.x, av.y, av.z, av.w};
        float w[4] = {wv.x, wv.y, wv.z, wv.w};
#pragma unroll
        for (int ii = 0; ii < 4; ++ii)
#pragma unroll
          for (int jj = 0; jj < 4; ++jj)
            acc[ii][jj] = fmaf(a[ii], w[jj], acc[ii][jj]);
      }
#pragma unroll
      for (int ii = 0; ii < 4; ++ii)
#pragma unroll
        for (int jj = 0; jj < 4; ++jj)
          amax[ii][jj] = fmaxf(amax[ii][jj], acc[ii][jj]);
    }
    __syncthreads();
  }
#pragma unroll
  for (int ii = 0; ii < 4; ++ii) {
    int n = p0 + pg * 4 + ii;
    float sqp = 0.f;
    __bf16 oh[4], ol[4], ob[4];
#pragma unroll
    for (int jj = 0; jj < 4; ++jj) {
      int c = cg * 4 + jj;
      float val = relu_(amax[ii][jj] + cC[c]) * cC[64 + c] + cC[128 + c];
      sqp = fmaf(val, val, sqp);
      __bf16 h = (__bf16)val;
      oh[jj] = h;
      ol[jj] = (__bf16)(val - (float)h);
      ob[jj] = h;
    }
    *(uint2*)(xh + (size_t)n * 64 + cg * 4) = *(const uint2*)oh;
    *(uint2*)(xl + (size_t)n * 64 + cg * 4) = *(const uint2*)ol;
    *(uint2*)(xb + (size_t)n * 192 + cg * 4) = *(const uint2*)ob;
    red[(pg * 4 + ii) * 17 + cg] = sqp;
  }
  __syncthreads();
  if (tid < 64) {
    float s = 0.f;
#pragma unroll
    for (int g = 0; g < 16; ++g) s += red[tid * 17 + g];
    sqo[p0 + tid] = s;
  }
}

// ---------------- Kernel 3: kNN on x1 via MFMA hi/lo (R6-measured best config) ----------------
__global__ __launch_bounds__(256) void k_knn2(const __bf16* __restrict__ xh,
                                              const __bf16* __restrict__ xl,
                                              const float* __restrict__ sq,
                                              int* __restrict__ idx2) {
  __shared__ __align__(16) __bf16 Bh[64 * 72];
  __shared__ __align__(16) __bf16 Bl[64 * 72];
  __shared__ float sqs[2048];
  int tid = threadIdx.x;
  int w = tid >> 6, lane = tid & 63;
  int quad = lane >> 4, lm = lane & 15;
  int b = blockIdx.x >> 5, qc = blockIdx.x & 31;
  int q0 = qc * 64;
  size_t bb = (size_t)b * 2048;
  for (int u = tid; u < 512; u += 256)
    *(float4*)(sqs + u * 4) = *(const float4*)(sq + bb + u * 4);
  const __bf16* qh = xh + (bb + q0 + w * 16 + lm) * 64 + quad * 8;
  const __bf16* ql = xl + (bb + q0 + w * 16 + lm) * 64 + quad * 8;
  bf16x8 Ah0 = *(const bf16x8*)(qh);
  bf16x8 Ah1 = *(const bf16x8*)(qh + 32);
  bf16x8 Al0 = *(const bf16x8*)(ql);
  bf16x8 Al1 = *(const bf16x8*)(ql + 32);
  __syncthreads();
  float qsq[4];
#pragma unroll
  for (int r = 0; r < 4; ++r) qsq[r] = sqs[q0 + w * 16 + quad * 4 + r];
  float bd[4][5];
  int bi[4][5];
#pragma unroll
  for (int r = 0; r < 4; ++r)
#pragma unroll
    for (int k = 0; k < 5; ++k) { bd[r][k] = 1e30f; bi[r][k] = 0; }
  for (int ct = 0; ct < 32; ++ct) {
#pragma unroll
    for (int pass = 0; pass < 2; ++pass) {
      int unit = pass * 256 + tid;
      int n = unit >> 3, cc = unit & 7;
      const __bf16* gsrc = xh + (bb + ct * 64 + n) * 64 + cc * 8;
      const __bf16* gsrl = xl + (bb + ct * 64 + n) * 64 + cc * 8;
      *(uint4*)(Bh + n * 72 + cc * 8) = *(const uint4*)gsrc;
      *(uint4*)(Bl + n * 72 + cc * 8) = *(const uint4*)gsrl;
    }
    __syncthreads();
#pragma unroll
    for (int nt = 0; nt < 4; ++nt) {
      const __bf16* bph = Bh + (nt * 16 + lm) * 72 + quad * 8;
      const __bf16* bpl = Bl + (nt * 16 + lm) * 72 + quad * 8;
      bf16x8 Bh0 = *(const bf16x8*)(bph);
      bf16x8 Bh1 = *(const bf16x8*)(bph + 32);
      bf16x8 Bl0 = *(const bf16x8*)(bpl);
      bf16x8 Bl1 = *(const bf16x8*)(bpl + 32);
      f32x4 acc = {0.f, 0.f, 0.f, 0.f};
      acc = __builtin_amdgcn_mfma_f32_16x16x32_bf16(Ah0, Bh0, acc, 0, 0, 0);
      acc = __builtin_amdgcn_mfma_f32_16x16x32_bf16(Ah1, Bh1, acc, 0, 0, 0);
      acc = __builtin_amdgcn_mfma_f32_16x16x32_bf16(Ah0, Bl0, acc, 0, 0, 0);
      acc = __builtin_amdgcn_mfma_f32_16x16x32_bf16(Ah1, Bl1, acc, 0, 0, 0);
      acc = __builtin_amdgcn_mfma_f32_16x16x32_bf16(Al0, Bh0, acc, 0, 0, 0);
      acc = __builtin_amdgcn_mfma_f32_16x16x32_bf16(Al1, Bh1, acc, 0, 0, 0);
      int cid = ct * 64 + nt * 16 + lm;
      float csq = sqs[cid];
#pragma unroll
      for (int r = 0; r < 4; ++r) {
        float d = (qsq[r] + csq) - 2.0f * acc[r];
        knn_insert(bd[r], bi[r], d, cid);
      }
    }
    __syncthreads();
  }
  for (int m = 1; m <= 8; m <<= 1) {
#pragma unroll
    for (int r = 0; r < 4; ++r) {
      float od[5]; int oi[5];
#pragma unroll
      for (int k = 0; k < 5; ++k) {
        od[k] = __shfl_xor(bd[r][k], m);
        oi[k] = __shfl_xor(bi[r][k], m);
      }
#pragma unroll
      for (int k = 0; k < 5; ++k) knn_insert(bd[r], bi[r], od[k], oi[k]);
    }
  }
  if (lm == 0) {
#pragma unroll
    for (int r = 0; r < 4; ++r) {
      int qi = q0 + w * 16 + quad * 4 + r;
      int* op = idx2 + (bb + qi) * 5;
#pragma unroll
      for (int k = 0; k < 5; ++k) op[k] = bi[r][k];
    }
  }
}

// ---------------- Kernel 4w: split w2 into P/Q weights, bf16 hi/lo, MFMA-B frag order ----------------
// layout: [nb=16][ks=2][lane=64][j=8]; nb<8 -> P cols (Wtop-Wbot), nb>=8 -> Q cols (Wbot)
__global__ __launch_bounds__(256) void k_wprep(const float* __restrict__ w2,
                                               __bf16* __restrict__ wph,
                                               __bf16* __restrict__ wpl) {
  int t = blockIdx.x * 256 + threadIdx.x;  // 0..2047
  int nb = t >> 7;
  int rem = t & 127;
  int ks = rem >> 6, lane = rem & 63;
  int k0 = ks * 32 + (lane >> 4) * 8;
  int col16 = lane & 15;
  __bf16 oh[8], ol[8];
#pragma unroll
  for (int j = 0; j < 8; ++j) {
    int k = k0 + j;
    float val;
    if (nb < 8) {
      int c = nb * 16 + col16;
      val = w2[k * 128 + c] - w2[(64 + k) * 128 + c];
    } else {
      int c = (nb - 8) * 16 + col16;
      val = w2[(64 + k) * 128 + c];
    }
    __bf16 h = (__bf16)val;
    oh[j] = h;
    ol[j] = (__bf16)(val - (float)h);
  }
  *(uint4*)(wph + (size_t)t * 8) = *(const uint4*)oh;
  *(uint4*)(wpl + (size_t)t * 8) = *(const uint4*)ol;
}

// ---------------- Kernel 4a: P = x1@(Wtop-Wbot), Q = x1@Wbot via hi/lo MFMA ----------------
// grid 1024 (64 points/block), block 256 = 4 waves (16 points each); W staged to LDS once
__global__ __launch_bounds__(256) void k_pq_mfma(const __bf16* __restrict__ xh,
                                                 const __bf16* __restrict__ xl,
                                                 const __bf16* __restrict__ wph,
                                                 const __bf16* __restrict__ wpl,
                                                 __bf16* __restrict__ Pb,
                                                 __bf16* __restrict__ Qb) {
  __shared__ __align__(16) __bf16 Wh[16384];
  __shared__ __align__(16) __bf16 Wl[16384];
  int tid = threadIdx.x;
  int w = tid >> 6, lane = tid & 63;
  int quad = lane >> 4, lm = lane & 15;
  int n0 = blockIdx.x * 64;
#pragma unroll
  for (int it = 0; it < 8; ++it) {
    int unit = it * 256 + tid;  // 0..2047
    *(uint4*)(Wh + (size_t)unit * 8) = *(const uint4*)(wph + (size_t)unit * 8);
    *(uint4*)(Wl + (size_t)unit * 8) = *(const uint4*)(wpl + (size_t)unit * 8);
  }
  // A-frags: points n0 + w*16 + lm
  const __bf16* ah = xh + (size_t)(n0 + w * 16 + lm) * 64 + quad * 8;
  const __bf16* al = xl + (size_t)(n0 + w * 16 + lm) * 64 + quad * 8;
  bf16x8 Ah0 = *(const bf16x8*)(ah);
  bf16x8 Ah1 = *(const bf16x8*)(ah + 32);
  bf16x8 Al0 = *(const bf16x8*)(al);
  bf16x8 Al1 = *(const bf16x8*)(al + 32);
  __syncthreads();
  f32x4 acc[16];
#pragma unroll
  for (int nb = 0; nb < 16; ++nb) acc[nb] = (f32x4){0.f, 0.f, 0.f, 0.f};
#pragma unroll 4
  for (int nb = 0; nb < 16; ++nb) {
    const __bf16* bh0 = Wh + ((size_t)(nb * 2 + 0) * 64 + lane) * 8;
    const __bf16* bh1 = Wh + ((size_t)(nb * 2 + 1) * 64 + lane) * 8;
    const __bf16* bl0 = Wl + ((size_t)(nb * 2 + 0) * 64 + lane) * 8;
    const __bf16* bl1 = Wl + ((size_t)(nb * 2 + 1) * 64 + lane) * 8;
    bf16x8 Bh0 = *(const bf16x8*)bh0;
    bf16x8 Bh1 = *(const bf16x8*)bh1;
    bf16x8 Bl0 = *(const bf16x8*)bl0;
    bf16x8 Bl1 = *(const bf16x8*)bl1;
    acc[nb] = __builtin_amdgcn_mfma_f32_16x16x32_bf16(Ah0, Bh0, acc[nb], 0, 0, 0);
    acc[nb] = __builtin_amdgcn_mfma_f32_16x16x32_bf16(Ah1, Bh1, acc[nb], 0, 0, 0);
    acc[nb] = __builtin_amdgcn_mfma_f32_16x16x32_bf16(Ah0, Bl0, acc[nb], 0, 0, 0);
    acc[nb] = __builtin_amdgcn_mfma_f32_16x16x32_bf16(Ah1, Bl1, acc[nb], 0, 0, 0);
    acc[nb] = __builtin_amdgcn_mfma_f32_16x16x32_bf16(Al0, Bh0, acc[nb], 0, 0, 0);
    acc[nb] = __builtin_amdgcn_mfma_f32_16x16x32_bf16(Al1, Bh1, acc[nb], 0, 0, 0);
  }
  // C layout: row = quad*4 + r (point), col = lm (within nb's 16-col block)
#pragma unroll
  for (int nb = 0; nb < 16; ++nb) {
    bool isP = (nb < 8);
    __bf16* base = isP ? Pb : Qb;
    int col = (isP ? nb : nb - 8) * 16 + lm;
#pragma unroll
    for (int r = 0; r < 4; ++r) {
      int n = n0 + w * 16 + quad * 4 + r;
      base[(size_t)n * 128 + col] = (__bf16)acc[nb][r];
    }
  }
}

// ---------------- Kernel 4p: repack wl -> MFMA-B frag order bf16 ----------------
__global__ __launch_bounds__(256) void k_prep(const float* __restrict__ wl,
                                              __bf16* __restrict__ wlb) {
  int t = blockIdx.x * 256 + threadIdx.x;
  int nt = t / 3072;
  int rem = t - nt * 3072;
  int ks = rem / 512;
  int rem2 = rem - ks * 512;
  int nb = rem2 >> 6, lane = rem2 & 63;
  int k0 = ks * 32 + (lane >> 4) * 8;
  int n = nt * 128 + nb * 16 + (lane & 15);
  __bf16 o[8];
#pragma unroll
  for (int j = 0; j < 8; ++j) o[j] = (__bf16)wl[(k0 + j) * 1024 + n];
  *(uint4*)(wlb + (size_t)t * 8) = *(const uint4*)o;
}

// ---------------- Kernel 4b: gather-max + activation -> xb bf16 [n][64:192] ----------------
__global__ __launch_bounds__(256) void k_gmax(const __bf16* __restrict__ Pb,
                                              const __bf16* __restrict__ Qb,
                                              const int* __restrict__ idx2,
                                              const float* __restrict__ b2,
                                              const float* __restrict__ s2,
                                              const float* __restrict__ h2v,
                                              __bf16* __restrict__ xb) {
  int tid = threadIdx.x;
  int c = tid & 127, p = tid >> 7;
  int n = blockIdx.x * 2 + p;
  int b = n >> 11;
  const int* ip = idx2 + n * 5;
  float m = -3.4e38f;
#pragma unroll
  for (int k = 0; k < 5; ++k) {
    int j = ip[k];
    m = fmaxf(m, (float)Qb[((size_t)(b * 2048 + j)) * 128 + c]);
  }
  float v = (float)Pb[(size_t)n * 128 + c] + m + b2[c];
  xb[(size_t)n * 192 + 64 + c] = (__bf16)(relu_(v) * s2[c] + h2v[c]);
}

// ---------------- Kernel 5: bf16 MFMA GEMM fused point-max ----------------
__global__ __launch_bounds__(256) void k_linl_mfma(const __bf16* __restrict__ xb,
                                                   const __bf16* __restrict__ wlb,
                                                   float* __restrict__ pool_part) {
  __shared__ __align__(16) __bf16 Al[4096];
  __shared__ __align__(16) __bf16 Bl[4096];
  __shared__ float red[256];
  int tid = threadIdx.x;
  int w = tid >> 6, lane = tid & 63;
  int mt = blockIdx.x >> 3, nt = blockIdx.x & 7;
  int n0 = mt << 7;
  int wm = w & 1, wn = w >> 1;
  int quad = lane >> 4, lm = lane & 15;
  f32x4 acc[4][4];
#pragma unroll
  for (int i = 0; i < 4; ++i)
#pragma unroll
    for (int j = 0; j < 4; ++j) acc[i][j] = (f32x4){0.f, 0.f, 0.f, 0.f};
  for (int ks = 0; ks < 6; ++ks) {
    __syncthreads();
#pragma unroll
    for (int u = 0; u < 2; ++u) {
      int mb = w * 2 + u;
      const uint4* ga = (const uint4*)(xb + (size_t)(n0 + mb * 16 + lm) * 192 + ks * 32 + quad * 8);
      *(uint4*)(Al + (mb * 64 + lane) * 8) = *ga;
      const uint4* gb = (const uint4*)(wlb + ((((size_t)nt * 6 + ks) * 8 + mb) * 64 + lane) * 8);
      *(uint4*)(Bl + (mb * 64 + lane) * 8) = *gb;
    }
    __syncthreads();
    bf16x8 af[4], bfr[4];
#pragma unroll
    for (int i = 0; i < 4; ++i) {
      af[i] = *(const bf16x8*)(Al + ((wm * 4 + i) * 64 + lane) * 8);
      bfr[i] = *(const bf16x8*)(Bl + ((wn * 4 + i) * 64 + lane) * 8);
    }
#pragma unroll
    for (int i = 0; i < 4; ++i)
#pragma unroll
      for (int j = 0; j < 4; ++j)
        acc[i][j] = __builtin_amdgcn_mfma_f32_16x16x32_bf16(af[i], bfr[j], acc[i][j], 0, 0, 0);
  }
  float pm[4];
#pragma unroll
  for (int j = 0; j < 4; ++j) {
    float m = -3.4e38f;
#pragma unroll
    for (int i = 0; i < 4; ++i)
#pragma unroll
      for (int r = 0; r < 4; ++r) m = fmaxf(m, acc[i][j][r]);
    m = fmaxf(m, __shfl_xor(m, 16));
    m = fmaxf(m, __shfl_xor(m, 32));
    pm[j] = m;
  }
  __syncthreads();
  if (quad == 0) {
#pragma unroll
    for (int j = 0; j < 4; ++j) red[w * 64 + j * 16 + lm] = pm[j];
  }
  __syncthreads();
  if (tid < 128) {
    int wn2 = tid >> 6, cc = tid & 63;
    float v = fmaxf(red[(wn2 * 2) * 64 + cc], red[(wn2 * 2 + 1) * 64 + cc]);
    pool_part[(size_t)mt * 1024 + nt * 128 + wn2 * 64 + cc] = v;
  }
}

// ---------------- Kernel 6: head MLP ----------------
__global__ __launch_bounds__(256) void k_head(
    const float* __restrict__ pool_part, const float* __restrict__ bl,
    const float* __restrict__ sl, const float* __restrict__ hl,
    const float* __restrict__ wm1, const float* __restrict__ bm1,
    const float* __restrict__ sm1, const float* __restrict__ hm1,
    const float* __restrict__ wm2, const float* __restrict__ bm2,
    const float* __restrict__ sm2, const float* __restrict__ hm2,
    const float* __restrict__ wout, const float* __restrict__ bout,
    float* __restrict__ out) {
  __shared__ float p_s[1024], h1_s[512], h2_s[256];
  int b = blockIdx.x, tid = threadIdx.x;
  for (int c = tid; c < 1024; c += 256) {
    float m = -3.4e38f;
#pragma unroll 4
    for (int t = 0; t < 16; ++t)
      m = fmaxf(m, pool_part[(size_t)(b * 16 + t) * 1024 + c]);
    p_s[c] = relu_(m + bl[c]) * sl[c] + hl[c];
  }
  __syncthreads();
  for (int c = tid; c < 512; c += 256) {
    float a0 = 0, a1 = 0, a2 = 0, a3 = 0;
    for (int f = 0; f < 1024; f += 4) {
      a0 = fmaf(p_s[f], wm1[f * 512 + c], a0);
      a1 = fmaf(p_s[f + 1], wm1[(f + 1) * 512 + c], a1);
      a2 = fmaf(p_s[f + 2], wm1[(f + 2) * 512 + c], a2);
      a3 = fmaf(p_s[f + 3], wm1[(f + 3) * 512 + c], a3);
    }
    float a = (a0 + a1) + (a2 + a3);
    h1_s[c] = relu_(a + bm1[c]) * sm1[c] + hm1[c];
  }
  __syncthreads();
  if (tid < 256) {
    float a0 = 0, a1 = 0, a2 = 0, a3 = 0;
    for (int f = 0; f < 512; f += 4) {
      a0 = fmaf(h1_s[f], wm2[f * 256 + tid], a0);
      a1 = fmaf(h1_s[f + 1], wm2[(f + 1) * 256 + tid], a1);
      a2 = fmaf(h1_s[f + 2], wm2[(f + 2) * 256 + tid], a2);
      a3 = fmaf(h1_s[f + 3], wm2[(f + 3) * 256 + tid], a3);
    }
    float a = (a0 + a1) + (a2 + a3);
    h2_s[tid] = relu_(a + bm2[tid]) * sm2[tid] + hm2[tid];
  }
  __syncthreads();
  if (tid < 2) {
    float a0 = 0, a1 = 0;
    for (int f = 0; f < 256; f += 2) {
      a0 = fmaf(h2_s[f], wout[f * 2 + tid], a0);
      a1 = fmaf(h2_s[f + 1], wout[(f + 1) * 2 + tid], a1);
    }
    out[b * 2 + tid] = (a0 + a1) + bout[tid];
  }
}

extern "C" void kernel_launch(void* const* d_in, const int* in_sizes, int n_in,
                              void* d_out, int out_size, void* d_ws, size_t ws_size,
                              hipStream_t stream) {
  const float* pos = (const float*)d_in[0];
  const float* w1a = (const float*)d_in[1];
  const float* b1a = (const float*)d_in[2];
  const float* s1a = (const float*)d_in[3];
  const float* h1a = (const float*)d_in[4];
  const float* w1b = (const float*)d_in[5];
  const float* b1b = (const float*)d_in[6];
  const float* s1b = (const float*)d_in[7];
  const float* h1b = (const float*)d_in[8];
  const float* w1c = (const float*)d_in[9];
  const float* b1c = (const float*)d_in[10];
  const float* s1c = (const float*)d_in[11];
  const float* h1c = (const float*)d_in[12];
  const float* w2 = (const float*)d_in[13];
  const float* b2 = (const float*)d_in[14];
  const float* s2 = (const float*)d_in[15];
  const float* h2 = (const float*)d_in[16];
  const float* wl = (const float*)d_in[17];
  const float* bl = (const float*)d_in[18];
  const float* sl = (const float*)d_in[19];
  const float* hl = (const float*)d_in[20];
  const float* wm1 = (const float*)d_in[21];
  const float* bm1 = (const float*)d_in[22];
  const float* sm1 = (const float*)d_in[23];
  const float* hm1 = (const float*)d_in[24];
  const float* wm2 = (const float*)d_in[25];
  const float* bm2 = (const float*)d_in[26];
  const float* sm2 = (const float*)d_in[27];
  const float* hm2 = (const float*)d_in[28];
  const float* wout = (const float*)d_in[29];
  const float* bout = (const float*)d_in[30];
  float* out = (float*)d_out;

  // workspace (float units): xh | xl | Pb | Qb | xb | idx | sq | wph | wpl (~77 MB)
  float* base = (float*)d_ws;
  __bf16* xh = (__bf16*)base;                   // 4,194,304 bf16
  __bf16* xl = (__bf16*)(base + 2097152);       // 4,194,304 bf16
  float* PbF = base + 4194304;
  float* QbF = PbF + 4194304;
  float* xbF = QbF + 4194304;
  int* idx = (int*)(xbF + 6291456);
  float* sq = (float*)(idx + 327680);
  __bf16* wph = (__bf16*)(sq + 65536);          // 16,384 bf16
  __bf16* wpl = (__bf16*)(sq + 65536 + 8192);   // 16,384 bf16
  __bf16* Pb = (__bf16*)PbF;
  __bf16* Qb = (__bf16*)QbF;
  __bf16* xb = (__bf16*)xbF;
  float* ut = PbF;                               // alias (dead until k_pq)
  float* vv = QbF;
  __bf16* wlb = (__bf16*)base;                   // alias xh (dead after k_pq)
  float* pool_part = base + 131072;

  k_knn1<<<2048, 256, 0, stream>>>(pos, idx);
  k_uv<<<1024, 256, 0, stream>>>(pos, w1a, b1a, ut, vv);
  k_edge1<<<1024, 256, 0, stream>>>(idx, ut, vv, s1a, h1a, w1b, b1b, s1b, h1b,
                                    w1c, b1c, s1c, h1c, xh, xl, sq, xb);
  k_knn2<<<1024, 256, 0, stream>>>(xh, xl, sq, idx);
  k_wprep<<<8, 256, 0, stream>>>(w2, wph, wpl);
  k_pq_mfma<<<1024, 256, 0, stream>>>(xh, xl, wph, wpl, Pb, Qb);
  k_prep<<<96, 256, 0, stream>>>(wl, wlb);
  k_gmax<<<32768, 256, 0, stream>>>(Pb, Qb, idx, b2, s2, h2, xb);
  k_linl_mfma<<<4096, 256, 0, stream>>>(xb, wlb, pool_part);
  k_head<<<32, 256, 0, stream>>>(pool_part, bl, sl, hl, wm1, bm1, sm1, hm1, wm2,
                                 bm2, sm2, hm2, wout, bout, out);
}

// Round 12
// 635.259 us; speedup vs baseline: 1.2609x; 1.0503x over previous
//
#include <hip/hip_runtime.h>

#define DEV __device__ __forceinline__
DEV float relu_(float x) { return fmaxf(x, 0.0f); }

typedef __attribute__((ext_vector_type(4))) float f32x4;
typedef __attribute__((ext_vector_type(8))) __bf16 bf16x8;

DEV unsigned short bfbits(__bf16 b) { union { unsigned short s; __bf16 b; } x; x.b = b; return x.s; }
DEV __bf16 bffrom(unsigned short s) { union { unsigned short s; __bf16 b; } x; x.s = s; return x.b; }

// branchy top-5 insert (R6-measured best for knn2's wave-coherent stream)
DEV void knn_insert(float (&bd)[5], int (&bi)[5], float d, int j) {
  if (d >= bd[4]) return;
  bd[4] = d; bi[4] = j;
#pragma unroll
  for (int p = 4; p > 0; --p) {
    if (bd[p] < bd[p - 1]) {
      float td = bd[p]; bd[p] = bd[p - 1]; bd[p - 1] = td;
      int ti = bi[p]; bi[p] = bi[p - 1]; bi[p - 1] = ti;
    }
  }
}

// branchless EXACT top-5 insert (used in knn1)
DEV void knn_insert_bl(float (&bd)[5], int (&bi)[5], float d, int j) {
#pragma unroll
  for (int p = 0; p < 5; ++p) {
    bool lt = d < bd[p];
    float nd = lt ? d : bd[p];
    float cd = lt ? bd[p] : d;
    int ni = lt ? j : bi[p];
    int ci = lt ? bi[p] : j;
    bd[p] = nd; d = cd;
    bi[p] = ni; j = ci;
  }
}

// ---------------- Kernel 1: kNN on pos (F=3), 8-way candidate split ----------------
__global__ __launch_bounds__(256) void k_knn1(const float* __restrict__ pos,
                                              int* __restrict__ idx1) {
  __shared__ float ps[6144];
  __shared__ float sqs[2048];
  __shared__ float md[640];
  __shared__ int mi[640];
  int tid = threadIdx.x;
  int b = blockIdx.x >> 6, qc = blockIdx.x & 63;
  const float* src = pos + b * 6144;
  for (int u = tid; u < 6144; u += 256) ps[u] = src[u];
  __syncthreads();
  for (int u = tid; u < 2048; u += 256) {
    float x = ps[u * 3], y = ps[u * 3 + 1], z = ps[u * 3 + 2];
    sqs[u] = fmaf(z, z, fmaf(y, y, x * x));
  }
  __syncthreads();
  int q = tid & 31, sub = tid >> 5;
  int qi = qc * 32 + q;
  float qx = ps[qi * 3], qy = ps[qi * 3 + 1], qz = ps[qi * 3 + 2];
  float qsq = sqs[qi];
  float bd[5] = {1e30f, 1e30f, 1e30f, 1e30f, 1e30f};
  int bi[5] = {0, 0, 0, 0, 0};
  int j0 = sub * 256;
  for (int j = j0; j < j0 + 256; ++j) {
    float px = ps[j * 3], py = ps[j * 3 + 1], pz = ps[j * 3 + 2];
    float dot = fmaf(qz, pz, fmaf(qy, py, qx * px));
    float d = (qsq + sqs[j]) - 2.0f * dot;
    knn_insert_bl(bd, bi, d, j);
  }
  for (int half = 4; half >= 1; half >>= 1) {
    __syncthreads();
    if (sub >= half && sub < 2 * half) {
      int slot = (q * 4 + (sub - half)) * 5;
#pragma unroll
      for (int k = 0; k < 5; ++k) { md[slot + k] = bd[k]; mi[slot + k] = bi[k]; }
    }
    __syncthreads();
    if (sub < half) {
      int slot = (q * 4 + sub) * 5;
#pragma unroll
      for (int k = 0; k < 5; ++k) knn_insert_bl(bd, bi, md[slot + k], mi[slot + k]);
    }
  }
  if (sub == 0) {
    int* op = idx1 + (b * 2048 + qi) * 5;
#pragma unroll
    for (int k = 0; k < 5; ++k) op[k] = bi[k];
  }
}

// ---------------- Kernel 1b: per-point u/v, BOTH row-major [n][64] ----------------
__global__ __launch_bounds__(256) void k_uv(const float* __restrict__ pos,
                                            const float* __restrict__ w1a,
                                            const float* __restrict__ b1a,
                                            float* __restrict__ uR,
                                            float* __restrict__ vR) {
  __shared__ float wAs[384];
  __shared__ float bs[64];
  int tid = threadIdx.x;
  for (int u = tid; u < 384; u += 256) wAs[u] = w1a[u];
  if (tid < 64) bs[tid] = b1a[tid];
  __syncthreads();
  int lane = tid & 63, fq = tid >> 6;
  int p = blockIdx.x * 64 + lane;
  float x0 = pos[p * 3], x1 = pos[p * 3 + 1], x2 = pos[p * 3 + 2];
  float uu[16], vv[16];
#pragma unroll
  for (int m = 0; m < 16; ++m) {
    int f = fq * 16 + m;
    float wt0 = wAs[f], wt1 = wAs[64 + f], wt2 = wAs[128 + f];
    float wb0 = wAs[192 + f], wb1 = wAs[256 + f], wb2 = wAs[320 + f];
    float uval = bs[f];
    uval = fmaf(x0, wt0 - wb0, uval);
    uval = fmaf(x1, wt1 - wb1, uval);
    uval = fmaf(x2, wt2 - wb2, uval);
    uu[m] = uval;
    vv[m] = fmaf(x2, wb2, fmaf(x1, wb1, x0 * wb0));
  }
#pragma unroll
  for (int it = 0; it < 4; ++it) {
    *(float4*)(uR + (size_t)p * 64 + fq * 16 + it * 4) = *(const float4*)(uu + it * 4);
    *(float4*)(vR + (size_t)p * 64 + fq * 16 + it * 4) = *(const float4*)(vv + it * 4);
  }
}

// ---------------- Kernel 1c: W1b/W1c -> bf16 hi/lo MFMA-B frag order ----------------
// layout: [m(0=B,1=C)][nb=4][s=2][lane=64][j=8]
__global__ __launch_bounds__(256) void k_wprep2(const float* __restrict__ w1b,
                                                const float* __restrict__ w1c,
                                                __bf16* __restrict__ wfh,
                                                __bf16* __restrict__ wfl) {
  int t = blockIdx.x * 256 + threadIdx.x;  // 0..1023
  int m = t >> 9;
  int rem = t & 511;
  int nb = rem >> 7;
  int rem2 = rem & 127;
  int s = rem2 >> 6, lane = rem2 & 63;
  int k0 = s * 32 + (lane >> 4) * 8;
  int c = nb * 16 + (lane & 15);
  const float* W = m ? w1c : w1b;
  __bf16 oh[8], ol[8];
#pragma unroll
  for (int j = 0; j < 8; ++j) {
    float val = W[(k0 + j) * 64 + c];
    __bf16 h = (__bf16)val;
    oh[j] = h;
    ol[j] = (__bf16)(val - (float)h);
  }
  size_t off = (size_t)m * 4096 + ((size_t)((nb * 2 + s) * 64 + lane)) * 8;
  *(uint4*)(wfh + off) = *(const uint4*)oh;
  *(uint4*)(wfl + off) = *(const uint4*)ol;
}

// ---------------- Kernel 2: EdgeConv1 layers 2/3 via hi/lo MFMA, barrier-free k-loop ----------------
// grid 1024 (64 points/block), block 256 = 4 waves x 16 points; wave-private h2 LDS
__global__ __launch_bounds__(256) void k_edge1(
    const int* __restrict__ idx1, const float* __restrict__ uR,
    const float* __restrict__ vR,
    const float* __restrict__ s1a, const float* __restrict__ h1a,
    const float* __restrict__ b1b, const float* __restrict__ s1b,
    const float* __restrict__ h1b,
    const float* __restrict__ b1c, const float* __restrict__ s1c,
    const float* __restrict__ h1c,
    const __bf16* __restrict__ wfh, const __bf16* __restrict__ wfl,
    __bf16* __restrict__ xh, __bf16* __restrict__ xl,
    float* __restrict__ sqo, __bf16* __restrict__ xb) {
  __shared__ __align__(16) __bf16 Wh[8192], Wl[8192];     // [B|C] frag-ordered hi/lo
  __shared__ __align__(16) unsigned h2b[4 * 1088];        // per-wave [16e][68] hi|lo<<16
  int tid = threadIdx.x;
  int w = tid >> 6, lane = tid & 63;
  int quad = lane >> 4, lm = lane & 15;
#pragma unroll
  for (int it = 0; it < 4; ++it) {
    int u4 = it * 256 + tid;
    *(uint4*)(Wh + (size_t)u4 * 8) = *(const uint4*)(wfh + (size_t)u4 * 8);
    *(uint4*)(Wl + (size_t)u4 * 8) = *(const uint4*)(wfl + (size_t)u4 * 8);
  }
  int p0 = blockIdx.x * 64;
  int b = p0 >> 11;
  size_t bb = (size_t)b * 2048;
  int edge = p0 + w * 16 + lm;  // this lane's point i
  float sA[2][8], hA[2][8];
#pragma unroll
  for (int s = 0; s < 2; ++s)
#pragma unroll
    for (int j = 0; j < 8; ++j) {
      int k = s * 32 + quad * 8 + j;
      sA[s][j] = s1a[k]; hA[s][j] = h1a[k];
    }
  float bB[4], sB[4], hB[4], bC[4], sC[4], hC[4];
#pragma unroll
  for (int nb = 0; nb < 4; ++nb) {
    int c = nb * 16 + lm;
    bB[nb] = b1b[c]; sB[nb] = s1b[c]; hB[nb] = h1b[c];
    bC[nb] = b1c[c]; sC[nb] = s1c[c]; hC[nb] = h1c[c];
  }
  unsigned* h2w = h2b + w * 1088;
  f32x4 mmax[4];
#pragma unroll
  for (int nb = 0; nb < 4; ++nb)
    mmax[nb] = (f32x4){-3.4e38f, -3.4e38f, -3.4e38f, -3.4e38f};
  __syncthreads();  // weights staged (only barrier)
  const float* urow = uR + (size_t)edge * 64;
  for (int kk = 0; kk < 5; ++kk) {
    int jn = idx1[edge * 5 + kk];
    const float* vrow = vR + (bb + jn) * 64;
    // h1 A-frags in registers
    bf16x8 Ah[2], Al[2];
#pragma unroll
    for (int s = 0; s < 2; ++s) {
      int off = s * 32 + quad * 8;
      float4 u0 = *(const float4*)(urow + off);
      float4 u1 = *(const float4*)(urow + off + 4);
      float4 v0 = *(const float4*)(vrow + off);
      float4 v1 = *(const float4*)(vrow + off + 4);
      float uv[8] = {u0.x + v0.x, u0.y + v0.y, u0.z + v0.z, u0.w + v0.w,
                     u1.x + v1.x, u1.y + v1.y, u1.z + v1.z, u1.w + v1.w};
      __bf16 th[8], tl[8];
#pragma unroll
      for (int j = 0; j < 8; ++j) {
        float val = relu_(uv[j]) * sA[s][j] + hA[s][j];
        __bf16 hb = (__bf16)val;
        th[j] = hb;
        tl[j] = (__bf16)(val - (float)hb);
      }
      Ah[s] = *(const bf16x8*)th;
      Al[s] = *(const bf16x8*)tl;
    }
    // layer2: h2 = act(h1 @ W1b), write wave-private LDS (packed hi|lo)
#pragma unroll
    for (int nb = 0; nb < 4; ++nb) {
      bf16x8 Bh0 = *(const bf16x8*)(Wh + ((size_t)((nb * 2 + 0) * 64 + lane)) * 8);
      bf16x8 Bh1 = *(const bf16x8*)(Wh + ((size_t)((nb * 2 + 1) * 64 + lane)) * 8);
      bf16x8 Bl0 = *(const bf16x8*)(Wl + ((size_t)((nb * 2 + 0) * 64 + lane)) * 8);
      bf16x8 Bl1 = *(const bf16x8*)(Wl + ((size_t)((nb * 2 + 1) * 64 + lane)) * 8);
      f32x4 a2 = {0.f, 0.f, 0.f, 0.f};
      a2 = __builtin_amdgcn_mfma_f32_16x16x32_bf16(Ah[0], Bh0, a2, 0, 0, 0);
      a2 = __builtin_amdgcn_mfma_f32_16x16x32_bf16(Ah[1], Bh1, a2, 0, 0, 0);
      a2 = __builtin_amdgcn_mfma_f32_16x16x32_bf16(Ah[0], Bl0, a2, 0, 0, 0);
      a2 = __builtin_amdgcn_mfma_f32_16x16x32_bf16(Ah[1], Bl1, a2, 0, 0, 0);
      a2 = __builtin_amdgcn_mfma_f32_16x16x32_bf16(Al[0], Bh0, a2, 0, 0, 0);
      a2 = __builtin_amdgcn_mfma_f32_16x16x32_bf16(Al[1], Bh1, a2, 0, 0, 0);
#pragma unroll
      for (int r = 0; r < 4; ++r) {
        float vv2 = relu_(a2[r] + bB[nb]) * sB[nb] + hB[nb];
        __bf16 hb = (__bf16)vv2;
        __bf16 lb = (__bf16)(vv2 - (float)hb);
        h2w[(quad * 4 + r) * 68 + nb * 16 + lm] =
            (unsigned)bfbits(hb) | ((unsigned)bfbits(lb) << 16);
      }
    }
    // layer3 A-frags from wave-private LDS (intra-wave: no barrier needed)
    bf16x8 A3h[2], A3l[2];
#pragma unroll
    for (int s = 0; s < 2; ++s) {
      const unsigned* rp = h2w + lm * 68 + s * 32 + quad * 8;
      uint4 da = *(const uint4*)rp;
      uint4 db = *(const uint4*)(rp + 4);
      unsigned dw[8] = {da.x, da.y, da.z, da.w, db.x, db.y, db.z, db.w};
      __bf16 th[8], tl[8];
#pragma unroll
      for (int j = 0; j < 8; ++j) {
        th[j] = bffrom((unsigned short)(dw[j] & 0xFFFFu));
        tl[j] = bffrom((unsigned short)(dw[j] >> 16));
      }
      A3h[s] = *(const bf16x8*)th;
      A3l[s] = *(const bf16x8*)tl;
    }
    // layer3: pre-act accumulate, max over kk
#pragma unroll
    for (int nb = 0; nb < 4; ++nb) {
      bf16x8 Bh0 = *(const bf16x8*)(Wh + 4096 + ((size_t)((nb * 2 + 0) * 64 + lane)) * 8);
      bf16x8 Bh1 = *(const bf16x8*)(Wh + 4096 + ((size_t)((nb * 2 + 1) * 64 + lane)) * 8);
      bf16x8 Bl0 = *(const bf16x8*)(Wl + 4096 + ((size_t)((nb * 2 + 0) * 64 + lane)) * 8);
      bf16x8 Bl1 = *(const bf16x8*)(Wl + 4096 + ((size_t)((nb * 2 + 1) * 64 + lane)) * 8);
      f32x4 a3 = {0.f, 0.f, 0.f, 0.f};
      a3 = __builtin_amdgcn_mfma_f32_16x16x32_bf16(A3h[0], Bh0, a3, 0, 0, 0);
      a3 = __builtin_amdgcn_mfma_f32_16x16x32_bf16(A3h[1], Bh1, a3, 0, 0, 0);
      a3 = __builtin_amdgcn_mfma_f32_16x16x32_bf16(A3h[0], Bl0, a3, 0, 0, 0);
      a3 = __builtin_amdgcn_mfma_f32_16x16x32_bf16(A3h[1], Bl1, a3, 0, 0, 0);
      a3 = __builtin_amdgcn_mfma_f32_16x16x32_bf16(A3l[0], Bh0, a3, 0, 0, 0);
      a3 = __builtin_amdgcn_mfma_f32_16x16x32_bf16(A3l[1], Bh1, a3, 0, 0, 0);
#pragma unroll
      for (int r = 0; r < 4; ++r) mmax[nb][r] = fmaxf(mmax[nb][r], a3[r]);
    }
  }
  // epilogue: activation (monotone), bf16 hi/lo split, sq via shuffle
  float sqp[4] = {0.f, 0.f, 0.f, 0.f};
#pragma unroll
  for (int nb = 0; nb < 4; ++nb) {
    int c = nb * 16 + lm;
#pragma unroll
    for (int r = 0; r < 4; ++r) {
      float vv3 = relu_(mmax[nb][r] + bC[nb]) * sC[nb] + hC[nb];
      sqp[r] = fmaf(vv3, vv3, sqp[r]);
      __bf16 hb = (__bf16)vv3;
      __bf16 lb = (__bf16)(vv3 - (float)hb);
      int n = p0 + w * 16 + quad * 4 + r;
      xh[(size_t)n * 64 + c] = hb;
      xl[(size_t)n * 64 + c] = lb;
      xb[(size_t)n * 192 + c] = hb;
    }
  }
#pragma unroll
  for (int r = 0; r < 4; ++r) {
    float s = sqp[r];
    s += __shfl_xor(s, 1);
    s += __shfl_xor(s, 2);
    s += __shfl_xor(s, 4);
    s += __shfl_xor(s, 8);
    if (lm == 0) sqo[p0 + w * 16 + quad * 4 + r] = s;
  }
}

// ---------------- Kernel 3: kNN on x1 via MFMA hi/lo (R6-measured best config) ----------------
__global__ __launch_bounds__(256) void k_knn2(const __bf16* __restrict__ xh,
                                              const __bf16* __restrict__ xl,
                                              const float* __restrict__ sq,
                                              int* __restrict__ idx2) {
  __shared__ __align__(16) __bf16 Bh[64 * 72];
  __shared__ __align__(16) __bf16 Bl[64 * 72];
  __shared__ float sqs[2048];
  int tid = threadIdx.x;
  int w = tid >> 6, lane = tid & 63;
  int quad = lane >> 4, lm = lane & 15;
  int b = blockIdx.x >> 5, qc = blockIdx.x & 31;
  int q0 = qc * 64;
  size_t bb = (size_t)b * 2048;
  for (int u = tid; u < 512; u += 256)
    *(float4*)(sqs + u * 4) = *(const float4*)(sq + bb + u * 4);
  const __bf16* qh = xh + (bb + q0 + w * 16 + lm) * 64 + quad * 8;
  const __bf16* ql = xl + (bb + q0 + w * 16 + lm) * 64 + quad * 8;
  bf16x8 Ah0 = *(const bf16x8*)(qh);
  bf16x8 Ah1 = *(const bf16x8*)(qh + 32);
  bf16x8 Al0 = *(const bf16x8*)(ql);
  bf16x8 Al1 = *(const bf16x8*)(ql + 32);
  __syncthreads();
  float qsq[4];
#pragma unroll
  for (int r = 0; r < 4; ++r) qsq[r] = sqs[q0 + w * 16 + quad * 4 + r];
  float bd[4][5];
  int bi[4][5];
#pragma unroll
  for (int r = 0; r < 4; ++r)
#pragma unroll
    for (int k = 0; k < 5; ++k) { bd[r][k] = 1e30f; bi[r][k] = 0; }
  for (int ct = 0; ct < 32; ++ct) {
#pragma unroll
    for (int pass = 0; pass < 2; ++pass) {
      int unit = pass * 256 + tid;
      int n = unit >> 3, cc = unit & 7;
      const __bf16* gsrc = xh + (bb + ct * 64 + n) * 64 + cc * 8;
      const __bf16* gsrl = xl + (bb + ct * 64 + n) * 64 + cc * 8;
      *(uint4*)(Bh + n * 72 + cc * 8) = *(const uint4*)gsrc;
      *(uint4*)(Bl + n * 72 + cc * 8) = *(const uint4*)gsrl;
    }
    __syncthreads();
#pragma unroll
    for (int nt = 0; nt < 4; ++nt) {
      const __bf16* bph = Bh + (nt * 16 + lm) * 72 + quad * 8;
      const __bf16* bpl = Bl + (nt * 16 + lm) * 72 + quad * 8;
      bf16x8 Bh0 = *(const bf16x8*)(bph);
      bf16x8 Bh1 = *(const bf16x8*)(bph + 32);
      bf16x8 Bl0 = *(const bf16x8*)(bpl);
      bf16x8 Bl1 = *(const bf16x8*)(bpl + 32);
      f32x4 acc = {0.f, 0.f, 0.f, 0.f};
      acc = __builtin_amdgcn_mfma_f32_16x16x32_bf16(Ah0, Bh0, acc, 0, 0, 0);
      acc = __builtin_amdgcn_mfma_f32_16x16x32_bf16(Ah1, Bh1, acc, 0, 0, 0);
      acc = __builtin_amdgcn_mfma_f32_16x16x32_bf16(Ah0, Bl0, acc, 0, 0, 0);
      acc = __builtin_amdgcn_mfma_f32_16x16x32_bf16(Ah1, Bl1, acc, 0, 0, 0);
      acc = __builtin_amdgcn_mfma_f32_16x16x32_bf16(Al0, Bh0, acc, 0, 0, 0);
      acc = __builtin_amdgcn_mfma_f32_16x16x32_bf16(Al1, Bh1, acc, 0, 0, 0);
      int cid = ct * 64 + nt * 16 + lm;
      float csq = sqs[cid];
#pragma unroll
      for (int r = 0; r < 4; ++r) {
        float d = (qsq[r] + csq) - 2.0f * acc[r];
        knn_insert(bd[r], bi[r], d, cid);
      }
    }
    __syncthreads();
  }
  for (int m = 1; m <= 8; m <<= 1) {
#pragma unroll
    for (int r = 0; r < 4; ++r) {
      float od[5]; int oi[5];
#pragma unroll
      for (int k = 0; k < 5; ++k) {
        od[k] = __shfl_xor(bd[r][k], m);
        oi[k] = __shfl_xor(bi[r][k], m);
      }
#pragma unroll
      for (int k = 0; k < 5; ++k) knn_insert(bd[r], bi[r], od[k], oi[k]);
    }
  }
  if (lm == 0) {
#pragma unroll
    for (int r = 0; r < 4; ++r) {
      int qi = q0 + w * 16 + quad * 4 + r;
      int* op = idx2 + (bb + qi) * 5;
#pragma unroll
      for (int k = 0; k < 5; ++k) op[k] = bi[r][k];
    }
  }
}

// ---------------- Kernel 4w: split w2 into P/Q weights, bf16 hi/lo, MFMA-B frag order ----------------
__global__ __launch_bounds__(256) void k_wprep(const float* __restrict__ w2,
                                               __bf16* __restrict__ wph,
                                               __bf16* __restrict__ wpl) {
  int t = blockIdx.x * 256 + threadIdx.x;  // 0..2047
  int nb = t >> 7;
  int rem = t & 127;
  int ks = rem >> 6, lane = rem & 63;
  int k0 = ks * 32 + (lane >> 4) * 8;
  int col16 = lane & 15;
  __bf16 oh[8], ol[8];
#pragma unroll
  for (int j = 0; j < 8; ++j) {
    int k = k0 + j;
    float val;
    if (nb < 8) {
      int c = nb * 16 + col16;
      val = w2[k * 128 + c] - w2[(64 + k) * 128 + c];
    } else {
      int c = (nb - 8) * 16 + col16;
      val = w2[(64 + k) * 128 + c];
    }
    __bf16 h = (__bf16)val;
    oh[j] = h;
    ol[j] = (__bf16)(val - (float)h);
  }
  *(uint4*)(wph + (size_t)t * 8) = *(const uint4*)oh;
  *(uint4*)(wpl + (size_t)t * 8) = *(const uint4*)ol;
}

// ---------------- Kernel 4a: P/Q via hi/lo MFMA ----------------
__global__ __launch_bounds__(256) void k_pq_mfma(const __bf16* __restrict__ xh,
                                                 const __bf16* __restrict__ xl,
                                                 const __bf16* __restrict__ wph,
                                                 const __bf16* __restrict__ wpl,
                                                 __bf16* __restrict__ Pb,
                                                 __bf16* __restrict__ Qb) {
  __shared__ __align__(16) __bf16 Wh[16384];
  __shared__ __align__(16) __bf16 Wl[16384];
  int tid = threadIdx.x;
  int w = tid >> 6, lane = tid & 63;
  int quad = lane >> 4, lm = lane & 15;
  int n0 = blockIdx.x * 64;
#pragma unroll
  for (int it = 0; it < 8; ++it) {
    int unit = it * 256 + tid;
    *(uint4*)(Wh + (size_t)unit * 8) = *(const uint4*)(wph + (size_t)unit * 8);
    *(uint4*)(Wl + (size_t)unit * 8) = *(const uint4*)(wpl + (size_t)unit * 8);
  }
  const __bf16* ah = xh + (size_t)(n0 + w * 16 + lm) * 64 + quad * 8;
  const __bf16* al = xl + (size_t)(n0 + w * 16 + lm) * 64 + quad * 8;
  bf16x8 Ah0 = *(const bf16x8*)(ah);
  bf16x8 Ah1 = *(const bf16x8*)(ah + 32);
  bf16x8 Al0 = *(const bf16x8*)(al);
  bf16x8 Al1 = *(const bf16x8*)(al + 32);
  __syncthreads();
  f32x4 acc[16];
#pragma unroll
  for (int nb = 0; nb < 16; ++nb) acc[nb] = (f32x4){0.f, 0.f, 0.f, 0.f};
#pragma unroll 4
  for (int nb = 0; nb < 16; ++nb) {
    bf16x8 Bh0 = *(const bf16x8*)(Wh + ((size_t)(nb * 2 + 0) * 64 + lane) * 8);
    bf16x8 Bh1 = *(const bf16x8*)(Wh + ((size_t)(nb * 2 + 1) * 64 + lane) * 8);
    bf16x8 Bl0 = *(const bf16x8*)(Wl + ((size_t)(nb * 2 + 0) * 64 + lane) * 8);
    bf16x8 Bl1 = *(const bf16x8*)(Wl + ((size_t)(nb * 2 + 1) * 64 + lane) * 8);
    acc[nb] = __builtin_amdgcn_mfma_f32_16x16x32_bf16(Ah0, Bh0, acc[nb], 0, 0, 0);
    acc[nb] = __builtin_amdgcn_mfma_f32_16x16x32_bf16(Ah1, Bh1, acc[nb], 0, 0, 0);
    acc[nb] = __builtin_amdgcn_mfma_f32_16x16x32_bf16(Ah0, Bl0, acc[nb], 0, 0, 0);
    acc[nb] = __builtin_amdgcn_mfma_f32_16x16x32_bf16(Ah1, Bl1, acc[nb], 0, 0, 0);
    acc[nb] = __builtin_amdgcn_mfma_f32_16x16x32_bf16(Al0, Bh0, acc[nb], 0, 0, 0);
    acc[nb] = __builtin_amdgcn_mfma_f32_16x16x32_bf16(Al1, Bh1, acc[nb], 0, 0, 0);
  }
#pragma unroll
  for (int nb = 0; nb < 16; ++nb) {
    bool isP = (nb < 8);
    __bf16* base = isP ? Pb : Qb;
    int col = (isP ? nb : nb - 8) * 16 + lm;
#pragma unroll
    for (int r = 0; r < 4; ++r) {
      int n = n0 + w * 16 + quad * 4 + r;
      base[(size_t)n * 128 + col] = (__bf16)acc[nb][r];
    }
  }
}

// ---------------- Kernel 4p: repack wl -> MFMA-B frag order bf16 ----------------
__global__ __launch_bounds__(256) void k_prep(const float* __restrict__ wl,
                                              __bf16* __restrict__ wlb) {
  int t = blockIdx.x * 256 + threadIdx.x;
  int nt = t / 3072;
  int rem = t - nt * 3072;
  int ks = rem / 512;
  int rem2 = rem - ks * 512;
  int nb = rem2 >> 6, lane = rem2 & 63;
  int k0 = ks * 32 + (lane >> 4) * 8;
  int n = nt * 128 + nb * 16 + (lane & 15);
  __bf16 o[8];
#pragma unroll
  for (int j = 0; j < 8; ++j) o[j] = (__bf16)wl[(k0 + j) * 1024 + n];
  *(uint4*)(wlb + (size_t)t * 8) = *(const uint4*)o;
}

// ---------------- Kernel 4b: gather-max + activation -> xb bf16 [n][64:192] ----------------
__global__ __launch_bounds__(256) void k_gmax(const __bf16* __restrict__ Pb,
                                              const __bf16* __restrict__ Qb,
                                              const int* __restrict__ idx2,
                                              const float* __restrict__ b2,
                                              const float* __restrict__ s2,
                                              const float* __restrict__ h2v,
                                              __bf16* __restrict__ xb) {
  int tid = threadIdx.x;
  int c = tid & 127, p = tid >> 7;
  int n = blockIdx.x * 2 + p;
  int b = n >> 11;
  const int* ip = idx2 + n * 5;
  float m = -3.4e38f;
#pragma unroll
  for (int k = 0; k < 5; ++k) {
    int j = ip[k];
    m = fmaxf(m, (float)Qb[((size_t)(b * 2048 + j)) * 128 + c]);
  }
  float v = (float)Pb[(size_t)n * 128 + c] + m + b2[c];
  xb[(size_t)n * 192 + 64 + c] = (__bf16)(relu_(v) * s2[c] + h2v[c]);
}

// ---------------- Kernel 5: bf16 MFMA GEMM fused point-max ----------------
__global__ __launch_bounds__(256) void k_linl_mfma(const __bf16* __restrict__ xb,
                                                   const __bf16* __restrict__ wlb,
                                                   float* __restrict__ pool_part) {
  __shared__ __align__(16) __bf16 Al[4096];
  __shared__ __align__(16) __bf16 Bl[4096];
  __shared__ float red[256];
  int tid = threadIdx.x;
  int w = tid >> 6, lane = tid & 63;
  int mt = blockIdx.x >> 3, nt = blockIdx.x & 7;
  int n0 = mt << 7;
  int wm = w & 1, wn = w >> 1;
  int quad = lane >> 4, lm = lane & 15;
  f32x4 acc[4][4];
#pragma unroll
  for (int i = 0; i < 4; ++i)
#pragma unroll
    for (int j = 0; j < 4; ++j) acc[i][j] = (f32x4){0.f, 0.f, 0.f, 0.f};
  for (int ks = 0; ks < 6; ++ks) {
    __syncthreads();
#pragma unroll
    for (int u = 0; u < 2; ++u) {
      int mb = w * 2 + u;
      const uint4* ga = (const uint4*)(xb + (size_t)(n0 + mb * 16 + lm) * 192 + ks * 32 + quad * 8);
      *(uint4*)(Al + (mb * 64 + lane) * 8) = *ga;
      const uint4* gb = (const uint4*)(wlb + ((((size_t)nt * 6 + ks) * 8 + mb) * 64 + lane) * 8);
      *(uint4*)(Bl + (mb * 64 + lane) * 8) = *gb;
    }
    __syncthreads();
    bf16x8 af[4], bfr[4];
#pragma unroll
    for (int i = 0; i < 4; ++i) {
      af[i] = *(const bf16x8*)(Al + ((wm * 4 + i) * 64 + lane) * 8);
      bfr[i] = *(const bf16x8*)(Bl + ((wn * 4 + i) * 64 + lane) * 8);
    }
#pragma unroll
    for (int i = 0; i < 4; ++i)
#pragma unroll
      for (int j = 0; j < 4; ++j)
        acc[i][j] = __builtin_amdgcn_mfma_f32_16x16x32_bf16(af[i], bfr[j], acc[i][j], 0, 0, 0);
  }
  float pm[4];
#pragma unroll
  for (int j = 0; j < 4; ++j) {
    float m = -3.4e38f;
#pragma unroll
    for (int i = 0; i < 4; ++i)
#pragma unroll
      for (int r = 0; r < 4; ++r) m = fmaxf(m, acc[i][j][r]);
    m = fmaxf(m, __shfl_xor(m, 16));
    m = fmaxf(m, __shfl_xor(m, 32));
    pm[j] = m;
  }
  __syncthreads();
  if (quad == 0) {
#pragma unroll
    for (int j = 0; j < 4; ++j) red[w * 64 + j * 16 + lm] = pm[j];
  }
  __syncthreads();
  if (tid < 128) {
    int wn2 = tid >> 6, cc = tid & 63;
    float v = fmaxf(red[(wn2 * 2) * 64 + cc], red[(wn2 * 2 + 1) * 64 + cc]);
    pool_part[(size_t)mt * 1024 + nt * 128 + wn2 * 64 + cc] = v;
  }
}

// ---------------- Kernel 6: head MLP ----------------
__global__ __launch_bounds__(256) void k_head(
    const float* __restrict__ pool_part, const float* __restrict__ bl,
    const float* __restrict__ sl, const float* __restrict__ hl,
    const float* __restrict__ wm1, const float* __restrict__ bm1,
    const float* __restrict__ sm1, const float* __restrict__ hm1,
    const float* __restrict__ wm2, const float* __restrict__ bm2,
    const float* __restrict__ sm2, const float* __restrict__ hm2,
    const float* __restrict__ wout, const float* __restrict__ bout,
    float* __restrict__ out) {
  __shared__ float p_s[1024], h1_s[512], h2_s[256];
  int b = blockIdx.x, tid = threadIdx.x;
  for (int c = tid; c < 1024; c += 256) {
    float m = -3.4e38f;
#pragma unroll 4
    for (int t = 0; t < 16; ++t)
      m = fmaxf(m, pool_part[(size_t)(b * 16 + t) * 1024 + c]);
    p_s[c] = relu_(m + bl[c]) * sl[c] + hl[c];
  }
  __syncthreads();
  for (int c = tid; c < 512; c += 256) {
    float a0 = 0, a1 = 0, a2 = 0, a3 = 0;
    for (int f = 0; f < 1024; f += 4) {
      a0 = fmaf(p_s[f], wm1[f * 512 + c], a0);
      a1 = fmaf(p_s[f + 1], wm1[(f + 1) * 512 + c], a1);
      a2 = fmaf(p_s[f + 2], wm1[(f + 2) * 512 + c], a2);
      a3 = fmaf(p_s[f + 3], wm1[(f + 3) * 512 + c], a3);
    }
    float a = (a0 + a1) + (a2 + a3);
    h1_s[c] = relu_(a + bm1[c]) * sm1[c] + hm1[c];
  }
  __syncthreads();
  if (tid < 256) {
    float a0 = 0, a1 = 0, a2 = 0, a3 = 0;
    for (int f = 0; f < 512; f += 4) {
      a0 = fmaf(h1_s[f], wm2[f * 256 + tid], a0);
      a1 = fmaf(h1_s[f + 1], wm2[(f + 1) * 256 + tid], a1);
      a2 = fmaf(h1_s[f + 2], wm2[(f + 2) * 256 + tid], a2);
      a3 = fmaf(h1_s[f + 3], wm2[(f + 3) * 256 + tid], a3);
    }
    float a = (a0 + a1) + (a2 + a3);
    h2_s[tid] = relu_(a + bm2[tid]) * sm2[tid] + hm2[tid];
  }
  __syncthreads();
  if (tid < 2) {
    float a0 = 0, a1 = 0;
    for (int f = 0; f < 256; f += 2) {
      a0 = fmaf(h2_s[f], wout[f * 2 + tid], a0);
      a1 = fmaf(h2_s[f + 1], wout[(f + 1) * 2 + tid], a1);
    }
    out[b * 2 + tid] = (a0 + a1) + bout[tid];
  }
}

extern "C" void kernel_launch(void* const* d_in, const int* in_sizes, int n_in,
                              void* d_out, int out_size, void* d_ws, size_t ws_size,
                              hipStream_t stream) {
  const float* pos = (const float*)d_in[0];
  const float* w1a = (const float*)d_in[1];
  const float* b1a = (const float*)d_in[2];
  const float* s1a = (const float*)d_in[3];
  const float* h1a = (const float*)d_in[4];
  const float* w1b = (const float*)d_in[5];
  const float* b1b = (const float*)d_in[6];
  const float* s1b = (const float*)d_in[7];
  const float* h1b = (const float*)d_in[8];
  const float* w1c = (const float*)d_in[9];
  const float* b1c = (const float*)d_in[10];
  const float* s1c = (const float*)d_in[11];
  const float* h1c = (const float*)d_in[12];
  const float* w2 = (const float*)d_in[13];
  const float* b2 = (const float*)d_in[14];
  const float* s2 = (const float*)d_in[15];
  const float* h2 = (const float*)d_in[16];
  const float* wl = (const float*)d_in[17];
  const float* bl = (const float*)d_in[18];
  const float* sl = (const float*)d_in[19];
  const float* hl = (const float*)d_in[20];
  const float* wm1 = (const float*)d_in[21];
  const float* bm1 = (const float*)d_in[22];
  const float* sm1 = (const float*)d_in[23];
  const float* hm1 = (const float*)d_in[24];
  const float* wm2 = (const float*)d_in[25];
  const float* bm2 = (const float*)d_in[26];
  const float* sm2 = (const float*)d_in[27];
  const float* hm2 = (const float*)d_in[28];
  const float* wout = (const float*)d_in[29];
  const float* bout = (const float*)d_in[30];
  float* out = (float*)d_out;

  // workspace: xh | xl | Pb | Qb | xb | idx | sq | wph | wpl | wfh | wfl (~77 MB)
  float* base = (float*)d_ws;
  __bf16* xh = (__bf16*)base;
  __bf16* xl = (__bf16*)(base + 2097152);
  float* PbF = base + 4194304;
  float* QbF = PbF + 4194304;
  float* xbF = QbF + 4194304;
  int* idx = (int*)(xbF + 6291456);
  float* sq = (float*)(idx + 327680);
  __bf16* wph = (__bf16*)(sq + 65536);            // 16384 bf16 (8192 f)
  __bf16* wpl = (__bf16*)(sq + 65536 + 8192);     // 16384 bf16
  __bf16* wfh = (__bf16*)(sq + 65536 + 16384);    // 8192 bf16 (4096 f)
  __bf16* wfl = (__bf16*)(sq + 65536 + 20480);    // 8192 bf16
  __bf16* Pb = (__bf16*)PbF;
  __bf16* Qb = (__bf16*)QbF;
  __bf16* xb = (__bf16*)xbF;
  float* uR = PbF;                                 // alias (dead until k_pq_mfma)
  float* vR = QbF;
  __bf16* wlb = (__bf16*)base;                     // alias xh (dead after k_pq_mfma)
  float* pool_part = base + 131072;

  k_knn1<<<2048, 256, 0, stream>>>(pos, idx);
  k_uv<<<1024, 256, 0, stream>>>(pos, w1a, b1a, uR, vR);
  k_wprep2<<<4, 256, 0, stream>>>(w1b, w1c, wfh, wfl);
  k_edge1<<<1024, 256, 0, stream>>>(idx, uR, vR, s1a, h1a, b1b, s1b, h1b, b1c,
                                    s1c, h1c, wfh, wfl, xh, xl, sq, xb);
  k_knn2<<<1024, 256, 0, stream>>>(xh, xl, sq, idx);
  k_wprep<<<8, 256, 0, stream>>>(w2, wph, wpl);
  k_pq_mfma<<<1024, 256, 0, stream>>>(xh, xl, wph, wpl, Pb, Qb);
  k_prep<<<96, 256, 0, stream>>>(wl, wlb);
  k_gmax<<<32768, 256, 0, stream>>>(Pb, Qb, idx, b2, s2, h2, xb);
  k_linl_mfma<<<4096, 256, 0, stream>>>(xb, wlb, pool_part);
  k_head<<<32, 256, 0, stream>>>(pool_part, bl, sl, hl, wm1, bm1, sm1, hm1, wm2,
                                 bm2, sm2, hm2, wout, bout, out);
}

// Round 14
// 600.255 us; speedup vs baseline: 1.3344x; 1.0583x over previous
//
#include <hip/hip_runtime.h>

#define DEV __device__ __forceinline__
DEV float relu_(float x) { return fmaxf(x, 0.0f); }

typedef __attribute__((ext_vector_type(4))) float f32x4;
typedef __attribute__((ext_vector_type(8))) __bf16 bf16x8;

DEV unsigned short bfbits(__bf16 b) { union { unsigned short s; __bf16 b; } x; x.b = b; return x.s; }
DEV __bf16 bffrom(unsigned short s) { union { unsigned short s; __bf16 b; } x; x.s = s; return x.b; }

// branchy top-5 insert (R6-measured best for knn2's wave-coherent stream)
DEV void knn_insert(float (&bd)[5], int (&bi)[5], float d, int j) {
  if (d >= bd[4]) return;
  bd[4] = d; bi[4] = j;
#pragma unroll
  for (int p = 4; p > 0; --p) {
    if (bd[p] < bd[p - 1]) {
      float td = bd[p]; bd[p] = bd[p - 1]; bd[p - 1] = td;
      int ti = bi[p]; bi[p] = bi[p - 1]; bi[p - 1] = ti;
    }
  }
}

// branchless EXACT top-5 insert (used in knn1)
DEV void knn_insert_bl(float (&bd)[5], int (&bi)[5], float d, int j) {
#pragma unroll
  for (int p = 0; p < 5; ++p) {
    bool lt = d < bd[p];
    float nd = lt ? d : bd[p];
    float cd = lt ? bd[p] : d;
    int ni = lt ? j : bi[p];
    int ci = lt ? bi[p] : j;
    bd[p] = nd; d = cd;
    bi[p] = ni; j = ci;
  }
}

// ---------------- Kernel 1: kNN on pos (F=3), 8-way candidate split ----------------
__global__ __launch_bounds__(256) void k_knn1(const float* __restrict__ pos,
                                              int* __restrict__ idx1) {
  __shared__ float ps[6144];
  __shared__ float sqs[2048];
  __shared__ float md[640];
  __shared__ int mi[640];
  int tid = threadIdx.x;
  int b = blockIdx.x >> 6, qc = blockIdx.x & 63;
  const float* src = pos + b * 6144;
  for (int u = tid; u < 6144; u += 256) ps[u] = src[u];
  __syncthreads();
  for (int u = tid; u < 2048; u += 256) {
    float x = ps[u * 3], y = ps[u * 3 + 1], z = ps[u * 3 + 2];
    sqs[u] = fmaf(z, z, fmaf(y, y, x * x));
  }
  __syncthreads();
  int q = tid & 31, sub = tid >> 5;
  int qi = qc * 32 + q;
  float qx = ps[qi * 3], qy = ps[qi * 3 + 1], qz = ps[qi * 3 + 2];
  float qsq = sqs[qi];
  float bd[5] = {1e30f, 1e30f, 1e30f, 1e30f, 1e30f};
  int bi[5] = {0, 0, 0, 0, 0};
  int j0 = sub * 256;
  for (int j = j0; j < j0 + 256; ++j) {
    float px = ps[j * 3], py = ps[j * 3 + 1], pz = ps[j * 3 + 2];
    float dot = fmaf(qz, pz, fmaf(qy, py, qx * px));
    float d = (qsq + sqs[j]) - 2.0f * dot;
    knn_insert_bl(bd, bi, d, j);
  }
  for (int half = 4; half >= 1; half >>= 1) {
    __syncthreads();
    if (sub >= half && sub < 2 * half) {
      int slot = (q * 4 + (sub - half)) * 5;
#pragma unroll
      for (int k = 0; k < 5; ++k) { md[slot + k] = bd[k]; mi[slot + k] = bi[k]; }
    }
    __syncthreads();
    if (sub < half) {
      int slot = (q * 4 + sub) * 5;
#pragma unroll
      for (int k = 0; k < 5; ++k) knn_insert_bl(bd, bi, md[slot + k], mi[slot + k]);
    }
  }
  if (sub == 0) {
    int* op = idx1 + (b * 2048 + qi) * 5;
#pragma unroll
    for (int k = 0; k < 5; ++k) op[k] = bi[k];
  }
}

// ---------------- Kernel 1b: per-point u/v row-major; LDS-staged coalesced writes ----------------
__global__ __launch_bounds__(256) void k_uv(const float* __restrict__ pos,
                                            const float* __restrict__ w1a,
                                            const float* __restrict__ b1a,
                                            float* __restrict__ uR,
                                            float* __restrict__ vR) {
  __shared__ float wAs[384];
  __shared__ float bs[64];
  __shared__ __align__(16) float uS[64 * 68];
  __shared__ __align__(16) float vS[64 * 68];
  int tid = threadIdx.x;
  for (int u = tid; u < 384; u += 256) wAs[u] = w1a[u];
  if (tid < 64) bs[tid] = b1a[tid];
  __syncthreads();
  int lane = tid & 63, fq = tid >> 6;
  int p0 = blockIdx.x * 64;
  int p = p0 + lane;
  float x0 = pos[p * 3], x1 = pos[p * 3 + 1], x2 = pos[p * 3 + 2];
#pragma unroll
  for (int m = 0; m < 16; ++m) {
    int f = fq * 16 + m;
    float wt0 = wAs[f], wt1 = wAs[64 + f], wt2 = wAs[128 + f];
    float wb0 = wAs[192 + f], wb1 = wAs[256 + f], wb2 = wAs[320 + f];
    float uval = bs[f];
    uval = fmaf(x0, wt0 - wb0, uval);
    uval = fmaf(x1, wt1 - wb1, uval);
    uval = fmaf(x2, wt2 - wb2, uval);
    uS[lane * 68 + f] = uval;
    vS[lane * 68 + f] = fmaf(x2, wb2, fmaf(x1, wb1, x0 * wb0));
  }
  __syncthreads();
#pragma unroll
  for (int it = 0; it < 4; ++it) {
    int g = it * 1024 + tid * 4;  // 0..4095
    int pl = g >> 6, f = g & 63;
    float4 uu = *(const float4*)(uS + pl * 68 + f);
    float4 vv = *(const float4*)(vS + pl * 68 + f);
    *(float4*)(uR + (size_t)p0 * 64 + g) = uu;
    *(float4*)(vR + (size_t)p0 * 64 + g) = vv;
  }
}

// ---------------- merged prep: w1b/w1c + w2 + wl repacks in one launch ----------------
__global__ __launch_bounds__(256) void k_prep_all(
    const float* __restrict__ w1b, const float* __restrict__ w1c,
    const float* __restrict__ w2, const float* __restrict__ wl,
    __bf16* __restrict__ wfh, __bf16* __restrict__ wfl,
    __bf16* __restrict__ wph, __bf16* __restrict__ wpl,
    __bf16* __restrict__ wlb) {
  int blk = blockIdx.x;
  if (blk < 4) {
    int t = blk * 256 + threadIdx.x;  // 0..1023
    int m = t >> 9;
    int rem = t & 511;
    int nb = rem >> 7;
    int rem2 = rem & 127;
    int s = rem2 >> 6, lane = rem2 & 63;
    int k0 = s * 32 + (lane >> 4) * 8;
    int c = nb * 16 + (lane & 15);
    const float* W = m ? w1c : w1b;
    __bf16 oh[8], ol[8];
#pragma unroll
    for (int j = 0; j < 8; ++j) {
      float val = W[(k0 + j) * 64 + c];
      __bf16 h = (__bf16)val;
      oh[j] = h;
      ol[j] = (__bf16)(val - (float)h);
    }
    size_t off = (size_t)m * 4096 + ((size_t)((nb * 2 + s) * 64 + lane)) * 8;
    *(uint4*)(wfh + off) = *(const uint4*)oh;
    *(uint4*)(wfl + off) = *(const uint4*)ol;
  } else if (blk < 12) {
    int t = (blk - 4) * 256 + threadIdx.x;  // 0..2047
    int nb = t >> 7;
    int rem = t & 127;
    int ks = rem >> 6, lane = rem & 63;
    int k0 = ks * 32 + (lane >> 4) * 8;
    int col16 = lane & 15;
    __bf16 oh[8], ol[8];
#pragma unroll
    for (int j = 0; j < 8; ++j) {
      int k = k0 + j;
      float val;
      if (nb < 8) {
        int c = nb * 16 + col16;
        val = w2[k * 128 + c] - w2[(64 + k) * 128 + c];
      } else {
        int c = (nb - 8) * 16 + col16;
        val = w2[(64 + k) * 128 + c];
      }
      __bf16 h = (__bf16)val;
      oh[j] = h;
      ol[j] = (__bf16)(val - (float)h);
    }
    *(uint4*)(wph + (size_t)t * 8) = *(const uint4*)oh;
    *(uint4*)(wpl + (size_t)t * 8) = *(const uint4*)ol;
  } else {
    int t = (blk - 12) * 256 + threadIdx.x;  // 0..24575
    int nt = t / 3072;
    int rem = t - nt * 3072;
    int ks = rem / 512;
    int rem2 = rem - ks * 512;
    int nb = rem2 >> 6, lane = rem2 & 63;
    int k0 = ks * 32 + (lane >> 4) * 8;
    int n = nt * 128 + nb * 16 + (lane & 15);
    __bf16 o[8];
#pragma unroll
    for (int j = 0; j < 8; ++j) o[j] = (__bf16)wl[(k0 + j) * 1024 + n];
    *(uint4*)(wlb + (size_t)t * 8) = *(const uint4*)o;
  }
}

// ---------------- Kernel 2: EdgeConv1 layers 2/3 via hi/lo MFMA, barrier-free k-loop ----------------
__global__ __launch_bounds__(256) void k_edge1(
    const int* __restrict__ idx1, const float* __restrict__ uR,
    const float* __restrict__ vR,
    const float* __restrict__ s1a, const float* __restrict__ h1a,
    const float* __restrict__ b1b, const float* __restrict__ s1b,
    const float* __restrict__ h1b,
    const float* __restrict__ b1c, const float* __restrict__ s1c,
    const float* __restrict__ h1c,
    const __bf16* __restrict__ wfh, const __bf16* __restrict__ wfl,
    __bf16* __restrict__ xh, __bf16* __restrict__ xl,
    float* __restrict__ sqo, __bf16* __restrict__ xb) {
  __shared__ __align__(16) __bf16 Wh[8192], Wl[8192];
  __shared__ __align__(16) unsigned h2b[4 * 1088];
  int tid = threadIdx.x;
  int w = tid >> 6, lane = tid & 63;
  int quad = lane >> 4, lm = lane & 15;
#pragma unroll
  for (int it = 0; it < 4; ++it) {
    int u4 = it * 256 + tid;
    *(uint4*)(Wh + (size_t)u4 * 8) = *(const uint4*)(wfh + (size_t)u4 * 8);
    *(uint4*)(Wl + (size_t)u4 * 8) = *(const uint4*)(wfl + (size_t)u4 * 8);
  }
  int p0 = blockIdx.x * 64;
  int b = p0 >> 11;
  size_t bb = (size_t)b * 2048;
  int edge = p0 + w * 16 + lm;
  float sA[2][8], hA[2][8];
#pragma unroll
  for (int s = 0; s < 2; ++s)
#pragma unroll
    for (int j = 0; j < 8; ++j) {
      int k = s * 32 + quad * 8 + j;
      sA[s][j] = s1a[k]; hA[s][j] = h1a[k];
    }
  float bB[4], sB[4], hB[4], bC[4], sC[4], hC[4];
#pragma unroll
  for (int nb = 0; nb < 4; ++nb) {
    int c = nb * 16 + lm;
    bB[nb] = b1b[c]; sB[nb] = s1b[c]; hB[nb] = h1b[c];
    bC[nb] = b1c[c]; sC[nb] = s1c[c]; hC[nb] = h1c[c];
  }
  unsigned* h2w = h2b + w * 1088;
  f32x4 mmax[4];
#pragma unroll
  for (int nb = 0; nb < 4; ++nb)
    mmax[nb] = (f32x4){-3.4e38f, -3.4e38f, -3.4e38f, -3.4e38f};
  __syncthreads();
  const float* urow = uR + (size_t)edge * 64;
  for (int kk = 0; kk < 5; ++kk) {
    int jn = idx1[edge * 5 + kk];
    const float* vrow = vR + (bb + jn) * 64;
    bf16x8 Ah[2], Al[2];
#pragma unroll
    for (int s = 0; s < 2; ++s) {
      int off = s * 32 + quad * 8;
      float4 u0 = *(const float4*)(urow + off);
      float4 u1 = *(const float4*)(urow + off + 4);
      float4 v0 = *(const float4*)(vrow + off);
      float4 v1 = *(const float4*)(vrow + off + 4);
      float uv[8] = {u0.x + v0.x, u0.y + v0.y, u0.z + v0.z, u0.w + v0.w,
                     u1.x + v1.x, u1.y + v1.y, u1.z + v1.z, u1.w + v1.w};
      __bf16 th[8], tl[8];
#pragma unroll
      for (int j = 0; j < 8; ++j) {
        float val = relu_(uv[j]) * sA[s][j] + hA[s][j];
        __bf16 hb = (__bf16)val;
        th[j] = hb;
        tl[j] = (__bf16)(val - (float)hb);
      }
      Ah[s] = *(const bf16x8*)th;
      Al[s] = *(const bf16x8*)tl;
    }
#pragma unroll
    for (int nb = 0; nb < 4; ++nb) {
      bf16x8 Bh0 = *(const bf16x8*)(Wh + ((size_t)((nb * 2 + 0) * 64 + lane)) * 8);
      bf16x8 Bh1 = *(const bf16x8*)(Wh + ((size_t)((nb * 2 + 1) * 64 + lane)) * 8);
      bf16x8 Bl0 = *(const bf16x8*)(Wl + ((size_t)((nb * 2 + 0) * 64 + lane)) * 8);
      bf16x8 Bl1 = *(const bf16x8*)(Wl + ((size_t)((nb * 2 + 1) * 64 + lane)) * 8);
      f32x4 a2 = {0.f, 0.f, 0.f, 0.f};
      a2 = __builtin_amdgcn_mfma_f32_16x16x32_bf16(Ah[0], Bh0, a2, 0, 0, 0);
      a2 = __builtin_amdgcn_mfma_f32_16x16x32_bf16(Ah[1], Bh1, a2, 0, 0, 0);
      a2 = __builtin_amdgcn_mfma_f32_16x16x32_bf16(Ah[0], Bl0, a2, 0, 0, 0);
      a2 = __builtin_amdgcn_mfma_f32_16x16x32_bf16(Ah[1], Bl1, a2, 0, 0, 0);
      a2 = __builtin_amdgcn_mfma_f32_16x16x32_bf16(Al[0], Bh0, a2, 0, 0, 0);
      a2 = __builtin_amdgcn_mfma_f32_16x16x32_bf16(Al[1], Bh1, a2, 0, 0, 0);
#pragma unroll
      for (int r = 0; r < 4; ++r) {
        float vv2 = relu_(a2[r] + bB[nb]) * sB[nb] + hB[nb];
        __bf16 hb = (__bf16)vv2;
        __bf16 lb = (__bf16)(vv2 - (float)hb);
        h2w[(quad * 4 + r) * 68 + nb * 16 + lm] =
            (unsigned)bfbits(hb) | ((unsigned)bfbits(lb) << 16);
      }
    }
    bf16x8 A3h[2], A3l[2];
#pragma unroll
    for (int s = 0; s < 2; ++s) {
      const unsigned* rp = h2w + lm * 68 + s * 32 + quad * 8;
      uint4 da = *(const uint4*)rp;
      uint4 db = *(const uint4*)(rp + 4);
      unsigned dw[8] = {da.x, da.y, da.z, da.w, db.x, db.y, db.z, db.w};
      __bf16 th[8], tl[8];
#pragma unroll
      for (int j = 0; j < 8; ++j) {
        th[j] = bffrom((unsigned short)(dw[j] & 0xFFFFu));
        tl[j] = bffrom((unsigned short)(dw[j] >> 16));
      }
      A3h[s] = *(const bf16x8*)th;
      A3l[s] = *(const bf16x8*)tl;
    }
#pragma unroll
    for (int nb = 0; nb < 4; ++nb) {
      bf16x8 Bh0 = *(const bf16x8*)(Wh + 4096 + ((size_t)((nb * 2 + 0) * 64 + lane)) * 8);
      bf16x8 Bh1 = *(const bf16x8*)(Wh + 4096 + ((size_t)((nb * 2 + 1) * 64 + lane)) * 8);
      bf16x8 Bl0 = *(const bf16x8*)(Wl + 4096 + ((size_t)((nb * 2 + 0) * 64 + lane)) * 8);
      bf16x8 Bl1 = *(const bf16x8*)(Wl + 4096 + ((size_t)((nb * 2 + 1) * 64 + lane)) * 8);
      f32x4 a3 = {0.f, 0.f, 0.f, 0.f};
      a3 = __builtin_amdgcn_mfma_f32_16x16x32_bf16(A3h[0], Bh0, a3, 0, 0, 0);
      a3 = __builtin_amdgcn_mfma_f32_16x16x32_bf16(A3h[1], Bh1, a3, 0, 0, 0);
      a3 = __builtin_amdgcn_mfma_f32_16x16x32_bf16(A3h[0], Bl0, a3, 0, 0, 0);
      a3 = __builtin_amdgcn_mfma_f32_16x16x32_bf16(A3h[1], Bl1, a3, 0, 0, 0);
      a3 = __builtin_amdgcn_mfma_f32_16x16x32_bf16(A3l[0], Bh0, a3, 0, 0, 0);
      a3 = __builtin_amdgcn_mfma_f32_16x16x32_bf16(A3l[1], Bh1, a3, 0, 0, 0);
#pragma unroll
      for (int r = 0; r < 4; ++r) mmax[nb][r] = fmaxf(mmax[nb][r], a3[r]);
    }
  }
  float sqp[4] = {0.f, 0.f, 0.f, 0.f};
#pragma unroll
  for (int nb = 0; nb < 4; ++nb) {
    int c = nb * 16 + lm;
#pragma unroll
    for (int r = 0; r < 4; ++r) {
      float vv3 = relu_(mmax[nb][r] + bC[nb]) * sC[nb] + hC[nb];
      sqp[r] = fmaf(vv3, vv3, sqp[r]);
      __bf16 hb = (__bf16)vv3;
      __bf16 lb = (__bf16)(vv3 - (float)hb);
      int n = p0 + w * 16 + quad * 4 + r;
      xh[(size_t)n * 64 + c] = hb;
      xl[(size_t)n * 64 + c] = lb;
      xb[(size_t)n * 192 + c] = hb;
    }
  }
#pragma unroll
  for (int r = 0; r < 4; ++r) {
    float s = sqp[r];
    s += __shfl_xor(s, 1);
    s += __shfl_xor(s, 2);
    s += __shfl_xor(s, 4);
    s += __shfl_xor(s, 8);
    if (lm == 0) sqo[p0 + w * 16 + quad * 4 + r] = s;
  }
}

// ---------------- Kernel 3: kNN on x1 via MFMA hi/lo (R6-measured best config) ----------------
__global__ __launch_bounds__(256) void k_knn2(const __bf16* __restrict__ xh,
                                              const __bf16* __restrict__ xl,
                                              const float* __restrict__ sq,
                                              int* __restrict__ idx2) {
  __shared__ __align__(16) __bf16 Bh[64 * 72];
  __shared__ __align__(16) __bf16 Bl[64 * 72];
  __shared__ float sqs[2048];
  int tid = threadIdx.x;
  int w = tid >> 6, lane = tid & 63;
  int quad = lane >> 4, lm = lane & 15;
  int b = blockIdx.x >> 5, qc = blockIdx.x & 31;
  int q0 = qc * 64;
  size_t bb = (size_t)b * 2048;
  for (int u = tid; u < 512; u += 256)
    *(float4*)(sqs + u * 4) = *(const float4*)(sq + bb + u * 4);
  const __bf16* qh = xh + (bb + q0 + w * 16 + lm) * 64 + quad * 8;
  const __bf16* ql = xl + (bb + q0 + w * 16 + lm) * 64 + quad * 8;
  bf16x8 Ah0 = *(const bf16x8*)(qh);
  bf16x8 Ah1 = *(const bf16x8*)(qh + 32);
  bf16x8 Al0 = *(const bf16x8*)(ql);
  bf16x8 Al1 = *(const bf16x8*)(ql + 32);
  __syncthreads();
  float qsq[4];
#pragma unroll
  for (int r = 0; r < 4; ++r) qsq[r] = sqs[q0 + w * 16 + quad * 4 + r];
  float bd[4][5];
  int bi[4][5];
#pragma unroll
  for (int r = 0; r < 4; ++r)
#pragma unroll
    for (int k = 0; k < 5; ++k) { bd[r][k] = 1e30f; bi[r][k] = 0; }
  for (int ct = 0; ct < 32; ++ct) {
#pragma unroll
    for (int pass = 0; pass < 2; ++pass) {
      int unit = pass * 256 + tid;
      int n = unit >> 3, cc = unit & 7;
      const __bf16* gsrc = xh + (bb + ct * 64 + n) * 64 + cc * 8;
      const __bf16* gsrl = xl + (bb + ct * 64 + n) * 64 + cc * 8;
      *(uint4*)(Bh + n * 72 + cc * 8) = *(const uint4*)gsrc;
      *(uint4*)(Bl + n * 72 + cc * 8) = *(const uint4*)gsrl;
    }
    __syncthreads();
#pragma unroll
    for (int nt = 0; nt < 4; ++nt) {
      const __bf16* bph = Bh + (nt * 16 + lm) * 72 + quad * 8;
      const __bf16* bpl = Bl + (nt * 16 + lm) * 72 + quad * 8;
      bf16x8 Bh0 = *(const bf16x8*)(bph);
      bf16x8 Bh1 = *(const bf16x8*)(bph + 32);
      bf16x8 Bl0 = *(const bf16x8*)(bpl);
      bf16x8 Bl1 = *(const bf16x8*)(bpl + 32);
      f32x4 acc = {0.f, 0.f, 0.f, 0.f};
      acc = __builtin_amdgcn_mfma_f32_16x16x32_bf16(Ah0, Bh0, acc, 0, 0, 0);
      acc = __builtin_amdgcn_mfma_f32_16x16x32_bf16(Ah1, Bh1, acc, 0, 0, 0);
      acc = __builtin_amdgcn_mfma_f32_16x16x32_bf16(Ah0, Bl0, acc, 0, 0, 0);
      acc = __builtin_amdgcn_mfma_f32_16x16x32_bf16(Ah1, Bl1, acc, 0, 0, 0);
      acc = __builtin_amdgcn_mfma_f32_16x16x32_bf16(Al0, Bh0, acc, 0, 0, 0);
      acc = __builtin_amdgcn_mfma_f32_16x16x32_bf16(Al1, Bh1, acc, 0, 0, 0);
      int cid = ct * 64 + nt * 16 + lm;
      float csq = sqs[cid];
#pragma unroll
      for (int r = 0; r < 4; ++r) {
        float d = (qsq[r] + csq) - 2.0f * acc[r];
        knn_insert(bd[r], bi[r], d, cid);
      }
    }
    __syncthreads();
  }
  for (int m = 1; m <= 8; m <<= 1) {
#pragma unroll
    for (int r = 0; r < 4; ++r) {
      float od[5]; int oi[5];
#pragma unroll
      for (int k = 0; k < 5; ++k) {
        od[k] = __shfl_xor(bd[r][k], m);
        oi[k] = __shfl_xor(bi[r][k], m);
      }
#pragma unroll
      for (int k = 0; k < 5; ++k) knn_insert(bd[r], bi[r], od[k], oi[k]);
    }
  }
  if (lm == 0) {
#pragma unroll
    for (int r = 0; r < 4; ++r) {
      int qi = q0 + w * 16 + quad * 4 + r;
      int* op = idx2 + (bb + qi) * 5;
#pragma unroll
      for (int k = 0; k < 5; ++k) op[k] = bi[r][k];
    }
  }
}

// ---------------- Kernel 4a: P/Q via hi/lo MFMA ----------------
__global__ __launch_bounds__(256) void k_pq_mfma(const __bf16* __restrict__ xh,
                                                 const __bf16* __restrict__ xl,
                                                 const __bf16* __restrict__ wph,
                                                 const __bf16* __restrict__ wpl,
                                                 __bf16* __restrict__ Pb,
                                                 __bf16* __restrict__ Qb) {
  __shared__ __align__(16) __bf16 Wh[16384];
  __shared__ __align__(16) __bf16 Wl[16384];
  int tid = threadIdx.x;
  int w = tid >> 6, lane = tid & 63;
  int quad = lane >> 4, lm = lane & 15;
  int n0 = blockIdx.x * 64;
#pragma unroll
  for (int it = 0; it < 8; ++it) {
    int unit = it * 256 + tid;
    *(uint4*)(Wh + (size_t)unit * 8) = *(const uint4*)(wph + (size_t)unit * 8);
    *(uint4*)(Wl + (size_t)unit * 8) = *(const uint4*)(wpl + (size_t)unit * 8);
  }
  const __bf16* ah = xh + (size_t)(n0 + w * 16 + lm) * 64 + quad * 8;
  const __bf16* al = xl + (size_t)(n0 + w * 16 + lm) * 64 + quad * 8;
  bf16x8 Ah0 = *(const bf16x8*)(ah);
  bf16x8 Ah1 = *(const bf16x8*)(ah + 32);
  bf16x8 Al0 = *(const bf16x8*)(al);
  bf16x8 Al1 = *(const bf16x8*)(al + 32);
  __syncthreads();
  f32x4 acc[16];
#pragma unroll
  for (int nb = 0; nb < 16; ++nb) acc[nb] = (f32x4){0.f, 0.f, 0.f, 0.f};
#pragma unroll 4
  for (int nb = 0; nb < 16; ++nb) {
    bf16x8 Bh0 = *(const bf16x8*)(Wh + ((size_t)(nb * 2 + 0) * 64 + lane) * 8);
    bf16x8 Bh1 = *(const bf16x8*)(Wh + ((size_t)(nb * 2 + 1) * 64 + lane) * 8);
    bf16x8 Bl0 = *(const bf16x8*)(Wl + ((size_t)(nb * 2 + 0) * 64 + lane) * 8);
    bf16x8 Bl1 = *(const bf16x8*)(Wl + ((size_t)(nb * 2 + 1) * 64 + lane) * 8);
    acc[nb] = __builtin_amdgcn_mfma_f32_16x16x32_bf16(Ah0, Bh0, acc[nb], 0, 0, 0);
    acc[nb] = __builtin_amdgcn_mfma_f32_16x16x32_bf16(Ah1, Bh1, acc[nb], 0, 0, 0);
    acc[nb] = __builtin_amdgcn_mfma_f32_16x16x32_bf16(Ah0, Bl0, acc[nb], 0, 0, 0);
    acc[nb] = __builtin_amdgcn_mfma_f32_16x16x32_bf16(Ah1, Bl1, acc[nb], 0, 0, 0);
    acc[nb] = __builtin_amdgcn_mfma_f32_16x16x32_bf16(Al0, Bh0, acc[nb], 0, 0, 0);
    acc[nb] = __builtin_amdgcn_mfma_f32_16x16x32_bf16(Al1, Bh1, acc[nb], 0, 0, 0);
  }
#pragma unroll
  for (int nb = 0; nb < 16; ++nb) {
    bool isP = (nb < 8);
    __bf16* base = isP ? Pb : Qb;
    int col = (isP ? nb : nb - 8) * 16 + lm;
#pragma unroll
    for (int r = 0; r < 4; ++r) {
      int n = n0 + w * 16 + quad * 4 + r;
      base[(size_t)n * 128 + col] = (__bf16)acc[nb][r];
    }
  }
}

// ---------------- Kernel 4b: gather-max + activation -> xb bf16 [n][64:192] ----------------
__global__ __launch_bounds__(256) void k_gmax(const __bf16* __restrict__ Pb,
                                              const __bf16* __restrict__ Qb,
                                              const int* __restrict__ idx2,
                                              const float* __restrict__ b2,
                                              const float* __restrict__ s2,
                                              const float* __restrict__ h2v,
                                              __bf16* __restrict__ xb) {
  int tid = threadIdx.x;
  int c = tid & 127, p = tid >> 7;
  int n = blockIdx.x * 2 + p;
  int b = n >> 11;
  const int* ip = idx2 + n * 5;
  float m = -3.4e38f;
#pragma unroll
  for (int k = 0; k < 5; ++k) {
    int j = ip[k];
    m = fmaxf(m, (float)Qb[((size_t)(b * 2048 + j)) * 128 + c]);
  }
  float v = (float)Pb[(size_t)n * 128 + c] + m + b2[c];
  xb[(size_t)n * 192 + 64 + c] = (__bf16)(relu_(v) * s2[c] + h2v[c]);
}

// ---------------- Kernel 5: bf16 MFMA GEMM fused point-max, 64m x 256n tiles ----------------
__global__ __launch_bounds__(256) void k_linl_mfma(const __bf16* __restrict__ xb,
                                                   const __bf16* __restrict__ wlb,
                                                   float* __restrict__ pool_part) {
  __shared__ __align__(16) __bf16 Al[2048];
  __shared__ __align__(16) __bf16 Bl[8192];
  int tid = threadIdx.x;
  int w = tid >> 6, lane = tid & 63;
  int mg = blockIdx.x >> 2, ng = blockIdx.x & 3;
  int n0 = mg << 6;
  int quad = lane >> 4, lm = lane & 15;
  f32x4 acc[4][4];
#pragma unroll
  for (int i = 0; i < 4; ++i)
#pragma unroll
    for (int j = 0; j < 4; ++j) acc[i][j] = (f32x4){0.f, 0.f, 0.f, 0.f};
  for (int ks = 0; ks < 6; ++ks) {
    __syncthreads();
    {
      int mb = tid >> 6, ln = tid & 63;
      int lmm = ln & 15, qd = ln >> 4;
      const uint4* ga = (const uint4*)(xb + (size_t)(n0 + mb * 16 + lmm) * 192 + ks * 32 + qd * 8);
      *(uint4*)(Al + ((size_t)(mb * 64 + ln)) * 8) = *ga;
    }
#pragma unroll
    for (int nt2 = 0; nt2 < 2; ++nt2) {
#pragma unroll
      for (int u = 0; u < 2; ++u) {
        int unit = u * 256 + tid;
        const uint4* gb = (const uint4*)(wlb + ((size_t)((ng * 2 + nt2) * 6 + ks)) * 4096 + (size_t)unit * 8);
        *(uint4*)(Bl + (size_t)nt2 * 4096 + (size_t)unit * 8) = *gb;
      }
    }
    __syncthreads();
    bf16x8 af[4], bfr[4];
#pragma unroll
    for (int i = 0; i < 4; ++i)
      af[i] = *(const bf16x8*)(Al + ((size_t)(i * 64 + lane)) * 8);
    int nt2 = w >> 1, nbb = (w & 1) * 4;
#pragma unroll
    for (int j = 0; j < 4; ++j)
      bfr[j] = *(const bf16x8*)(Bl + (size_t)nt2 * 4096 + ((size_t)((nbb + j) * 64 + lane)) * 8);
#pragma unroll
    for (int i = 0; i < 4; ++i)
#pragma unroll
      for (int j = 0; j < 4; ++j)
        acc[i][j] = __builtin_amdgcn_mfma_f32_16x16x32_bf16(af[i], bfr[j], acc[i][j], 0, 0, 0);
  }
#pragma unroll
  for (int j = 0; j < 4; ++j) {
    float m = -3.4e38f;
#pragma unroll
    for (int i = 0; i < 4; ++i)
#pragma unroll
      for (int r = 0; r < 4; ++r) m = fmaxf(m, acc[i][j][r]);
    m = fmaxf(m, __shfl_xor(m, 16));
    m = fmaxf(m, __shfl_xor(m, 32));
    if (quad == 0) {
      int ch = ng * 256 + (w >> 1) * 128 + (w & 1) * 64 + j * 16 + lm;
      pool_part[(size_t)mg * 1024 + ch] = m;
    }
  }
}

// ---------------- Kernel 6: head MLP (32-way pool merge) ----------------
__global__ __launch_bounds__(256) void k_head(
    const float* __restrict__ pool_part, const float* __restrict__ bl,
    const float* __restrict__ sl, const float* __restrict__ hl,
    const float* __restrict__ wm1, const float* __restrict__ bm1,
    const float* __restrict__ sm1, const float* __restrict__ hm1,
    const float* __restrict__ wm2, const float* __restrict__ bm2,
    const float* __restrict__ sm2, const float* __restrict__ hm2,
    const float* __restrict__ wout, const float* __restrict__ bout,
    float* __restrict__ out) {
  __shared__ float p_s[1024], h1_s[512], h2_s[256];
  int b = blockIdx.x, tid = threadIdx.x;
  for (int c = tid; c < 1024; c += 256) {
    float m = -3.4e38f;
#pragma unroll 4
    for (int t = 0; t < 32; ++t)
      m = fmaxf(m, pool_part[(size_t)(b * 32 + t) * 1024 + c]);
    p_s[c] = relu_(m + bl[c]) * sl[c] + hl[c];
  }
  __syncthreads();
  for (int c = tid; c < 512; c += 256) {
    float a0 = 0, a1 = 0, a2 = 0, a3 = 0;
    for (int f = 0; f < 1024; f += 4) {
      a0 = fmaf(p_s[f], wm1[f * 512 + c], a0);
      a1 = fmaf(p_s[f + 1], wm1[(f + 1) * 512 + c], a1);
      a2 = fmaf(p_s[f + 2], wm1[(f + 2) * 512 + c], a2);
      a3 = fmaf(p_s[f + 3], wm1[(f + 3) * 512 + c], a3);
    }
    float a = (a0 + a1) + (a2 + a3);
    h1_s[c] = relu_(a + bm1[c]) * sm1[c] + hm1[c];
  }
  __syncthreads();
  if (tid < 256) {
    float a0 = 0, a1 = 0, a2 = 0, a3 = 0;
    for (int f = 0; f < 512; f += 4) {
      a0 = fmaf(h1_s[f], wm2[f * 256 + tid], a0);
      a1 = fmaf(h1_s[f + 1], wm2[(f + 1) * 256 + tid], a1);
      a2 = fmaf(h1_s[f + 2], wm2[(f + 2) * 256 + tid], a2);
      a3 = fmaf(h1_s[f + 3], wm2[(f + 3) * 256 + tid], a3);
    }
    float a = (a0 + a1) + (a2 + a3);
    h2_s[tid] = relu_(a + bm2[tid]) * sm2[tid] + hm2[tid];
  }
  __syncthreads();
  if (tid < 2) {
    float a0 = 0, a1 = 0;
    for (int f = 0; f < 256; f += 2) {
      a0 = fmaf(h2_s[f], wout[f * 2 + tid], a0);
      a1 = fmaf(h2_s[f + 1], wout[(f + 1) * 2 + tid], a1);
    }
    out[b * 2 + tid] = (a0 + a1) + bout[tid];
  }
}

extern "C" void kernel_launch(void* const* d_in, const int* in_sizes, int n_in,
                              void* d_out, int out_size, void* d_ws, size_t ws_size,
                              hipStream_t stream) {
  const float* pos = (const float*)d_in[0];
  const float* w1a = (const float*)d_in[1];
  const float* b1a = (const float*)d_in[2];
  const float* s1a = (const float*)d_in[3];
  const float* h1a = (const float*)d_in[4];
  const float* w1b = (const float*)d_in[5];
  const float* b1b = (const float*)d_in[6];
  const float* s1b = (const float*)d_in[7];
  const float* h1b = (const float*)d_in[8];
  const float* w1c = (const float*)d_in[9];
  const float* b1c = (const float*)d_in[10];
  const float* s1c = (const float*)d_in[11];
  const float* h1c = (const float*)d_in[12];
  const float* w2 = (const float*)d_in[13];
  const float* b2 = (const float*)d_in[14];
  const float* s2 = (const float*)d_in[15];
  const float* h2 = (const float*)d_in[16];
  const float* wl = (const float*)d_in[17];
  const float* bl = (const float*)d_in[18];
  const float* sl = (const float*)d_in[19];
  const float* hl = (const float*)d_in[20];
  const float* wm1 = (const float*)d_in[21];
  const float* bm1 = (const float*)d_in[22];
  const float* sm1 = (const float*)d_in[23];
  const float* hm1 = (const float*)d_in[24];
  const float* wm2 = (const float*)d_in[25];
  const float* bm2 = (const float*)d_in[26];
  const float* sm2 = (const float*)d_in[27];
  const float* hm2 = (const float*)d_in[28];
  const float* wout = (const float*)d_in[29];
  const float* bout = (const float*)d_in[30];
  float* out = (float*)d_out;

  // workspace: xh | xl | Pb | Qb | xb | idx | sq | wph/wpl/wfh/wfl | wlb (~77.6 MB)
  // wlb has its OWN region now (prep runs first; aliasing xh was the R13 bug).
  float* base = (float*)d_ws;
  __bf16* xh = (__bf16*)base;
  __bf16* xl = (__bf16*)(base + 2097152);
  float* PbF = base + 4194304;
  float* QbF = PbF + 4194304;
  float* xbF = QbF + 4194304;
  int* idx = (int*)(xbF + 6291456);
  float* sq = (float*)(idx + 327680);
  __bf16* wph = (__bf16*)(sq + 65536);
  __bf16* wpl = (__bf16*)(sq + 65536 + 8192);
  __bf16* wfh = (__bf16*)(sq + 65536 + 16384);
  __bf16* wfl = (__bf16*)(sq + 65536 + 20480);
  __bf16* wlb = (__bf16*)(sq + 65536 + 24576);   // dedicated 196,608 bf16 = 98,304 f
  __bf16* Pb = (__bf16*)PbF;
  __bf16* Qb = (__bf16*)QbF;
  __bf16* xb = (__bf16*)xbF;
  float* uR = PbF;                                // alias (dead until k_pq_mfma)
  float* vR = QbF;
  float* pool_part = base + 131072;               // overlaps xl/Pb head: both dead by linl

  k_prep_all<<<108, 256, 0, stream>>>(w1b, w1c, w2, wl, wfh, wfl, wph, wpl, wlb);
  k_knn1<<<2048, 256, 0, stream>>>(pos, idx);
  k_uv<<<1024, 256, 0, stream>>>(pos, w1a, b1a, uR, vR);
  k_edge1<<<1024, 256, 0, stream>>>(idx, uR, vR, s1a, h1a, b1b, s1b, h1b, b1c,
                                    s1c, h1c, wfh, wfl, xh, xl, sq, xb);
  k_knn2<<<1024, 256, 0, stream>>>(xh, xl, sq, idx);
  k_pq_mfma<<<1024, 256, 0, stream>>>(xh, xl, wph, wpl, Pb, Qb);
  k_gmax<<<32768, 256, 0, stream>>>(Pb, Qb, idx, b2, s2, h2, xb);
  k_linl_mfma<<<4096, 256, 0, stream>>>(xb, wlb, pool_part);
  k_head<<<32, 256, 0, stream>>>(pool_part, bl, sl, hl, wm1, bm1, sm1, hm1, wm2,
                                 bm2, sm2, hm2, wout, bout, out);
}

// Round 15
// 575.083 us; speedup vs baseline: 1.3928x; 1.0438x over previous
//
#include <hip/hip_runtime.h>

#define DEV __device__ __forceinline__
DEV float relu_(float x) { return fmaxf(x, 0.0f); }

typedef __attribute__((ext_vector_type(4))) float f32x4;
typedef __attribute__((ext_vector_type(8))) __bf16 bf16x8;

DEV unsigned short bfbits(__bf16 b) { union { unsigned short s; __bf16 b; } x; x.b = b; return x.s; }
DEV __bf16 bffrom(unsigned short s) { union { unsigned short s; __bf16 b; } x; x.s = s; return x.b; }

// branchy top-5 insert (R6-measured best for knn2's wave-coherent stream)
DEV void knn_insert(float (&bd)[5], int (&bi)[5], float d, int j) {
  if (d >= bd[4]) return;
  bd[4] = d; bi[4] = j;
#pragma unroll
  for (int p = 4; p > 0; --p) {
    if (bd[p] < bd[p - 1]) {
      float td = bd[p]; bd[p] = bd[p - 1]; bd[p - 1] = td;
      int ti = bi[p]; bi[p] = bi[p - 1]; bi[p - 1] = ti;
    }
  }
}

// branchless EXACT top-5 insert (used in knn1)
DEV void knn_insert_bl(float (&bd)[5], int (&bi)[5], float d, int j) {
#pragma unroll
  for (int p = 0; p < 5; ++p) {
    bool lt = d < bd[p];
    float nd = lt ? d : bd[p];
    float cd = lt ? bd[p] : d;
    int ni = lt ? j : bi[p];
    int ci = lt ? bi[p] : j;
    bd[p] = nd; d = cd;
    bi[p] = ni; j = ci;
  }
}

// ---------------- Kernel FRONT: knn1 (blk<2048) + uv (2048..3071) + preps (3072..3179) ----------------
// All three are independent functions of the inputs; merged to kill 2 launch gaps.
__global__ __launch_bounds__(256) void k_front(
    const float* __restrict__ pos, const float* __restrict__ w1a,
    const float* __restrict__ b1a, const float* __restrict__ w1b,
    const float* __restrict__ w1c, const float* __restrict__ w2,
    const float* __restrict__ wl,
    int* __restrict__ idx1, float* __restrict__ uR, float* __restrict__ vR,
    __bf16* __restrict__ wfh, __bf16* __restrict__ wfl,
    __bf16* __restrict__ wph, __bf16* __restrict__ wpl,
    __bf16* __restrict__ wlb) {
  __shared__ __align__(16) float smem[9472];  // union: knn1 (9472f) / uv (9152f)
  int tid = threadIdx.x;
  int blk = blockIdx.x;
  if (blk < 2048) {
    // ----- knn1: 8-way candidate split (byte-identical math to R14) -----
    float* ps = smem;            // 6144
    float* sqs = smem + 6144;    // 2048
    float* md = smem + 8192;     // 640
    int* mi = (int*)(smem + 8832);  // 640
    int b = blk >> 6, qc = blk & 63;
    const float* src = pos + b * 6144;
    for (int u = tid; u < 6144; u += 256) ps[u] = src[u];
    __syncthreads();
    for (int u = tid; u < 2048; u += 256) {
      float x = ps[u * 3], y = ps[u * 3 + 1], z = ps[u * 3 + 2];
      sqs[u] = fmaf(z, z, fmaf(y, y, x * x));
    }
    __syncthreads();
    int q = tid & 31, sub = tid >> 5;
    int qi = qc * 32 + q;
    float qx = ps[qi * 3], qy = ps[qi * 3 + 1], qz = ps[qi * 3 + 2];
    float qsq = sqs[qi];
    float bd[5] = {1e30f, 1e30f, 1e30f, 1e30f, 1e30f};
    int bi[5] = {0, 0, 0, 0, 0};
    int j0 = sub * 256;
    for (int j = j0; j < j0 + 256; ++j) {
      float px = ps[j * 3], py = ps[j * 3 + 1], pz = ps[j * 3 + 2];
      float dot = fmaf(qz, pz, fmaf(qy, py, qx * px));
      float d = (qsq + sqs[j]) - 2.0f * dot;
      knn_insert_bl(bd, bi, d, j);
    }
    for (int half = 4; half >= 1; half >>= 1) {
      __syncthreads();
      if (sub >= half && sub < 2 * half) {
        int slot = (q * 4 + (sub - half)) * 5;
#pragma unroll
        for (int k = 0; k < 5; ++k) { md[slot + k] = bd[k]; mi[slot + k] = bi[k]; }
      }
      __syncthreads();
      if (sub < half) {
        int slot = (q * 4 + sub) * 5;
#pragma unroll
        for (int k = 0; k < 5; ++k) knn_insert_bl(bd, bi, md[slot + k], mi[slot + k]);
      }
    }
    if (sub == 0) {
      int* op = idx1 + (b * 2048 + qi) * 5;
#pragma unroll
      for (int k = 0; k < 5; ++k) op[k] = bi[k];
    }
  } else if (blk < 3072) {
    // ----- uv: per-point u/v row-major, LDS-staged coalesced writes -----
    float* wAs = smem;           // 384
    float* bs = smem + 384;      // 64
    float* uS = smem + 448;      // 4352 (offset 1792B, 16B-aligned)
    float* vS = smem + 4800;     // 4352
    for (int u = tid; u < 384; u += 256) wAs[u] = w1a[u];
    if (tid < 64) bs[tid] = b1a[tid];
    __syncthreads();
    int lane = tid & 63, fq = tid >> 6;
    int p0 = (blk - 2048) * 64;
    int p = p0 + lane;
    float x0 = pos[p * 3], x1 = pos[p * 3 + 1], x2 = pos[p * 3 + 2];
#pragma unroll
    for (int m = 0; m < 16; ++m) {
      int f = fq * 16 + m;
      float wt0 = wAs[f], wt1 = wAs[64 + f], wt2 = wAs[128 + f];
      float wb0 = wAs[192 + f], wb1 = wAs[256 + f], wb2 = wAs[320 + f];
      float uval = bs[f];
      uval = fmaf(x0, wt0 - wb0, uval);
      uval = fmaf(x1, wt1 - wb1, uval);
      uval = fmaf(x2, wt2 - wb2, uval);
      uS[lane * 68 + f] = uval;
      vS[lane * 68 + f] = fmaf(x2, wb2, fmaf(x1, wb1, x0 * wb0));
    }
    __syncthreads();
#pragma unroll
    for (int it = 0; it < 4; ++it) {
      int g = it * 1024 + tid * 4;
      int pl = g >> 6, f = g & 63;
      float4 uu = *(const float4*)(uS + pl * 68 + f);
      float4 vv = *(const float4*)(vS + pl * 68 + f);
      *(float4*)(uR + (size_t)p0 * 64 + g) = uu;
      *(float4*)(vR + (size_t)p0 * 64 + g) = vv;
    }
  } else {
    int pblk = blk - 3072;
    if (pblk < 4) {
      int t = pblk * 256 + tid;
      int m = t >> 9;
      int rem = t & 511;
      int nb = rem >> 7;
      int rem2 = rem & 127;
      int s = rem2 >> 6, lane = rem2 & 63;
      int k0 = s * 32 + (lane >> 4) * 8;
      int c = nb * 16 + (lane & 15);
      const float* W = m ? w1c : w1b;
      __bf16 oh[8], ol[8];
#pragma unroll
      for (int j = 0; j < 8; ++j) {
        float val = W[(k0 + j) * 64 + c];
        __bf16 h = (__bf16)val;
        oh[j] = h;
        ol[j] = (__bf16)(val - (float)h);
      }
      size_t off = (size_t)m * 4096 + ((size_t)((nb * 2 + s) * 64 + lane)) * 8;
      *(uint4*)(wfh + off) = *(const uint4*)oh;
      *(uint4*)(wfl + off) = *(const uint4*)ol;
    } else if (pblk < 12) {
      int t = (pblk - 4) * 256 + tid;
      int nb = t >> 7;
      int rem = t & 127;
      int ks = rem >> 6, lane = rem & 63;
      int k0 = ks * 32 + (lane >> 4) * 8;
      int col16 = lane & 15;
      __bf16 oh[8], ol[8];
#pragma unroll
      for (int j = 0; j < 8; ++j) {
        int k = k0 + j;
        float val;
        if (nb < 8) {
          int c = nb * 16 + col16;
          val = w2[k * 128 + c] - w2[(64 + k) * 128 + c];
        } else {
          int c = (nb - 8) * 16 + col16;
          val = w2[(64 + k) * 128 + c];
        }
        __bf16 h = (__bf16)val;
        oh[j] = h;
        ol[j] = (__bf16)(val - (float)h);
      }
      *(uint4*)(wph + (size_t)t * 8) = *(const uint4*)oh;
      *(uint4*)(wpl + (size_t)t * 8) = *(const uint4*)ol;
    } else {
      int t = (pblk - 12) * 256 + tid;
      int nt = t / 3072;
      int rem = t - nt * 3072;
      int ks = rem / 512;
      int rem2 = rem - ks * 512;
      int nb = rem2 >> 6, lane = rem2 & 63;
      int k0 = ks * 32 + (lane >> 4) * 8;
      int n = nt * 128 + nb * 16 + (lane & 15);
      __bf16 o[8];
#pragma unroll
      for (int j = 0; j < 8; ++j) o[j] = (__bf16)wl[(k0 + j) * 1024 + n];
      *(uint4*)(wlb + (size_t)t * 8) = *(const uint4*)o;
    }
  }
}

// ---------------- Kernel 2: EdgeConv1 layers 2/3 via hi/lo MFMA, barrier-free k-loop ----------------
__global__ __launch_bounds__(256) void k_edge1(
    const int* __restrict__ idx1, const float* __restrict__ uR,
    const float* __restrict__ vR,
    const float* __restrict__ s1a, const float* __restrict__ h1a,
    const float* __restrict__ b1b, const float* __restrict__ s1b,
    const float* __restrict__ h1b,
    const float* __restrict__ b1c, const float* __restrict__ s1c,
    const float* __restrict__ h1c,
    const __bf16* __restrict__ wfh, const __bf16* __restrict__ wfl,
    __bf16* __restrict__ xh, __bf16* __restrict__ xl,
    float* __restrict__ sqo, __bf16* __restrict__ xb) {
  __shared__ __align__(16) __bf16 Wh[8192], Wl[8192];
  __shared__ __align__(16) unsigned h2b[4 * 1088];
  int tid = threadIdx.x;
  int w = tid >> 6, lane = tid & 63;
  int quad = lane >> 4, lm = lane & 15;
#pragma unroll
  for (int it = 0; it < 4; ++it) {
    int u4 = it * 256 + tid;
    *(uint4*)(Wh + (size_t)u4 * 8) = *(const uint4*)(wfh + (size_t)u4 * 8);
    *(uint4*)(Wl + (size_t)u4 * 8) = *(const uint4*)(wfl + (size_t)u4 * 8);
  }
  int p0 = blockIdx.x * 64;
  int b = p0 >> 11;
  size_t bb = (size_t)b * 2048;
  int edge = p0 + w * 16 + lm;
  float sA[2][8], hA[2][8];
#pragma unroll
  for (int s = 0; s < 2; ++s)
#pragma unroll
    for (int j = 0; j < 8; ++j) {
      int k = s * 32 + quad * 8 + j;
      sA[s][j] = s1a[k]; hA[s][j] = h1a[k];
    }
  float bB[4], sB[4], hB[4], bC[4], sC[4], hC[4];
#pragma unroll
  for (int nb = 0; nb < 4; ++nb) {
    int c = nb * 16 + lm;
    bB[nb] = b1b[c]; sB[nb] = s1b[c]; hB[nb] = h1b[c];
    bC[nb] = b1c[c]; sC[nb] = s1c[c]; hC[nb] = h1c[c];
  }
  unsigned* h2w = h2b + w * 1088;
  f32x4 mmax[4];
#pragma unroll
  for (int nb = 0; nb < 4; ++nb)
    mmax[nb] = (f32x4){-3.4e38f, -3.4e38f, -3.4e38f, -3.4e38f};
  __syncthreads();
  const float* urow = uR + (size_t)edge * 64;
  for (int kk = 0; kk < 5; ++kk) {
    int jn = idx1[edge * 5 + kk];
    const float* vrow = vR + (bb + jn) * 64;
    bf16x8 Ah[2], Al[2];
#pragma unroll
    for (int s = 0; s < 2; ++s) {
      int off = s * 32 + quad * 8;
      float4 u0 = *(const float4*)(urow + off);
      float4 u1 = *(const float4*)(urow + off + 4);
      float4 v0 = *(const float4*)(vrow + off);
      float4 v1 = *(const float4*)(vrow + off + 4);
      float uv[8] = {u0.x + v0.x, u0.y + v0.y, u0.z + v0.z, u0.w + v0.w,
                     u1.x + v1.x, u1.y + v1.y, u1.z + v1.z, u1.w + v1.w};
      __bf16 th[8], tl[8];
#pragma unroll
      for (int j = 0; j < 8; ++j) {
        float val = relu_(uv[j]) * sA[s][j] + hA[s][j];
        __bf16 hb = (__bf16)val;
        th[j] = hb;
        tl[j] = (__bf16)(val - (float)hb);
      }
      Ah[s] = *(const bf16x8*)th;
      Al[s] = *(const bf16x8*)tl;
    }
#pragma unroll
    for (int nb = 0; nb < 4; ++nb) {
      bf16x8 Bh0 = *(const bf16x8*)(Wh + ((size_t)((nb * 2 + 0) * 64 + lane)) * 8);
      bf16x8 Bh1 = *(const bf16x8*)(Wh + ((size_t)((nb * 2 + 1) * 64 + lane)) * 8);
      bf16x8 Bl0 = *(const bf16x8*)(Wl + ((size_t)((nb * 2 + 0) * 64 + lane)) * 8);
      bf16x8 Bl1 = *(const bf16x8*)(Wl + ((size_t)((nb * 2 + 1) * 64 + lane)) * 8);
      f32x4 a2 = {0.f, 0.f, 0.f, 0.f};
      a2 = __builtin_amdgcn_mfma_f32_16x16x32_bf16(Ah[0], Bh0, a2, 0, 0, 0);
      a2 = __builtin_amdgcn_mfma_f32_16x16x32_bf16(Ah[1], Bh1, a2, 0, 0, 0);
      a2 = __builtin_amdgcn_mfma_f32_16x16x32_bf16(Ah[0], Bl0, a2, 0, 0, 0);
      a2 = __builtin_amdgcn_mfma_f32_16x16x32_bf16(Ah[1], Bl1, a2, 0, 0, 0);
      a2 = __builtin_amdgcn_mfma_f32_16x16x32_bf16(Al[0], Bh0, a2, 0, 0, 0);
      a2 = __builtin_amdgcn_mfma_f32_16x16x32_bf16(Al[1], Bh1, a2, 0, 0, 0);
#pragma unroll
      for (int r = 0; r < 4; ++r) {
        float vv2 = relu_(a2[r] + bB[nb]) * sB[nb] + hB[nb];
        __bf16 hb = (__bf16)vv2;
        __bf16 lb = (__bf16)(vv2 - (float)hb);
        h2w[(quad * 4 + r) * 68 + nb * 16 + lm] =
            (unsigned)bfbits(hb) | ((unsigned)bfbits(lb) << 16);
      }
    }
    bf16x8 A3h[2], A3l[2];
#pragma unroll
    for (int s = 0; s < 2; ++s) {
      const unsigned* rp = h2w + lm * 68 + s * 32 + quad * 8;
      uint4 da = *(const uint4*)rp;
      uint4 db = *(const uint4*)(rp + 4);
      unsigned dw[8] = {da.x, da.y, da.z, da.w, db.x, db.y, db.z, db.w};
      __bf16 th[8], tl[8];
#pragma unroll
      for (int j = 0; j < 8; ++j) {
        th[j] = bffrom((unsigned short)(dw[j] & 0xFFFFu));
        tl[j] = bffrom((unsigned short)(dw[j] >> 16));
      }
      A3h[s] = *(const bf16x8*)th;
      A3l[s] = *(const bf16x8*)tl;
    }
#pragma unroll
    for (int nb = 0; nb < 4; ++nb) {
      bf16x8 Bh0 = *(const bf16x8*)(Wh + 4096 + ((size_t)((nb * 2 + 0) * 64 + lane)) * 8);
      bf16x8 Bh1 = *(const bf16x8*)(Wh + 4096 + ((size_t)((nb * 2 + 1) * 64 + lane)) * 8);
      bf16x8 Bl0 = *(const bf16x8*)(Wl + 4096 + ((size_t)((nb * 2 + 0) * 64 + lane)) * 8);
      bf16x8 Bl1 = *(const bf16x8*)(Wl + 4096 + ((size_t)((nb * 2 + 1) * 64 + lane)) * 8);
      f32x4 a3 = {0.f, 0.f, 0.f, 0.f};
      a3 = __builtin_amdgcn_mfma_f32_16x16x32_bf16(A3h[0], Bh0, a3, 0, 0, 0);
      a3 = __builtin_amdgcn_mfma_f32_16x16x32_bf16(A3h[1], Bh1, a3, 0, 0, 0);
      a3 = __builtin_amdgcn_mfma_f32_16x16x32_bf16(A3h[0], Bl0, a3, 0, 0, 0);
      a3 = __builtin_amdgcn_mfma_f32_16x16x32_bf16(A3h[1], Bl1, a3, 0, 0, 0);
      a3 = __builtin_amdgcn_mfma_f32_16x16x32_bf16(A3l[0], Bh0, a3, 0, 0, 0);
      a3 = __builtin_amdgcn_mfma_f32_16x16x32_bf16(A3l[1], Bh1, a3, 0, 0, 0);
#pragma unroll
      for (int r = 0; r < 4; ++r) mmax[nb][r] = fmaxf(mmax[nb][r], a3[r]);
    }
  }
  float sqp[4] = {0.f, 0.f, 0.f, 0.f};
#pragma unroll
  for (int nb = 0; nb < 4; ++nb) {
    int c = nb * 16 + lm;
#pragma unroll
    for (int r = 0; r < 4; ++r) {
      float vv3 = relu_(mmax[nb][r] + bC[nb]) * sC[nb] + hC[nb];
      sqp[r] = fmaf(vv3, vv3, sqp[r]);
      __bf16 hb = (__bf16)vv3;
      __bf16 lb = (__bf16)(vv3 - (float)hb);
      int n = p0 + w * 16 + quad * 4 + r;
      xh[(size_t)n * 64 + c] = hb;
      xl[(size_t)n * 64 + c] = lb;
      xb[(size_t)n * 192 + c] = hb;
    }
  }
#pragma unroll
  for (int r = 0; r < 4; ++r) {
    float s = sqp[r];
    s += __shfl_xor(s, 1);
    s += __shfl_xor(s, 2);
    s += __shfl_xor(s, 4);
    s += __shfl_xor(s, 8);
    if (lm == 0) sqo[p0 + w * 16 + quad * 4 + r] = s;
  }
}

// ---------------- Kernel 3: kNN on x1 via MFMA hi/lo (R6-measured best config) ----------------
__global__ __launch_bounds__(256) void k_knn2(const __bf16* __restrict__ xh,
                                              const __bf16* __restrict__ xl,
                                              const float* __restrict__ sq,
                                              int* __restrict__ idx2) {
  __shared__ __align__(16) __bf16 Bh[64 * 72];
  __shared__ __align__(16) __bf16 Bl[64 * 72];
  __shared__ float sqs[2048];
  int tid = threadIdx.x;
  int w = tid >> 6, lane = tid & 63;
  int quad = lane >> 4, lm = lane & 15;
  int b = blockIdx.x >> 5, qc = blockIdx.x & 31;
  int q0 = qc * 64;
  size_t bb = (size_t)b * 2048;
  for (int u = tid; u < 512; u += 256)
    *(float4*)(sqs + u * 4) = *(const float4*)(sq + bb + u * 4);
  const __bf16* qh = xh + (bb + q0 + w * 16 + lm) * 64 + quad * 8;
  const __bf16* ql = xl + (bb + q0 + w * 16 + lm) * 64 + quad * 8;
  bf16x8 Ah0 = *(const bf16x8*)(qh);
  bf16x8 Ah1 = *(const bf16x8*)(qh + 32);
  bf16x8 Al0 = *(const bf16x8*)(ql);
  bf16x8 Al1 = *(const bf16x8*)(ql + 32);
  __syncthreads();
  float qsq[4];
#pragma unroll
  for (int r = 0; r < 4; ++r) qsq[r] = sqs[q0 + w * 16 + quad * 4 + r];
  float bd[4][5];
  int bi[4][5];
#pragma unroll
  for (int r = 0; r < 4; ++r)
#pragma unroll
    for (int k = 0; k < 5; ++k) { bd[r][k] = 1e30f; bi[r][k] = 0; }
  for (int ct = 0; ct < 32; ++ct) {
#pragma unroll
    for (int pass = 0; pass < 2; ++pass) {
      int unit = pass * 256 + tid;
      int n = unit >> 3, cc = unit & 7;
      const __bf16* gsrc = xh + (bb + ct * 64 + n) * 64 + cc * 8;
      const __bf16* gsrl = xl + (bb + ct * 64 + n) * 64 + cc * 8;
      *(uint4*)(Bh + n * 72 + cc * 8) = *(const uint4*)gsrc;
      *(uint4*)(Bl + n * 72 + cc * 8) = *(const uint4*)gsrl;
    }
    __syncthreads();
#pragma unroll
    for (int nt = 0; nt < 4; ++nt) {
      const __bf16* bph = Bh + (nt * 16 + lm) * 72 + quad * 8;
      const __bf16* bpl = Bl + (nt * 16 + lm) * 72 + quad * 8;
      bf16x8 Bh0 = *(const bf16x8*)(bph);
      bf16x8 Bh1 = *(const bf16x8*)(bph + 32);
      bf16x8 Bl0 = *(const bf16x8*)(bpl);
      bf16x8 Bl1 = *(const bf16x8*)(bpl + 32);
      f32x4 acc = {0.f, 0.f, 0.f, 0.f};
      acc = __builtin_amdgcn_mfma_f32_16x16x32_bf16(Ah0, Bh0, acc, 0, 0, 0);
      acc = __builtin_amdgcn_mfma_f32_16x16x32_bf16(Ah1, Bh1, acc, 0, 0, 0);
      acc = __builtin_amdgcn_mfma_f32_16x16x32_bf16(Ah0, Bl0, acc, 0, 0, 0);
      acc = __builtin_amdgcn_mfma_f32_16x16x32_bf16(Ah1, Bl1, acc, 0, 0, 0);
      acc = __builtin_amdgcn_mfma_f32_16x16x32_bf16(Al0, Bh0, acc, 0, 0, 0);
      acc = __builtin_amdgcn_mfma_f32_16x16x32_bf16(Al1, Bh1, acc, 0, 0, 0);
      int cid = ct * 64 + nt * 16 + lm;
      float csq = sqs[cid];
#pragma unroll
      for (int r = 0; r < 4; ++r) {
        float d = (qsq[r] + csq) - 2.0f * acc[r];
        knn_insert(bd[r], bi[r], d, cid);
      }
    }
    __syncthreads();
  }
  for (int m = 1; m <= 8; m <<= 1) {
#pragma unroll
    for (int r = 0; r < 4; ++r) {
      float od[5]; int oi[5];
#pragma unroll
      for (int k = 0; k < 5; ++k) {
        od[k] = __shfl_xor(bd[r][k], m);
        oi[k] = __shfl_xor(bi[r][k], m);
      }
#pragma unroll
      for (int k = 0; k < 5; ++k) knn_insert(bd[r], bi[r], od[k], oi[k]);
    }
  }
  if (lm == 0) {
#pragma unroll
    for (int r = 0; r < 4; ++r) {
      int qi = q0 + w * 16 + quad * 4 + r;
      int* op = idx2 + (bb + qi) * 5;
#pragma unroll
      for (int k = 0; k < 5; ++k) op[k] = bi[r][k];
    }
  }
}

// ---------------- Kernel 4a: P/Q via hi/lo MFMA ----------------
__global__ __launch_bounds__(256) void k_pq_mfma(const __bf16* __restrict__ xh,
                                                 const __bf16* __restrict__ xl,
                                                 const __bf16* __restrict__ wph,
                                                 const __bf16* __restrict__ wpl,
                                                 __bf16* __restrict__ Pb,
                                                 __bf16* __restrict__ Qb) {
  __shared__ __align__(16) __bf16 Wh[16384];
  __shared__ __align__(16) __bf16 Wl[16384];
  int tid = threadIdx.x;
  int w = tid >> 6, lane = tid & 63;
  int quad = lane >> 4, lm = lane & 15;
  int n0 = blockIdx.x * 64;
#pragma unroll
  for (int it = 0; it < 8; ++it) {
    int unit = it * 256 + tid;
    *(uint4*)(Wh + (size_t)unit * 8) = *(const uint4*)(wph + (size_t)unit * 8);
    *(uint4*)(Wl + (size_t)unit * 8) = *(const uint4*)(wpl + (size_t)unit * 8);
  }
  const __bf16* ah = xh + (size_t)(n0 + w * 16 + lm) * 64 + quad * 8;
  const __bf16* al = xl + (size_t)(n0 + w * 16 + lm) * 64 + quad * 8;
  bf16x8 Ah0 = *(const bf16x8*)(ah);
  bf16x8 Ah1 = *(const bf16x8*)(ah + 32);
  bf16x8 Al0 = *(const bf16x8*)(al);
  bf16x8 Al1 = *(const bf16x8*)(al + 32);
  __syncthreads();
  f32x4 acc[16];
#pragma unroll
  for (int nb = 0; nb < 16; ++nb) acc[nb] = (f32x4){0.f, 0.f, 0.f, 0.f};
#pragma unroll 4
  for (int nb = 0; nb < 16; ++nb) {
    bf16x8 Bh0 = *(const bf16x8*)(Wh + ((size_t)(nb * 2 + 0) * 64 + lane) * 8);
    bf16x8 Bh1 = *(const bf16x8*)(Wh + ((size_t)(nb * 2 + 1) * 64 + lane) * 8);
    bf16x8 Bl0 = *(const bf16x8*)(Wl + ((size_t)(nb * 2 + 0) * 64 + lane) * 8);
    bf16x8 Bl1 = *(const bf16x8*)(Wl + ((size_t)(nb * 2 + 1) * 64 + lane) * 8);
    acc[nb] = __builtin_amdgcn_mfma_f32_16x16x32_bf16(Ah0, Bh0, acc[nb], 0, 0, 0);
    acc[nb] = __builtin_amdgcn_mfma_f32_16x16x32_bf16(Ah1, Bh1, acc[nb], 0, 0, 0);
    acc[nb] = __builtin_amdgcn_mfma_f32_16x16x32_bf16(Ah0, Bl0, acc[nb], 0, 0, 0);
    acc[nb] = __builtin_amdgcn_mfma_f32_16x16x32_bf16(Ah1, Bl1, acc[nb], 0, 0, 0);
    acc[nb] = __builtin_amdgcn_mfma_f32_16x16x32_bf16(Al0, Bh0, acc[nb], 0, 0, 0);
    acc[nb] = __builtin_amdgcn_mfma_f32_16x16x32_bf16(Al1, Bh1, acc[nb], 0, 0, 0);
  }
#pragma unroll
  for (int nb = 0; nb < 16; ++nb) {
    bool isP = (nb < 8);
    __bf16* base = isP ? Pb : Qb;
    int col = (isP ? nb : nb - 8) * 16 + lm;
#pragma unroll
    for (int r = 0; r < 4; ++r) {
      int n = n0 + w * 16 + quad * 4 + r;
      base[(size_t)n * 128 + col] = (__bf16)acc[nb][r];
    }
  }
}

// ---------------- Kernel 4b: gather-max + activation, 2 channels/lane ----------------
// grid 16384 (4 points/block); per-channel math order identical to R14 (bit-exact)
__global__ __launch_bounds__(256) void k_gmax(const __bf16* __restrict__ Pb,
                                              const __bf16* __restrict__ Qb,
                                              const int* __restrict__ idx2,
                                              const float* __restrict__ b2,
                                              const float* __restrict__ s2,
                                              const float* __restrict__ h2v,
                                              __bf16* __restrict__ xb) {
  int tid = threadIdx.x;
  int c2 = tid & 63, p = tid >> 6;  // channels 2*c2, 2*c2+1
  int n = blockIdx.x * 4 + p;
  int b = n >> 11;
  const int* ip = idx2 + n * 5;
  int c0 = c2 * 2;
  float m0 = -3.4e38f, m1 = -3.4e38f;
#pragma unroll
  for (int k = 0; k < 5; ++k) {
    int j = ip[k];
    unsigned q = *(const unsigned*)(Qb + ((size_t)(b * 2048 + j)) * 128 + c0);
    m0 = fmaxf(m0, (float)bffrom((unsigned short)(q & 0xFFFFu)));
    m1 = fmaxf(m1, (float)bffrom((unsigned short)(q >> 16)));
  }
  unsigned pv = *(const unsigned*)(Pb + (size_t)n * 128 + c0);
  float v0 = (float)bffrom((unsigned short)(pv & 0xFFFFu)) + m0 + b2[c0];
  float v1 = (float)bffrom((unsigned short)(pv >> 16)) + m1 + b2[c0 + 1];
  __bf16 o0 = (__bf16)(relu_(v0) * s2[c0] + h2v[c0]);
  __bf16 o1 = (__bf16)(relu_(v1) * s2[c0 + 1] + h2v[c0 + 1]);
  unsigned ov = (unsigned)bfbits(o0) | ((unsigned)bfbits(o1) << 16);
  *(unsigned*)(xb + (size_t)n * 192 + 64 + c0) = ov;
}

// ---------------- Kernel 5: bf16 MFMA GEMM fused point-max, 64m x 256n tiles ----------------
__global__ __launch_bounds__(256) void k_linl_mfma(const __bf16* __restrict__ xb,
                                                   const __bf16* __restrict__ wlb,
                                                   float* __restrict__ pool_part) {
  __shared__ __align__(16) __bf16 Al[2048];
  __shared__ __align__(16) __bf16 Bl[8192];
  int tid = threadIdx.x;
  int w = tid >> 6, lane = tid & 63;
  int mg = blockIdx.x >> 2, ng = blockIdx.x & 3;
  int n0 = mg << 6;
  int quad = lane >> 4, lm = lane & 15;
  f32x4 acc[4][4];
#pragma unroll
  for (int i = 0; i < 4; ++i)
#pragma unroll
    for (int j = 0; j < 4; ++j) acc[i][j] = (f32x4){0.f, 0.f, 0.f, 0.f};
  for (int ks = 0; ks < 6; ++ks) {
    __syncthreads();
    {
      int mb = tid >> 6, ln = tid & 63;
      int lmm = ln & 15, qd = ln >> 4;
      const uint4* ga = (const uint4*)(xb + (size_t)(n0 + mb * 16 + lmm) * 192 + ks * 32 + qd * 8);
      *(uint4*)(Al + ((size_t)(mb * 64 + ln)) * 8) = *ga;
    }
#pragma unroll
    for (int nt2 = 0; nt2 < 2; ++nt2) {
#pragma unroll
      for (int u = 0; u < 2; ++u) {
        int unit = u * 256 + tid;
        const uint4* gb = (const uint4*)(wlb + ((size_t)((ng * 2 + nt2) * 6 + ks)) * 4096 + (size_t)unit * 8);
        *(uint4*)(Bl + (size_t)nt2 * 4096 + (size_t)unit * 8) = *gb;
      }
    }
    __syncthreads();
    bf16x8 af[4], bfr[4];
#pragma unroll
    for (int i = 0; i < 4; ++i)
      af[i] = *(const bf16x8*)(Al + ((size_t)(i * 64 + lane)) * 8);
    int nt2 = w >> 1, nbb = (w & 1) * 4;
#pragma unroll
    for (int j = 0; j < 4; ++j)
      bfr[j] = *(const bf16x8*)(Bl + (size_t)nt2 * 4096 + ((size_t)((nbb + j) * 64 + lane)) * 8);
#pragma unroll
    for (int i = 0; i < 4; ++i)
#pragma unroll
      for (int j = 0; j < 4; ++j)
        acc[i][j] = __builtin_amdgcn_mfma_f32_16x16x32_bf16(af[i], bfr[j], acc[i][j], 0, 0, 0);
  }
#pragma unroll
  for (int j = 0; j < 4; ++j) {
    float m = -3.4e38f;
#pragma unroll
    for (int i = 0; i < 4; ++i)
#pragma unroll
      for (int r = 0; r < 4; ++r) m = fmaxf(m, acc[i][j][r]);
    m = fmaxf(m, __shfl_xor(m, 16));
    m = fmaxf(m, __shfl_xor(m, 32));
    if (quad == 0) {
      int ch = ng * 256 + (w >> 1) * 128 + (w & 1) * 64 + j * 16 + lm;
      pool_part[(size_t)mg * 1024 + ch] = m;
    }
  }
}

// ---------------- Kernel 6: head MLP (32-way pool merge) ----------------
__global__ __launch_bounds__(256) void k_head(
    const float* __restrict__ pool_part, const float* __restrict__ bl,
    const float* __restrict__ sl, const float* __restrict__ hl,
    const float* __restrict__ wm1, const float* __restrict__ bm1,
    const float* __restrict__ sm1, const float* __restrict__ hm1,
    const float* __restrict__ wm2, const float* __restrict__ bm2,
    const float* __restrict__ sm2, const float* __restrict__ hm2,
    const float* __restrict__ wout, const float* __restrict__ bout,
    float* __restrict__ out) {
  __shared__ float p_s[1024], h1_s[512], h2_s[256];
  int b = blockIdx.x, tid = threadIdx.x;
  for (int c = tid; c < 1024; c += 256) {
    float m = -3.4e38f;
#pragma unroll 4
    for (int t = 0; t < 32; ++t)
      m = fmaxf(m, pool_part[(size_t)(b * 32 + t) * 1024 + c]);
    p_s[c] = relu_(m + bl[c]) * sl[c] + hl[c];
  }
  __syncthreads();
  for (int c = tid; c < 512; c += 256) {
    float a0 = 0, a1 = 0, a2 = 0, a3 = 0;
    for (int f = 0; f < 1024; f += 4) {
      a0 = fmaf(p_s[f], wm1[f * 512 + c], a0);
      a1 = fmaf(p_s[f + 1], wm1[(f + 1) * 512 + c], a1);
      a2 = fmaf(p_s[f + 2], wm1[(f + 2) * 512 + c], a2);
      a3 = fmaf(p_s[f + 3], wm1[(f + 3) * 512 + c], a3);
    }
    float a = (a0 + a1) + (a2 + a3);
    h1_s[c] = relu_(a + bm1[c]) * sm1[c] + hm1[c];
  }
  __syncthreads();
  if (tid < 256) {
    float a0 = 0, a1 = 0, a2 = 0, a3 = 0;
    for (int f = 0; f < 512; f += 4) {
      a0 = fmaf(h1_s[f], wm2[f * 256 + tid], a0);
      a1 = fmaf(h1_s[f + 1], wm2[(f + 1) * 256 + tid], a1);
      a2 = fmaf(h1_s[f + 2], wm2[(f + 2) * 256 + tid], a2);
      a3 = fmaf(h1_s[f + 3], wm2[(f + 3) * 256 + tid], a3);
    }
    float a = (a0 + a1) + (a2 + a3);
    h2_s[tid] = relu_(a + bm2[tid]) * sm2[tid] + hm2[tid];
  }
  __syncthreads();
  if (tid < 2) {
    float a0 = 0, a1 = 0;
    for (int f = 0; f < 256; f += 2) {
      a0 = fmaf(h2_s[f], wout[f * 2 + tid], a0);
      a1 = fmaf(h2_s[f + 1], wout[(f + 1) * 2 + tid], a1);
    }
    out[b * 2 + tid] = (a0 + a1) + bout[tid];
  }
}

extern "C" void kernel_launch(void* const* d_in, const int* in_sizes, int n_in,
                              void* d_out, int out_size, void* d_ws, size_t ws_size,
                              hipStream_t stream) {
  const float* pos = (const float*)d_in[0];
  const float* w1a = (const float*)d_in[1];
  const float* b1a = (const float*)d_in[2];
  const float* s1a = (const float*)d_in[3];
  const float* h1a = (const float*)d_in[4];
  const float* w1b = (const float*)d_in[5];
  const float* b1b = (const float*)d_in[6];
  const float* s1b = (const float*)d_in[7];
  const float* h1b = (const float*)d_in[8];
  const float* w1c = (const float*)d_in[9];
  const float* b1c = (const float*)d_in[10];
  const float* s1c = (const float*)d_in[11];
  const float* h1c = (const float*)d_in[12];
  const float* w2 = (const float*)d_in[13];
  const float* b2 = (const float*)d_in[14];
  const float* s2 = (const float*)d_in[15];
  const float* h2 = (const float*)d_in[16];
  const float* wl = (const float*)d_in[17];
  const float* bl = (const float*)d_in[18];
  const float* sl = (const float*)d_in[19];
  const float* hl = (const float*)d_in[20];
  const float* wm1 = (const float*)d_in[21];
  const float* bm1 = (const float*)d_in[22];
  const float* sm1 = (const float*)d_in[23];
  const float* hm1 = (const float*)d_in[24];
  const float* wm2 = (const float*)d_in[25];
  const float* bm2 = (const float*)d_in[26];
  const float* sm2 = (const float*)d_in[27];
  const float* hm2 = (const float*)d_in[28];
  const float* wout = (const float*)d_in[29];
  const float* bout = (const float*)d_in[30];
  float* out = (float*)d_out;

  // workspace: xh | xl | Pb | Qb | xb | idx | sq | wph/wpl/wfh/wfl | wlb (~77.6 MB)
  float* base = (float*)d_ws;
  __bf16* xh = (__bf16*)base;
  __bf16* xl = (__bf16*)(base + 2097152);
  float* PbF = base + 4194304;
  float* QbF = PbF + 4194304;
  float* xbF = QbF + 4194304;
  int* idx = (int*)(xbF + 6291456);
  float* sq = (float*)(idx + 327680);
  __bf16* wph = (__bf16*)(sq + 65536);
  __bf16* wpl = (__bf16*)(sq + 65536 + 8192);
  __bf16* wfh = (__bf16*)(sq + 65536 + 16384);
  __bf16* wfl = (__bf16*)(sq + 65536 + 20480);
  __bf16* wlb = (__bf16*)(sq + 65536 + 24576);   // dedicated region
  __bf16* Pb = (__bf16*)PbF;
  __bf16* Qb = (__bf16*)QbF;
  __bf16* xb = (__bf16*)xbF;
  float* uR = PbF;                                // alias (dead until k_pq_mfma)
  float* vR = QbF;
  float* pool_part = base + 131072;               // overlaps xl/Pb head: dead by linl

  k_front<<<3180, 256, 0, stream>>>(pos, w1a, b1a, w1b, w1c, w2, wl, idx, uR, vR,
                                    wfh, wfl, wph, wpl, wlb);
  k_edge1<<<1024, 256, 0, stream>>>(idx, uR, vR, s1a, h1a, b1b, s1b, h1b, b1c,
                                    s1c, h1c, wfh, wfl, xh, xl, sq, xb);
  k_knn2<<<1024, 256, 0, stream>>>(xh, xl, sq, idx);
  k_pq_mfma<<<1024, 256, 0, stream>>>(xh, xl, wph, wpl, Pb, Qb);
  k_gmax<<<16384, 256, 0, stream>>>(Pb, Qb, idx, b2, s2, h2, xb);
  k_linl_mfma<<<4096, 256, 0, stream>>>(xb, wlb, pool_part);
  k_head<<<32, 256, 0, stream>>>(pool_part, bl, sl, hl, wm1, bm1, sm1, hm1, wm2,
                                 bm2, sm2, hm2, wout, bout, out);
}

// Round 16
// 574.572 us; speedup vs baseline: 1.3941x; 1.0009x over previous
//
#include <hip/hip_runtime.h>

#define DEV __device__ __forceinline__
DEV float relu_(float x) { return fmaxf(x, 0.0f); }

typedef __attribute__((ext_vector_type(4))) float f32x4;
typedef __attribute__((ext_vector_type(8))) __bf16 bf16x8;

DEV unsigned short bfbits(__bf16 b) { union { unsigned short s; __bf16 b; } x; x.b = b; return x.s; }
DEV __bf16 bffrom(unsigned short s) { union { unsigned short s; __bf16 b; } x; x.s = s; return x.b; }

// branchy top-5 insert (R6-measured best for knn2's wave-coherent stream)
DEV void knn_insert(float (&bd)[5], int (&bi)[5], float d, int j) {
  if (d >= bd[4]) return;
  bd[4] = d; bi[4] = j;
#pragma unroll
  for (int p = 4; p > 0; --p) {
    if (bd[p] < bd[p - 1]) {
      float td = bd[p]; bd[p] = bd[p - 1]; bd[p - 1] = td;
      int ti = bi[p]; bi[p] = bi[p - 1]; bi[p - 1] = ti;
    }
  }
}

// branchless EXACT top-5 insert (used in knn1)
DEV void knn_insert_bl(float (&bd)[5], int (&bi)[5], float d, int j) {
#pragma unroll
  for (int p = 0; p < 5; ++p) {
    bool lt = d < bd[p];
    float nd = lt ? d : bd[p];
    float cd = lt ? bd[p] : d;
    int ni = lt ? j : bi[p];
    int ci = lt ? bi[p] : j;
    bd[p] = nd; d = cd;
    bi[p] = ni; j = ci;
  }
}

// ---------------- Kernel FRONT: knn1 (blk<2048) + uv (2048..3071) + preps (3072..3179) ----------------
__global__ __launch_bounds__(256) void k_front(
    const float* __restrict__ pos, const float* __restrict__ w1a,
    const float* __restrict__ b1a, const float* __restrict__ w1b,
    const float* __restrict__ w1c, const float* __restrict__ w2,
    const float* __restrict__ wl,
    int* __restrict__ idx1, float* __restrict__ uR, float* __restrict__ vR,
    __bf16* __restrict__ wfh, __bf16* __restrict__ wfl,
    __bf16* __restrict__ wph, __bf16* __restrict__ wpl,
    __bf16* __restrict__ wlb) {
  __shared__ __align__(16) float smem[9472];
  int tid = threadIdx.x;
  int blk = blockIdx.x;
  if (blk < 2048) {
    float* ps = smem;
    float* sqs = smem + 6144;
    float* md = smem + 8192;
    int* mi = (int*)(smem + 8832);
    int b = blk >> 6, qc = blk & 63;
    const float* src = pos + b * 6144;
    for (int u = tid; u < 6144; u += 256) ps[u] = src[u];
    __syncthreads();
    for (int u = tid; u < 2048; u += 256) {
      float x = ps[u * 3], y = ps[u * 3 + 1], z = ps[u * 3 + 2];
      sqs[u] = fmaf(z, z, fmaf(y, y, x * x));
    }
    __syncthreads();
    int q = tid & 31, sub = tid >> 5;
    int qi = qc * 32 + q;
    float qx = ps[qi * 3], qy = ps[qi * 3 + 1], qz = ps[qi * 3 + 2];
    float qsq = sqs[qi];
    float bd[5] = {1e30f, 1e30f, 1e30f, 1e30f, 1e30f};
    int bi[5] = {0, 0, 0, 0, 0};
    int j0 = sub * 256;
    for (int j = j0; j < j0 + 256; ++j) {
      float px = ps[j * 3], py = ps[j * 3 + 1], pz = ps[j * 3 + 2];
      float dot = fmaf(qz, pz, fmaf(qy, py, qx * px));
      float d = (qsq + sqs[j]) - 2.0f * dot;
      knn_insert_bl(bd, bi, d, j);
    }
    for (int half = 4; half >= 1; half >>= 1) {
      __syncthreads();
      if (sub >= half && sub < 2 * half) {
        int slot = (q * 4 + (sub - half)) * 5;
#pragma unroll
        for (int k = 0; k < 5; ++k) { md[slot + k] = bd[k]; mi[slot + k] = bi[k]; }
      }
      __syncthreads();
      if (sub < half) {
        int slot = (q * 4 + sub) * 5;
#pragma unroll
        for (int k = 0; k < 5; ++k) knn_insert_bl(bd, bi, md[slot + k], mi[slot + k]);
      }
    }
    if (sub == 0) {
      int* op = idx1 + (b * 2048 + qi) * 5;
#pragma unroll
      for (int k = 0; k < 5; ++k) op[k] = bi[k];
    }
  } else if (blk < 3072) {
    float* wAs = smem;
    float* bs = smem + 384;
    float* uS = smem + 448;
    float* vS = smem + 4800;
    for (int u = tid; u < 384; u += 256) wAs[u] = w1a[u];
    if (tid < 64) bs[tid] = b1a[tid];
    __syncthreads();
    int lane = tid & 63, fq = tid >> 6;
    int p0 = (blk - 2048) * 64;
    int p = p0 + lane;
    float x0 = pos[p * 3], x1 = pos[p * 3 + 1], x2 = pos[p * 3 + 2];
#pragma unroll
    for (int m = 0; m < 16; ++m) {
      int f = fq * 16 + m;
      float wt0 = wAs[f], wt1 = wAs[64 + f], wt2 = wAs[128 + f];
      float wb0 = wAs[192 + f], wb1 = wAs[256 + f], wb2 = wAs[320 + f];
      float uval = bs[f];
      uval = fmaf(x0, wt0 - wb0, uval);
      uval = fmaf(x1, wt1 - wb1, uval);
      uval = fmaf(x2, wt2 - wb2, uval);
      uS[lane * 68 + f] = uval;
      vS[lane * 68 + f] = fmaf(x2, wb2, fmaf(x1, wb1, x0 * wb0));
    }
    __syncthreads();
#pragma unroll
    for (int it = 0; it < 4; ++it) {
      int g = it * 1024 + tid * 4;
      int pl = g >> 6, f = g & 63;
      float4 uu = *(const float4*)(uS + pl * 68 + f);
      float4 vv = *(const float4*)(vS + pl * 68 + f);
      *(float4*)(uR + (size_t)p0 * 64 + g) = uu;
      *(float4*)(vR + (size_t)p0 * 64 + g) = vv;
    }
  } else {
    int pblk = blk - 3072;
    if (pblk < 4) {
      int t = pblk * 256 + tid;
      int m = t >> 9;
      int rem = t & 511;
      int nb = rem >> 7;
      int rem2 = rem & 127;
      int s = rem2 >> 6, lane = rem2 & 63;
      int k0 = s * 32 + (lane >> 4) * 8;
      int c = nb * 16 + (lane & 15);
      const float* W = m ? w1c : w1b;
      __bf16 oh[8], ol[8];
#pragma unroll
      for (int j = 0; j < 8; ++j) {
        float val = W[(k0 + j) * 64 + c];
        __bf16 h = (__bf16)val;
        oh[j] = h;
        ol[j] = (__bf16)(val - (float)h);
      }
      size_t off = (size_t)m * 4096 + ((size_t)((nb * 2 + s) * 64 + lane)) * 8;
      *(uint4*)(wfh + off) = *(const uint4*)oh;
      *(uint4*)(wfl + off) = *(const uint4*)ol;
    } else if (pblk < 12) {
      int t = (pblk - 4) * 256 + tid;
      int nb = t >> 7;
      int rem = t & 127;
      int ks = rem >> 6, lane = rem & 63;
      int k0 = ks * 32 + (lane >> 4) * 8;
      int col16 = lane & 15;
      __bf16 oh[8], ol[8];
#pragma unroll
      for (int j = 0; j < 8; ++j) {
        int k = k0 + j;
        float val;
        if (nb < 8) {
          int c = nb * 16 + col16;
          val = w2[k * 128 + c] - w2[(64 + k) * 128 + c];
        } else {
          int c = (nb - 8) * 16 + col16;
          val = w2[(64 + k) * 128 + c];
        }
        __bf16 h = (__bf16)val;
        oh[j] = h;
        ol[j] = (__bf16)(val - (float)h);
      }
      *(uint4*)(wph + (size_t)t * 8) = *(const uint4*)oh;
      *(uint4*)(wpl + (size_t)t * 8) = *(const uint4*)ol;
    } else {
      int t = (pblk - 12) * 256 + tid;
      int nt = t / 3072;
      int rem = t - nt * 3072;
      int ks = rem / 512;
      int rem2 = rem - ks * 512;
      int nb = rem2 >> 6, lane = rem2 & 63;
      int k0 = ks * 32 + (lane >> 4) * 8;
      int n = nt * 128 + nb * 16 + (lane & 15);
      __bf16 o[8];
#pragma unroll
      for (int j = 0; j < 8; ++j) o[j] = (__bf16)wl[(k0 + j) * 1024 + n];
      *(uint4*)(wlb + (size_t)t * 8) = *(const uint4*)o;
    }
  }
}

// ---------------- Kernel 2: EdgeConv1 layers 2/3 via hi/lo MFMA, barrier-free k-loop ----------------
__global__ __launch_bounds__(256) void k_edge1(
    const int* __restrict__ idx1, const float* __restrict__ uR,
    const float* __restrict__ vR,
    const float* __restrict__ s1a, const float* __restrict__ h1a,
    const float* __restrict__ b1b, const float* __restrict__ s1b,
    const float* __restrict__ h1b,
    const float* __restrict__ b1c, const float* __restrict__ s1c,
    const float* __restrict__ h1c,
    const __bf16* __restrict__ wfh, const __bf16* __restrict__ wfl,
    __bf16* __restrict__ xh, __bf16* __restrict__ xl,
    float* __restrict__ sqo, __bf16* __restrict__ xb) {
  __shared__ __align__(16) __bf16 Wh[8192], Wl[8192];
  __shared__ __align__(16) unsigned h2b[4 * 1088];
  int tid = threadIdx.x;
  int w = tid >> 6, lane = tid & 63;
  int quad = lane >> 4, lm = lane & 15;
#pragma unroll
  for (int it = 0; it < 4; ++it) {
    int u4 = it * 256 + tid;
    *(uint4*)(Wh + (size_t)u4 * 8) = *(const uint4*)(wfh + (size_t)u4 * 8);
    *(uint4*)(Wl + (size_t)u4 * 8) = *(const uint4*)(wfl + (size_t)u4 * 8);
  }
  int p0 = blockIdx.x * 64;
  int b = p0 >> 11;
  size_t bb = (size_t)b * 2048;
  int edge = p0 + w * 16 + lm;
  float sA[2][8], hA[2][8];
#pragma unroll
  for (int s = 0; s < 2; ++s)
#pragma unroll
    for (int j = 0; j < 8; ++j) {
      int k = s * 32 + quad * 8 + j;
      sA[s][j] = s1a[k]; hA[s][j] = h1a[k];
    }
  float bB[4], sB[4], hB[4], bC[4], sC[4], hC[4];
#pragma unroll
  for (int nb = 0; nb < 4; ++nb) {
    int c = nb * 16 + lm;
    bB[nb] = b1b[c]; sB[nb] = s1b[c]; hB[nb] = h1b[c];
    bC[nb] = b1c[c]; sC[nb] = s1c[c]; hC[nb] = h1c[c];
  }
  unsigned* h2w = h2b + w * 1088;
  f32x4 mmax[4];
#pragma unroll
  for (int nb = 0; nb < 4; ++nb)
    mmax[nb] = (f32x4){-3.4e38f, -3.4e38f, -3.4e38f, -3.4e38f};
  __syncthreads();
  const float* urow = uR + (size_t)edge * 64;
  for (int kk = 0; kk < 5; ++kk) {
    int jn = idx1[edge * 5 + kk];
    const float* vrow = vR + (bb + jn) * 64;
    bf16x8 Ah[2], Al[2];
#pragma unroll
    for (int s = 0; s < 2; ++s) {
      int off = s * 32 + quad * 8;
      float4 u0 = *(const float4*)(urow + off);
      float4 u1 = *(const float4*)(urow + off + 4);
      float4 v0 = *(const float4*)(vrow + off);
      float4 v1 = *(const float4*)(vrow + off + 4);
      float uv[8] = {u0.x + v0.x, u0.y + v0.y, u0.z + v0.z, u0.w + v0.w,
                     u1.x + v1.x, u1.y + v1.y, u1.z + v1.z, u1.w + v1.w};
      __bf16 th[8], tl[8];
#pragma unroll
      for (int j = 0; j < 8; ++j) {
        float val = relu_(uv[j]) * sA[s][j] + hA[s][j];
        __bf16 hb = (__bf16)val;
        th[j] = hb;
        tl[j] = (__bf16)(val - (float)hb);
      }
      Ah[s] = *(const bf16x8*)th;
      Al[s] = *(const bf16x8*)tl;
    }
#pragma unroll
    for (int nb = 0; nb < 4; ++nb) {
      bf16x8 Bh0 = *(const bf16x8*)(Wh + ((size_t)((nb * 2 + 0) * 64 + lane)) * 8);
      bf16x8 Bh1 = *(const bf16x8*)(Wh + ((size_t)((nb * 2 + 1) * 64 + lane)) * 8);
      bf16x8 Bl0 = *(const bf16x8*)(Wl + ((size_t)((nb * 2 + 0) * 64 + lane)) * 8);
      bf16x8 Bl1 = *(const bf16x8*)(Wl + ((size_t)((nb * 2 + 1) * 64 + lane)) * 8);
      f32x4 a2 = {0.f, 0.f, 0.f, 0.f};
      a2 = __builtin_amdgcn_mfma_f32_16x16x32_bf16(Ah[0], Bh0, a2, 0, 0, 0);
      a2 = __builtin_amdgcn_mfma_f32_16x16x32_bf16(Ah[1], Bh1, a2, 0, 0, 0);
      a2 = __builtin_amdgcn_mfma_f32_16x16x32_bf16(Ah[0], Bl0, a2, 0, 0, 0);
      a2 = __builtin_amdgcn_mfma_f32_16x16x32_bf16(Ah[1], Bl1, a2, 0, 0, 0);
      a2 = __builtin_amdgcn_mfma_f32_16x16x32_bf16(Al[0], Bh0, a2, 0, 0, 0);
      a2 = __builtin_amdgcn_mfma_f32_16x16x32_bf16(Al[1], Bh1, a2, 0, 0, 0);
#pragma unroll
      for (int r = 0; r < 4; ++r) {
        float vv2 = relu_(a2[r] + bB[nb]) * sB[nb] + hB[nb];
        __bf16 hb = (__bf16)vv2;
        __bf16 lb = (__bf16)(vv2 - (float)hb);
        h2w[(quad * 4 + r) * 68 + nb * 16 + lm] =
            (unsigned)bfbits(hb) | ((unsigned)bfbits(lb) << 16);
      }
    }
    bf16x8 A3h[2], A3l[2];
#pragma unroll
    for (int s = 0; s < 2; ++s) {
      const unsigned* rp = h2w + lm * 68 + s * 32 + quad * 8;
      uint4 da = *(const uint4*)rp;
      uint4 db = *(const uint4*)(rp + 4);
      unsigned dw[8] = {da.x, da.y, da.z, da.w, db.x, db.y, db.z, db.w};
      __bf16 th[8], tl[8];
#pragma unroll
      for (int j = 0; j < 8; ++j) {
        th[j] = bffrom((unsigned short)(dw[j] & 0xFFFFu));
        tl[j] = bffrom((unsigned short)(dw[j] >> 16));
      }
      A3h[s] = *(const bf16x8*)th;
      A3l[s] = *(const bf16x8*)tl;
    }
#pragma unroll
    for (int nb = 0; nb < 4; ++nb) {
      bf16x8 Bh0 = *(const bf16x8*)(Wh + 4096 + ((size_t)((nb * 2 + 0) * 64 + lane)) * 8);
      bf16x8 Bh1 = *(const bf16x8*)(Wh + 4096 + ((size_t)((nb * 2 + 1) * 64 + lane)) * 8);
      bf16x8 Bl0 = *(const bf16x8*)(Wl + 4096 + ((size_t)((nb * 2 + 0) * 64 + lane)) * 8);
      bf16x8 Bl1 = *(const bf16x8*)(Wl + 4096 + ((size_t)((nb * 2 + 1) * 64 + lane)) * 8);
      f32x4 a3 = {0.f, 0.f, 0.f, 0.f};
      a3 = __builtin_amdgcn_mfma_f32_16x16x32_bf16(A3h[0], Bh0, a3, 0, 0, 0);
      a3 = __builtin_amdgcn_mfma_f32_16x16x32_bf16(A3h[1], Bh1, a3, 0, 0, 0);
      a3 = __builtin_amdgcn_mfma_f32_16x16x32_bf16(A3h[0], Bl0, a3, 0, 0, 0);
      a3 = __builtin_amdgcn_mfma_f32_16x16x32_bf16(A3h[1], Bl1, a3, 0, 0, 0);
      a3 = __builtin_amdgcn_mfma_f32_16x16x32_bf16(A3l[0], Bh0, a3, 0, 0, 0);
      a3 = __builtin_amdgcn_mfma_f32_16x16x32_bf16(A3l[1], Bh1, a3, 0, 0, 0);
#pragma unroll
      for (int r = 0; r < 4; ++r) mmax[nb][r] = fmaxf(mmax[nb][r], a3[r]);
    }
  }
  float sqp[4] = {0.f, 0.f, 0.f, 0.f};
#pragma unroll
  for (int nb = 0; nb < 4; ++nb) {
    int c = nb * 16 + lm;
#pragma unroll
    for (int r = 0; r < 4; ++r) {
      float vv3 = relu_(mmax[nb][r] + bC[nb]) * sC[nb] + hC[nb];
      sqp[r] = fmaf(vv3, vv3, sqp[r]);
      __bf16 hb = (__bf16)vv3;
      __bf16 lb = (__bf16)(vv3 - (float)hb);
      int n = p0 + w * 16 + quad * 4 + r;
      xh[(size_t)n * 64 + c] = hb;
      xl[(size_t)n * 64 + c] = lb;
      xb[(size_t)n * 192 + c] = hb;
    }
  }
#pragma unroll
  for (int r = 0; r < 4; ++r) {
    float s = sqp[r];
    s += __shfl_xor(s, 1);
    s += __shfl_xor(s, 2);
    s += __shfl_xor(s, 4);
    s += __shfl_xor(s, 8);
    if (lm == 0) sqo[p0 + w * 16 + quad * 4 + r] = s;
  }
}

// ---------------- Kernel MID: knn2 (blk<1024) + pq_mfma (1024..2047), 32KB LDS union ----------------
__global__ __launch_bounds__(256) void k_mid(const __bf16* __restrict__ xh,
                                             const __bf16* __restrict__ xl,
                                             const float* __restrict__ sq,
                                             int* __restrict__ idx2,
                                             const __bf16* __restrict__ wph,
                                             const __bf16* __restrict__ wpl,
                                             __bf16* __restrict__ Pb,
                                             __bf16* __restrict__ Qb) {
  __shared__ __align__(16) float smem[8192];  // union: knn2 6656f / pq 8192f
  int tid = threadIdx.x;
  int w = tid >> 6, lane = tid & 63;
  int quad = lane >> 4, lm = lane & 15;
  if (blockIdx.x < 1024) {
    // ----- knn2: byte-identical math to R15 -----
    __bf16* Bh = (__bf16*)smem;           // 4608 bf16 (2304 f)
    __bf16* Bl = (__bf16*)(smem + 2304);  // 4608 bf16
    float* sqs = smem + 4608;             // 2048 f
    int b = blockIdx.x >> 5, qc = blockIdx.x & 31;
    int q0 = qc * 64;
    size_t bb = (size_t)b * 2048;
    for (int u = tid; u < 512; u += 256)
      *(float4*)(sqs + u * 4) = *(const float4*)(sq + bb + u * 4);
    const __bf16* qh = xh + (bb + q0 + w * 16 + lm) * 64 + quad * 8;
    const __bf16* ql = xl + (bb + q0 + w * 16 + lm) * 64 + quad * 8;
    bf16x8 Ah0 = *(const bf16x8*)(qh);
    bf16x8 Ah1 = *(const bf16x8*)(qh + 32);
    bf16x8 Al0 = *(const bf16x8*)(ql);
    bf16x8 Al1 = *(const bf16x8*)(ql + 32);
    __syncthreads();
    float qsq[4];
#pragma unroll
    for (int r = 0; r < 4; ++r) qsq[r] = sqs[q0 + w * 16 + quad * 4 + r];
    float bd[4][5];
    int bi[4][5];
#pragma unroll
    for (int r = 0; r < 4; ++r)
#pragma unroll
      for (int k = 0; k < 5; ++k) { bd[r][k] = 1e30f; bi[r][k] = 0; }
    for (int ct = 0; ct < 32; ++ct) {
#pragma unroll
      for (int pass = 0; pass < 2; ++pass) {
        int unit = pass * 256 + tid;
        int n = unit >> 3, cc = unit & 7;
        const __bf16* gsrc = xh + (bb + ct * 64 + n) * 64 + cc * 8;
        const __bf16* gsrl = xl + (bb + ct * 64 + n) * 64 + cc * 8;
        *(uint4*)(Bh + n * 72 + cc * 8) = *(const uint4*)gsrc;
        *(uint4*)(Bl + n * 72 + cc * 8) = *(const uint4*)gsrl;
      }
      __syncthreads();
#pragma unroll
      for (int nt = 0; nt < 4; ++nt) {
        const __bf16* bph = Bh + (nt * 16 + lm) * 72 + quad * 8;
        const __bf16* bpl = Bl + (nt * 16 + lm) * 72 + quad * 8;
        bf16x8 Bh0 = *(const bf16x8*)(bph);
        bf16x8 Bh1 = *(const bf16x8*)(bph + 32);
        bf16x8 Bl0 = *(const bf16x8*)(bpl);
        bf16x8 Bl1 = *(const bf16x8*)(bpl + 32);
        f32x4 acc = {0.f, 0.f, 0.f, 0.f};
        acc = __builtin_amdgcn_mfma_f32_16x16x32_bf16(Ah0, Bh0, acc, 0, 0, 0);
        acc = __builtin_amdgcn_mfma_f32_16x16x32_bf16(Ah1, Bh1, acc, 0, 0, 0);
        acc = __builtin_amdgcn_mfma_f32_16x16x32_bf16(Ah0, Bl0, acc, 0, 0, 0);
        acc = __builtin_amdgcn_mfma_f32_16x16x32_bf16(Ah1, Bl1, acc, 0, 0, 0);
        acc = __builtin_amdgcn_mfma_f32_16x16x32_bf16(Al0, Bh0, acc, 0, 0, 0);
        acc = __builtin_amdgcn_mfma_f32_16x16x32_bf16(Al1, Bh1, acc, 0, 0, 0);
        int cid = ct * 64 + nt * 16 + lm;
        float csq = sqs[cid];
#pragma unroll
        for (int r = 0; r < 4; ++r) {
          float d = (qsq[r] + csq) - 2.0f * acc[r];
          knn_insert(bd[r], bi[r], d, cid);
        }
      }
      __syncthreads();
    }
    for (int m = 1; m <= 8; m <<= 1) {
#pragma unroll
      for (int r = 0; r < 4; ++r) {
        float od[5]; int oi[5];
#pragma unroll
        for (int k = 0; k < 5; ++k) {
          od[k] = __shfl_xor(bd[r][k], m);
          oi[k] = __shfl_xor(bi[r][k], m);
        }
#pragma unroll
        for (int k = 0; k < 5; ++k) knn_insert(bd[r], bi[r], od[k], oi[k]);
      }
    }
    if (lm == 0) {
#pragma unroll
      for (int r = 0; r < 4; ++r) {
        int qi = q0 + w * 16 + quad * 4 + r;
        int* op = idx2 + (bb + qi) * 5;
#pragma unroll
        for (int k = 0; k < 5; ++k) op[k] = bi[r][k];
      }
    }
  } else {
    // ----- pq_mfma: same math, weights staged in 2 chunks of 8 nb (32KB LDS) -----
    __bf16* Wh = (__bf16*)smem;           // 8192 bf16 chunk (4096 f)
    __bf16* Wl = (__bf16*)(smem + 4096);  // 8192 bf16 chunk
    int n0 = (blockIdx.x - 1024) * 64;
    const __bf16* ah = xh + (size_t)(n0 + w * 16 + lm) * 64 + quad * 8;
    const __bf16* al = xl + (size_t)(n0 + w * 16 + lm) * 64 + quad * 8;
    bf16x8 Ah0 = *(const bf16x8*)(ah);
    bf16x8 Ah1 = *(const bf16x8*)(ah + 32);
    bf16x8 Al0 = *(const bf16x8*)(al);
    bf16x8 Al1 = *(const bf16x8*)(al + 32);
    f32x4 acc[16];
#pragma unroll
    for (int nb = 0; nb < 16; ++nb) acc[nb] = (f32x4){0.f, 0.f, 0.f, 0.f};
    for (int half = 0; half < 2; ++half) {
      __syncthreads();  // protect previous chunk's frag reads
#pragma unroll
      for (int it = 0; it < 4; ++it) {
        int unit = it * 256 + tid;  // 0..1023 (x8 bf16 = 8192)
        *(uint4*)(Wh + (size_t)unit * 8) =
            *(const uint4*)(wph + (size_t)half * 8192 + (size_t)unit * 8);
        *(uint4*)(Wl + (size_t)unit * 8) =
            *(const uint4*)(wpl + (size_t)half * 8192 + (size_t)unit * 8);
      }
      __syncthreads();
#pragma unroll
      for (int nb8 = 0; nb8 < 8; ++nb8) {
        int nb = half * 8 + nb8;
        bf16x8 Bh0 = *(const bf16x8*)(Wh + ((size_t)(nb8 * 2 + 0) * 64 + lane) * 8);
        bf16x8 Bh1 = *(const bf16x8*)(Wh + ((size_t)(nb8 * 2 + 1) * 64 + lane) * 8);
        bf16x8 Bl0 = *(const bf16x8*)(Wl + ((size_t)(nb8 * 2 + 0) * 64 + lane) * 8);
        bf16x8 Bl1 = *(const bf16x8*)(Wl + ((size_t)(nb8 * 2 + 1) * 64 + lane) * 8);
        acc[nb] = __builtin_amdgcn_mfma_f32_16x16x32_bf16(Ah0, Bh0, acc[nb], 0, 0, 0);
        acc[nb] = __builtin_amdgcn_mfma_f32_16x16x32_bf16(Ah1, Bh1, acc[nb], 0, 0, 0);
        acc[nb] = __builtin_amdgcn_mfma_f32_16x16x32_bf16(Ah0, Bl0, acc[nb], 0, 0, 0);
        acc[nb] = __builtin_amdgcn_mfma_f32_16x16x32_bf16(Ah1, Bl1, acc[nb], 0, 0, 0);
        acc[nb] = __builtin_amdgcn_mfma_f32_16x16x32_bf16(Al0, Bh0, acc[nb], 0, 0, 0);
        acc[nb] = __builtin_amdgcn_mfma_f32_16x16x32_bf16(Al1, Bh1, acc[nb], 0, 0, 0);
      }
    }
#pragma unroll
    for (int nb = 0; nb < 16; ++nb) {
      bool isP = (nb < 8);
      __bf16* base = isP ? Pb : Qb;
      int col = (isP ? nb : nb - 8) * 16 + lm;
#pragma unroll
      for (int r = 0; r < 4; ++r) {
        int n = n0 + w * 16 + quad * 4 + r;
        base[(size_t)n * 128 + col] = (__bf16)acc[nb][r];
      }
    }
  }
}

// ---------------- Kernel 4b: gather-max + activation, 2 channels/lane ----------------
__global__ __launch_bounds__(256) void k_gmax(const __bf16* __restrict__ Pb,
                                              const __bf16* __restrict__ Qb,
                                              const int* __restrict__ idx2,
                                              const float* __restrict__ b2,
                                              const float* __restrict__ s2,
                                              const float* __restrict__ h2v,
                                              __bf16* __restrict__ xb) {
  int tid = threadIdx.x;
  int c2 = tid & 63, p = tid >> 6;
  int n = blockIdx.x * 4 + p;
  int b = n >> 11;
  const int* ip = idx2 + n * 5;
  int c0 = c2 * 2;
  float m0 = -3.4e38f, m1 = -3.4e38f;
#pragma unroll
  for (int k = 0; k < 5; ++k) {
    int j = ip[k];
    unsigned q = *(const unsigned*)(Qb + ((size_t)(b * 2048 + j)) * 128 + c0);
    m0 = fmaxf(m0, (float)bffrom((unsigned short)(q & 0xFFFFu)));
    m1 = fmaxf(m1, (float)bffrom((unsigned short)(q >> 16)));
  }
  unsigned pv = *(const unsigned*)(Pb + (size_t)n * 128 + c0);
  float v0 = (float)bffrom((unsigned short)(pv & 0xFFFFu)) + m0 + b2[c0];
  float v1 = (float)bffrom((unsigned short)(pv >> 16)) + m1 + b2[c0 + 1];
  __bf16 o0 = (__bf16)(relu_(v0) * s2[c0] + h2v[c0]);
  __bf16 o1 = (__bf16)(relu_(v1) * s2[c0 + 1] + h2v[c0 + 1]);
  unsigned ov = (unsigned)bfbits(o0) | ((unsigned)bfbits(o1) << 16);
  *(unsigned*)(xb + (size_t)n * 192 + 64 + c0) = ov;
}

// ---------------- Kernel 5: bf16 MFMA GEMM fused point-max, 64m x 256n tiles ----------------
__global__ __launch_bounds__(256) void k_linl_mfma(const __bf16* __restrict__ xb,
                                                   const __bf16* __restrict__ wlb,
                                                   float* __restrict__ pool_part) {
  __shared__ __align__(16) __bf16 Al[2048];
  __shared__ __align__(16) __bf16 Bl[8192];
  int tid = threadIdx.x;
  int w = tid >> 6, lane = tid & 63;
  int mg = blockIdx.x >> 2, ng = blockIdx.x & 3;
  int n0 = mg << 6;
  int quad = lane >> 4, lm = lane & 15;
  f32x4 acc[4][4];
#pragma unroll
  for (int i = 0; i < 4; ++i)
#pragma unroll
    for (int j = 0; j < 4; ++j) acc[i][j] = (f32x4){0.f, 0.f, 0.f, 0.f};
  for (int ks = 0; ks < 6; ++ks) {
    __syncthreads();
    {
      int mb = tid >> 6, ln = tid & 63;
      int lmm = ln & 15, qd = ln >> 4;
      const uint4* ga = (const uint4*)(xb + (size_t)(n0 + mb * 16 + lmm) * 192 + ks * 32 + qd * 8);
      *(uint4*)(Al + ((size_t)(mb * 64 + ln)) * 8) = *ga;
    }
#pragma unroll
    for (int nt2 = 0; nt2 < 2; ++nt2) {
#pragma unroll
      for (int u = 0; u < 2; ++u) {
        int unit = u * 256 + tid;
        const uint4* gb = (const uint4*)(wlb + ((size_t)((ng * 2 + nt2) * 6 + ks)) * 4096 + (size_t)unit * 8);
        *(uint4*)(Bl + (size_t)nt2 * 4096 + (size_t)unit * 8) = *gb;
      }
    }
    __syncthreads();
    bf16x8 af[4], bfr[4];
#pragma unroll
    for (int i = 0; i < 4; ++i)
      af[i] = *(const bf16x8*)(Al + ((size_t)(i * 64 + lane)) * 8);
    int nt2 = w >> 1, nbb = (w & 1) * 4;
#pragma unroll
    for (int j = 0; j < 4; ++j)
      bfr[j] = *(const bf16x8*)(Bl + (size_t)nt2 * 4096 + ((size_t)((nbb + j) * 64 + lane)) * 8);
#pragma unroll
    for (int i = 0; i < 4; ++i)
#pragma unroll
      for (int j = 0; j < 4; ++j)
        acc[i][j] = __builtin_amdgcn_mfma_f32_16x16x32_bf16(af[i], bfr[j], acc[i][j], 0, 0, 0);
  }
#pragma unroll
  for (int j = 0; j < 4; ++j) {
    float m = -3.4e38f;
#pragma unroll
    for (int i = 0; i < 4; ++i)
#pragma unroll
      for (int r = 0; r < 4; ++r) m = fmaxf(m, acc[i][j][r]);
    m = fmaxf(m, __shfl_xor(m, 16));
    m = fmaxf(m, __shfl_xor(m, 32));
    if (quad == 0) {
      int ch = ng * 256 + (w >> 1) * 128 + (w & 1) * 64 + j * 16 + lm;
      pool_part[(size_t)mg * 1024 + ch] = m;
    }
  }
}

// ---------------- Kernel 6: head MLP (32-way pool merge) ----------------
__global__ __launch_bounds__(256) void k_head(
    const float* __restrict__ pool_part, const float* __restrict__ bl,
    const float* __restrict__ sl, const float* __restrict__ hl,
    const float* __restrict__ wm1, const float* __restrict__ bm1,
    const float* __restrict__ sm1, const float* __restrict__ hm1,
    const float* __restrict__ wm2, const float* __restrict__ bm2,
    const float* __restrict__ sm2, const float* __restrict__ hm2,
    const float* __restrict__ wout, const float* __restrict__ bout,
    float* __restrict__ out) {
  __shared__ float p_s[1024], h1_s[512], h2_s[256];
  int b = blockIdx.x, tid = threadIdx.x;
  for (int c = tid; c < 1024; c += 256) {
    float m = -3.4e38f;
#pragma unroll 4
    for (int t = 0; t < 32; ++t)
      m = fmaxf(m, pool_part[(size_t)(b * 32 + t) * 1024 + c]);
    p_s[c] = relu_(m + bl[c]) * sl[c] + hl[c];
  }
  __syncthreads();
  for (int c = tid; c < 512; c += 256) {
    float a0 = 0, a1 = 0, a2 = 0, a3 = 0;
    for (int f = 0; f < 1024; f += 4) {
      a0 = fmaf(p_s[f], wm1[f * 512 + c], a0);
      a1 = fmaf(p_s[f + 1], wm1[(f + 1) * 512 + c], a1);
      a2 = fmaf(p_s[f + 2], wm1[(f + 2) * 512 + c], a2);
      a3 = fmaf(p_s[f + 3], wm1[(f + 3) * 512 + c], a3);
    }
    float a = (a0 + a1) + (a2 + a3);
    h1_s[c] = relu_(a + bm1[c]) * sm1[c] + hm1[c];
  }
  __syncthreads();
  if (tid < 256) {
    float a0 = 0, a1 = 0, a2 = 0, a3 = 0;
    for (int f = 0; f < 512; f += 4) {
      a0 = fmaf(h1_s[f], wm2[f * 256 + tid], a0);
      a1 = fmaf(h1_s[f + 1], wm2[(f + 1) * 256 + tid], a1);
      a2 = fmaf(h1_s[f + 2], wm2[(f + 2) * 256 + tid], a2);
      a3 = fmaf(h1_s[f + 3], wm2[(f + 3) * 256 + tid], a3);
    }
    float a = (a0 + a1) + (a2 + a3);
    h2_s[tid] = relu_(a + bm2[tid]) * sm2[tid] + hm2[tid];
  }
  __syncthreads();
  if (tid < 2) {
    float a0 = 0, a1 = 0;
    for (int f = 0; f < 256; f += 2) {
      a0 = fmaf(h2_s[f], wout[f * 2 + tid], a0);
      a1 = fmaf(h2_s[f + 1], wout[(f + 1) * 2 + tid], a1);
    }
    out[b * 2 + tid] = (a0 + a1) + bout[tid];
  }
}

extern "C" void kernel_launch(void* const* d_in, const int* in_sizes, int n_in,
                              void* d_out, int out_size, void* d_ws, size_t ws_size,
                              hipStream_t stream) {
  const float* pos = (const float*)d_in[0];
  const float* w1a = (const float*)d_in[1];
  const float* b1a = (const float*)d_in[2];
  const float* s1a = (const float*)d_in[3];
  const float* h1a = (const float*)d_in[4];
  const float* w1b = (const float*)d_in[5];
  const float* b1b = (const float*)d_in[6];
  const float* s1b = (const float*)d_in[7];
  const float* h1b = (const float*)d_in[8];
  const float* w1c = (const float*)d_in[9];
  const float* b1c = (const float*)d_in[10];
  const float* s1c = (const float*)d_in[11];
  const float* h1c = (const float*)d_in[12];
  const float* w2 = (const float*)d_in[13];
  const float* b2 = (const float*)d_in[14];
  const float* s2 = (const float*)d_in[15];
  const float* h2 = (const float*)d_in[16];
  const float* wl = (const float*)d_in[17];
  const float* bl = (const float*)d_in[18];
  const float* sl = (const float*)d_in[19];
  const float* hl = (const float*)d_in[20];
  const float* wm1 = (const float*)d_in[21];
  const float* bm1 = (const float*)d_in[22];
  const float* sm1 = (const float*)d_in[23];
  const float* hm1 = (const float*)d_in[24];
  const float* wm2 = (const float*)d_in[25];
  const float* bm2 = (const float*)d_in[26];
  const float* sm2 = (const float*)d_in[27];
  const float* hm2 = (const float*)d_in[28];
  const float* wout = (const float*)d_in[29];
  const float* bout = (const float*)d_in[30];
  float* out = (float*)d_out;

  // workspace: xh | xl | Pb | Qb | xb | idx | sq | wph/wpl/wfh/wfl | wlb (~77.6 MB)
  float* base = (float*)d_ws;
  __bf16* xh = (__bf16*)base;
  __bf16* xl = (__bf16*)(base + 2097152);
  float* PbF = base + 4194304;
  float* QbF = PbF + 4194304;
  float* xbF = QbF + 4194304;
  int* idx = (int*)(xbF + 6291456);
  float* sq = (float*)(idx + 327680);
  __bf16* wph = (__bf16*)(sq + 65536);
  __bf16* wpl = (__bf16*)(sq + 65536 + 8192);
  __bf16* wfh = (__bf16*)(sq + 65536 + 16384);
  __bf16* wfl = (__bf16*)(sq + 65536 + 20480);
  __bf16* wlb = (__bf16*)(sq + 65536 + 24576);
  __bf16* Pb = (__bf16*)PbF;
  __bf16* Qb = (__bf16*)QbF;
  __bf16* xb = (__bf16*)xbF;
  float* uR = PbF;                                // alias (dead until k_mid's pq)
  float* vR = QbF;
  float* pool_part = base + 131072;               // overlaps xl/Pb head: dead by linl

  k_front<<<3180, 256, 0, stream>>>(pos, w1a, b1a, w1b, w1c, w2, wl, idx, uR, vR,
                                    wfh, wfl, wph, wpl, wlb);
  k_edge1<<<1024, 256, 0, stream>>>(idx, uR, vR, s1a, h1a, b1b, s1b, h1b, b1c,
                                    s1c, h1c, wfh, wfl, xh, xl, sq, xb);
  k_mid<<<2048, 256, 0, stream>>>(xh, xl, sq, idx, wph, wpl, Pb, Qb);
  k_gmax<<<16384, 256, 0, stream>>>(Pb, Qb, idx, b2, s2, h2, xb);
  k_linl_mfma<<<4096, 256, 0, stream>>>(xb, wlb, pool_part);
  k_head<<<32, 256, 0, stream>>>(pool_part, bl, sl, hl, wm1, bm1, sm1, hm1, wm2,
                                 bm2, sm2, hm2, wout, bout, out);
}

// Round 17
// 535.103 us; speedup vs baseline: 1.4969x; 1.0738x over previous
//
#include <hip/hip_runtime.h>

#define DEV __device__ __forceinline__
DEV float relu_(float x) { return fmaxf(x, 0.0f); }

typedef __attribute__((ext_vector_type(4))) float f32x4;
typedef __attribute__((ext_vector_type(8))) __bf16 bf16x8;

DEV unsigned short bfbits(__bf16 b) { union { unsigned short s; __bf16 b; } x; x.b = b; return x.s; }
DEV __bf16 bffrom(unsigned short s) { union { unsigned short s; __bf16 b; } x; x.s = s; return x.b; }

// branchy top-5 insert (R6-measured best for knn2's wave-coherent stream)
DEV void knn_insert(float (&bd)[5], int (&bi)[5], float d, int j) {
  if (d >= bd[4]) return;
  bd[4] = d; bi[4] = j;
#pragma unroll
  for (int p = 4; p > 0; --p) {
    if (bd[p] < bd[p - 1]) {
      float td = bd[p]; bd[p] = bd[p - 1]; bd[p - 1] = td;
      int ti = bi[p]; bi[p] = bi[p - 1]; bi[p - 1] = ti;
    }
  }
}

// branchless EXACT top-5 insert (used in knn1)
DEV void knn_insert_bl(float (&bd)[5], int (&bi)[5], float d, int j) {
#pragma unroll
  for (int p = 0; p < 5; ++p) {
    bool lt = d < bd[p];
    float nd = lt ? d : bd[p];
    float cd = lt ? bd[p] : d;
    int ni = lt ? j : bi[p];
    int ci = lt ? bi[p] : j;
    bd[p] = nd; d = cd;
    bi[p] = ni; j = ci;
  }
}

// ---------------- Kernel FRONT: knn1 (blk<2048) + uv (2048..3071) + preps (3072..3179) ----------------
__global__ __launch_bounds__(256) void k_front(
    const float* __restrict__ pos, const float* __restrict__ w1a,
    const float* __restrict__ b1a, const float* __restrict__ w1b,
    const float* __restrict__ w1c, const float* __restrict__ w2,
    const float* __restrict__ wl,
    int* __restrict__ idx1, float* __restrict__ uR, float* __restrict__ vR,
    __bf16* __restrict__ wfh, __bf16* __restrict__ wfl,
    __bf16* __restrict__ wph, __bf16* __restrict__ wpl,
    __bf16* __restrict__ wlb) {
  __shared__ __align__(16) float smem[9472];
  int tid = threadIdx.x;
  int blk = blockIdx.x;
  if (blk < 2048) {
    float* ps = smem;
    float* sqs = smem + 6144;
    float* md = smem + 8192;
    int* mi = (int*)(smem + 8832);
    int b = blk >> 6, qc = blk & 63;
    const float* src = pos + b * 6144;
    for (int u = tid; u < 6144; u += 256) ps[u] = src[u];
    __syncthreads();
    for (int u = tid; u < 2048; u += 256) {
      float x = ps[u * 3], y = ps[u * 3 + 1], z = ps[u * 3 + 2];
      sqs[u] = fmaf(z, z, fmaf(y, y, x * x));
    }
    __syncthreads();
    int q = tid & 31, sub = tid >> 5;
    int qi = qc * 32 + q;
    float qx = ps[qi * 3], qy = ps[qi * 3 + 1], qz = ps[qi * 3 + 2];
    float qsq = sqs[qi];
    float bd[5] = {1e30f, 1e30f, 1e30f, 1e30f, 1e30f};
    int bi[5] = {0, 0, 0, 0, 0};
    int j0 = sub * 256;
    for (int j = j0; j < j0 + 256; ++j) {
      float px = ps[j * 3], py = ps[j * 3 + 1], pz = ps[j * 3 + 2];
      float dot = fmaf(qz, pz, fmaf(qy, py, qx * px));
      float d = (qsq + sqs[j]) - 2.0f * dot;
      knn_insert_bl(bd, bi, d, j);
    }
    for (int half = 4; half >= 1; half >>= 1) {
      __syncthreads();
      if (sub >= half && sub < 2 * half) {
        int slot = (q * 4 + (sub - half)) * 5;
#pragma unroll
        for (int k = 0; k < 5; ++k) { md[slot + k] = bd[k]; mi[slot + k] = bi[k]; }
      }
      __syncthreads();
      if (sub < half) {
        int slot = (q * 4 + sub) * 5;
#pragma unroll
        for (int k = 0; k < 5; ++k) knn_insert_bl(bd, bi, md[slot + k], mi[slot + k]);
      }
    }
    if (sub == 0) {
      int* op = idx1 + (b * 2048 + qi) * 5;
#pragma unroll
      for (int k = 0; k < 5; ++k) op[k] = bi[k];
    }
  } else if (blk < 3072) {
    float* wAs = smem;
    float* bs = smem + 384;
    float* uS = smem + 448;
    float* vS = smem + 4800;
    for (int u = tid; u < 384; u += 256) wAs[u] = w1a[u];
    if (tid < 64) bs[tid] = b1a[tid];
    __syncthreads();
    int lane = tid & 63, fq = tid >> 6;
    int p0 = (blk - 2048) * 64;
    int p = p0 + lane;
    float x0 = pos[p * 3], x1 = pos[p * 3 + 1], x2 = pos[p * 3 + 2];
#pragma unroll
    for (int m = 0; m < 16; ++m) {
      int f = fq * 16 + m;
      float wt0 = wAs[f], wt1 = wAs[64 + f], wt2 = wAs[128 + f];
      float wb0 = wAs[192 + f], wb1 = wAs[256 + f], wb2 = wAs[320 + f];
      float uval = bs[f];
      uval = fmaf(x0, wt0 - wb0, uval);
      uval = fmaf(x1, wt1 - wb1, uval);
      uval = fmaf(x2, wt2 - wb2, uval);
      uS[lane * 68 + f] = uval;
      vS[lane * 68 + f] = fmaf(x2, wb2, fmaf(x1, wb1, x0 * wb0));
    }
    __syncthreads();
#pragma unroll
    for (int it = 0; it < 4; ++it) {
      int g = it * 1024 + tid * 4;
      int pl = g >> 6, f = g & 63;
      float4 uu = *(const float4*)(uS + pl * 68 + f);
      float4 vv = *(const float4*)(vS + pl * 68 + f);
      *(float4*)(uR + (size_t)p0 * 64 + g) = uu;
      *(float4*)(vR + (size_t)p0 * 64 + g) = vv;
    }
  } else {
    int pblk = blk - 3072;
    if (pblk < 4) {
      int t = pblk * 256 + tid;
      int m = t >> 9;
      int rem = t & 511;
      int nb = rem >> 7;
      int rem2 = rem & 127;
      int s = rem2 >> 6, lane = rem2 & 63;
      int k0 = s * 32 + (lane >> 4) * 8;
      int c = nb * 16 + (lane & 15);
      const float* W = m ? w1c : w1b;
      __bf16 oh[8], ol[8];
#pragma unroll
      for (int j = 0; j < 8; ++j) {
        float val = W[(k0 + j) * 64 + c];
        __bf16 h = (__bf16)val;
        oh[j] = h;
        ol[j] = (__bf16)(val - (float)h);
      }
      size_t off = (size_t)m * 4096 + ((size_t)((nb * 2 + s) * 64 + lane)) * 8;
      *(uint4*)(wfh + off) = *(const uint4*)oh;
      *(uint4*)(wfl + off) = *(const uint4*)ol;
    } else if (pblk < 12) {
      int t = (pblk - 4) * 256 + tid;
      int nb = t >> 7;
      int rem = t & 127;
      int ks = rem >> 6, lane = rem & 63;
      int k0 = ks * 32 + (lane >> 4) * 8;
      int col16 = lane & 15;
      __bf16 oh[8], ol[8];
#pragma unroll
      for (int j = 0; j < 8; ++j) {
        int k = k0 + j;
        float val;
        if (nb < 8) {
          int c = nb * 16 + col16;
          val = w2[k * 128 + c] - w2[(64 + k) * 128 + c];
        } else {
          int c = (nb - 8) * 16 + col16;
          val = w2[(64 + k) * 128 + c];
        }
        __bf16 h = (__bf16)val;
        oh[j] = h;
        ol[j] = (__bf16)(val - (float)h);
      }
      *(uint4*)(wph + (size_t)t * 8) = *(const uint4*)oh;
      *(uint4*)(wpl + (size_t)t * 8) = *(const uint4*)ol;
    } else {
      int t = (pblk - 12) * 256 + tid;
      int nt = t / 3072;
      int rem = t - nt * 3072;
      int ks = rem / 512;
      int rem2 = rem - ks * 512;
      int nb = rem2 >> 6, lane = rem2 & 63;
      int k0 = ks * 32 + (lane >> 4) * 8;
      int n = nt * 128 + nb * 16 + (lane & 15);
      __bf16 o[8];
#pragma unroll
      for (int j = 0; j < 8; ++j) o[j] = (__bf16)wl[(k0 + j) * 1024 + n];
      *(uint4*)(wlb + (size_t)t * 8) = *(const uint4*)o;
    }
  }
}

// ---------------- Kernel 2: EdgeConv1 layers 2/3 via hi/lo MFMA, barrier-free k-loop ----------------
__global__ __launch_bounds__(256) void k_edge1(
    const int* __restrict__ idx1, const float* __restrict__ uR,
    const float* __restrict__ vR,
    const float* __restrict__ s1a, const float* __restrict__ h1a,
    const float* __restrict__ b1b, const float* __restrict__ s1b,
    const float* __restrict__ h1b,
    const float* __restrict__ b1c, const float* __restrict__ s1c,
    const float* __restrict__ h1c,
    const __bf16* __restrict__ wfh, const __bf16* __restrict__ wfl,
    __bf16* __restrict__ xh, __bf16* __restrict__ xl,
    float* __restrict__ sqo, __bf16* __restrict__ xb) {
  __shared__ __align__(16) __bf16 Wh[8192], Wl[8192];
  __shared__ __align__(16) unsigned h2b[4 * 1088];
  int tid = threadIdx.x;
  int w = tid >> 6, lane = tid & 63;
  int quad = lane >> 4, lm = lane & 15;
#pragma unroll
  for (int it = 0; it < 4; ++it) {
    int u4 = it * 256 + tid;
    *(uint4*)(Wh + (size_t)u4 * 8) = *(const uint4*)(wfh + (size_t)u4 * 8);
    *(uint4*)(Wl + (size_t)u4 * 8) = *(const uint4*)(wfl + (size_t)u4 * 8);
  }
  int p0 = blockIdx.x * 64;
  int b = p0 >> 11;
  size_t bb = (size_t)b * 2048;
  int edge = p0 + w * 16 + lm;
  float sA[2][8], hA[2][8];
#pragma unroll
  for (int s = 0; s < 2; ++s)
#pragma unroll
    for (int j = 0; j < 8; ++j) {
      int k = s * 32 + quad * 8 + j;
      sA[s][j] = s1a[k]; hA[s][j] = h1a[k];
    }
  float bB[4], sB[4], hB[4], bC[4], sC[4], hC[4];
#pragma unroll
  for (int nb = 0; nb < 4; ++nb) {
    int c = nb * 16 + lm;
    bB[nb] = b1b[c]; sB[nb] = s1b[c]; hB[nb] = h1b[c];
    bC[nb] = b1c[c]; sC[nb] = s1c[c]; hC[nb] = h1c[c];
  }
  unsigned* h2w = h2b + w * 1088;
  f32x4 mmax[4];
#pragma unroll
  for (int nb = 0; nb < 4; ++nb)
    mmax[nb] = (f32x4){-3.4e38f, -3.4e38f, -3.4e38f, -3.4e38f};
  __syncthreads();
  const float* urow = uR + (size_t)edge * 64;
  for (int kk = 0; kk < 5; ++kk) {
    int jn = idx1[edge * 5 + kk];
    const float* vrow = vR + (bb + jn) * 64;
    bf16x8 Ah[2], Al[2];
#pragma unroll
    for (int s = 0; s < 2; ++s) {
      int off = s * 32 + quad * 8;
      float4 u0 = *(const float4*)(urow + off);
      float4 u1 = *(const float4*)(urow + off + 4);
      float4 v0 = *(const float4*)(vrow + off);
      float4 v1 = *(const float4*)(vrow + off + 4);
      float uv[8] = {u0.x + v0.x, u0.y + v0.y, u0.z + v0.z, u0.w + v0.w,
                     u1.x + v1.x, u1.y + v1.y, u1.z + v1.z, u1.w + v1.w};
      __bf16 th[8], tl[8];
#pragma unroll
      for (int j = 0; j < 8; ++j) {
        float val = relu_(uv[j]) * sA[s][j] + hA[s][j];
        __bf16 hb = (__bf16)val;
        th[j] = hb;
        tl[j] = (__bf16)(val - (float)hb);
      }
      Ah[s] = *(const bf16x8*)th;
      Al[s] = *(const bf16x8*)tl;
    }
#pragma unroll
    for (int nb = 0; nb < 4; ++nb) {
      bf16x8 Bh0 = *(const bf16x8*)(Wh + ((size_t)((nb * 2 + 0) * 64 + lane)) * 8);
      bf16x8 Bh1 = *(const bf16x8*)(Wh + ((size_t)((nb * 2 + 1) * 64 + lane)) * 8);
      bf16x8 Bl0 = *(const bf16x8*)(Wl + ((size_t)((nb * 2 + 0) * 64 + lane)) * 8);
      bf16x8 Bl1 = *(const bf16x8*)(Wl + ((size_t)((nb * 2 + 1) * 64 + lane)) * 8);
      f32x4 a2 = {0.f, 0.f, 0.f, 0.f};
      a2 = __builtin_amdgcn_mfma_f32_16x16x32_bf16(Ah[0], Bh0, a2, 0, 0, 0);
      a2 = __builtin_amdgcn_mfma_f32_16x16x32_bf16(Ah[1], Bh1, a2, 0, 0, 0);
      a2 = __builtin_amdgcn_mfma_f32_16x16x32_bf16(Ah[0], Bl0, a2, 0, 0, 0);
      a2 = __builtin_amdgcn_mfma_f32_16x16x32_bf16(Ah[1], Bl1, a2, 0, 0, 0);
      a2 = __builtin_amdgcn_mfma_f32_16x16x32_bf16(Al[0], Bh0, a2, 0, 0, 0);
      a2 = __builtin_amdgcn_mfma_f32_16x16x32_bf16(Al[1], Bh1, a2, 0, 0, 0);
#pragma unroll
      for (int r = 0; r < 4; ++r) {
        float vv2 = relu_(a2[r] + bB[nb]) * sB[nb] + hB[nb];
        __bf16 hb = (__bf16)vv2;
        __bf16 lb = (__bf16)(vv2 - (float)hb);
        h2w[(quad * 4 + r) * 68 + nb * 16 + lm] =
            (unsigned)bfbits(hb) | ((unsigned)bfbits(lb) << 16);
      }
    }
    bf16x8 A3h[2], A3l[2];
#pragma unroll
    for (int s = 0; s < 2; ++s) {
      const unsigned* rp = h2w + lm * 68 + s * 32 + quad * 8;
      uint4 da = *(const uint4*)rp;
      uint4 db = *(const uint4*)(rp + 4);
      unsigned dw[8] = {da.x, da.y, da.z, da.w, db.x, db.y, db.z, db.w};
      __bf16 th[8], tl[8];
#pragma unroll
      for (int j = 0; j < 8; ++j) {
        th[j] = bffrom((unsigned short)(dw[j] & 0xFFFFu));
        tl[j] = bffrom((unsigned short)(dw[j] >> 16));
      }
      A3h[s] = *(const bf16x8*)th;
      A3l[s] = *(const bf16x8*)tl;
    }
#pragma unroll
    for (int nb = 0; nb < 4; ++nb) {
      bf16x8 Bh0 = *(const bf16x8*)(Wh + 4096 + ((size_t)((nb * 2 + 0) * 64 + lane)) * 8);
      bf16x8 Bh1 = *(const bf16x8*)(Wh + 4096 + ((size_t)((nb * 2 + 1) * 64 + lane)) * 8);
      bf16x8 Bl0 = *(const bf16x8*)(Wl + 4096 + ((size_t)((nb * 2 + 0) * 64 + lane)) * 8);
      bf16x8 Bl1 = *(const bf16x8*)(Wl + 4096 + ((size_t)((nb * 2 + 1) * 64 + lane)) * 8);
      f32x4 a3 = {0.f, 0.f, 0.f, 0.f};
      a3 = __builtin_amdgcn_mfma_f32_16x16x32_bf16(A3h[0], Bh0, a3, 0, 0, 0);
      a3 = __builtin_amdgcn_mfma_f32_16x16x32_bf16(A3h[1], Bh1, a3, 0, 0, 0);
      a3 = __builtin_amdgcn_mfma_f32_16x16x32_bf16(A3h[0], Bl0, a3, 0, 0, 0);
      a3 = __builtin_amdgcn_mfma_f32_16x16x32_bf16(A3h[1], Bl1, a3, 0, 0, 0);
      a3 = __builtin_amdgcn_mfma_f32_16x16x32_bf16(A3l[0], Bh0, a3, 0, 0, 0);
      a3 = __builtin_amdgcn_mfma_f32_16x16x32_bf16(A3l[1], Bh1, a3, 0, 0, 0);
#pragma unroll
      for (int r = 0; r < 4; ++r) mmax[nb][r] = fmaxf(mmax[nb][r], a3[r]);
    }
  }
  float sqp[4] = {0.f, 0.f, 0.f, 0.f};
#pragma unroll
  for (int nb = 0; nb < 4; ++nb) {
    int c = nb * 16 + lm;
#pragma unroll
    for (int r = 0; r < 4; ++r) {
      float vv3 = relu_(mmax[nb][r] + bC[nb]) * sC[nb] + hC[nb];
      sqp[r] = fmaf(vv3, vv3, sqp[r]);
      __bf16 hb = (__bf16)vv3;
      __bf16 lb = (__bf16)(vv3 - (float)hb);
      int n = p0 + w * 16 + quad * 4 + r;
      xh[(size_t)n * 64 + c] = hb;
      xl[(size_t)n * 64 + c] = lb;
      xb[(size_t)n * 192 + c] = hb;
    }
  }
#pragma unroll
  for (int r = 0; r < 4; ++r) {
    float s = sqp[r];
    s += __shfl_xor(s, 1);
    s += __shfl_xor(s, 2);
    s += __shfl_xor(s, 4);
    s += __shfl_xor(s, 8);
    if (lm == 0) sqo[p0 + w * 16 + quad * 4 + r] = s;
  }
}

// ---------------- Kernel MID: knn2 (blk<1024) + pq_mfma (1024..2047), 26.6KB LDS union ----------------
// pq branch: 4 chunks of 4 nb, immediate writes -> only 4 live acc (low VGPR, knn2 residency kept)
__global__ __launch_bounds__(256) void k_mid(const __bf16* __restrict__ xh,
                                             const __bf16* __restrict__ xl,
                                             const float* __restrict__ sq,
                                             int* __restrict__ idx2,
                                             const __bf16* __restrict__ wph,
                                             const __bf16* __restrict__ wpl,
                                             __bf16* __restrict__ Pb,
                                             __bf16* __restrict__ Qb) {
  __shared__ __align__(16) float smem[6656];  // union: knn2 6656f / pq 4096f
  int tid = threadIdx.x;
  int w = tid >> 6, lane = tid & 63;
  int quad = lane >> 4, lm = lane & 15;
  if (blockIdx.x < 1024) {
    // ----- knn2: byte-identical math to R15 -----
    __bf16* Bh = (__bf16*)smem;
    __bf16* Bl = (__bf16*)(smem + 2304);
    float* sqs = smem + 4608;
    int b = blockIdx.x >> 5, qc = blockIdx.x & 31;
    int q0 = qc * 64;
    size_t bb = (size_t)b * 2048;
    for (int u = tid; u < 512; u += 256)
      *(float4*)(sqs + u * 4) = *(const float4*)(sq + bb + u * 4);
    const __bf16* qh = xh + (bb + q0 + w * 16 + lm) * 64 + quad * 8;
    const __bf16* ql = xl + (bb + q0 + w * 16 + lm) * 64 + quad * 8;
    bf16x8 Ah0 = *(const bf16x8*)(qh);
    bf16x8 Ah1 = *(const bf16x8*)(qh + 32);
    bf16x8 Al0 = *(const bf16x8*)(ql);
    bf16x8 Al1 = *(const bf16x8*)(ql + 32);
    __syncthreads();
    float qsq[4];
#pragma unroll
    for (int r = 0; r < 4; ++r) qsq[r] = sqs[q0 + w * 16 + quad * 4 + r];
    float bd[4][5];
    int bi[4][5];
#pragma unroll
    for (int r = 0; r < 4; ++r)
#pragma unroll
      for (int k = 0; k < 5; ++k) { bd[r][k] = 1e30f; bi[r][k] = 0; }
    for (int ct = 0; ct < 32; ++ct) {
#pragma unroll
      for (int pass = 0; pass < 2; ++pass) {
        int unit = pass * 256 + tid;
        int n = unit >> 3, cc = unit & 7;
        const __bf16* gsrc = xh + (bb + ct * 64 + n) * 64 + cc * 8;
        const __bf16* gsrl = xl + (bb + ct * 64 + n) * 64 + cc * 8;
        *(uint4*)(Bh + n * 72 + cc * 8) = *(const uint4*)gsrc;
        *(uint4*)(Bl + n * 72 + cc * 8) = *(const uint4*)gsrl;
      }
      __syncthreads();
#pragma unroll
      for (int nt = 0; nt < 4; ++nt) {
        const __bf16* bph = Bh + (nt * 16 + lm) * 72 + quad * 8;
        const __bf16* bpl = Bl + (nt * 16 + lm) * 72 + quad * 8;
        bf16x8 Bh0 = *(const bf16x8*)(bph);
        bf16x8 Bh1 = *(const bf16x8*)(bph + 32);
        bf16x8 Bl0 = *(const bf16x8*)(bpl);
        bf16x8 Bl1 = *(const bf16x8*)(bpl + 32);
        f32x4 acc = {0.f, 0.f, 0.f, 0.f};
        acc = __builtin_amdgcn_mfma_f32_16x16x32_bf16(Ah0, Bh0, acc, 0, 0, 0);
        acc = __builtin_amdgcn_mfma_f32_16x16x32_bf16(Ah1, Bh1, acc, 0, 0, 0);
        acc = __builtin_amdgcn_mfma_f32_16x16x32_bf16(Ah0, Bl0, acc, 0, 0, 0);
        acc = __builtin_amdgcn_mfma_f32_16x16x32_bf16(Ah1, Bl1, acc, 0, 0, 0);
        acc = __builtin_amdgcn_mfma_f32_16x16x32_bf16(Al0, Bh0, acc, 0, 0, 0);
        acc = __builtin_amdgcn_mfma_f32_16x16x32_bf16(Al1, Bh1, acc, 0, 0, 0);
        int cid = ct * 64 + nt * 16 + lm;
        float csq = sqs[cid];
#pragma unroll
        for (int r = 0; r < 4; ++r) {
          float d = (qsq[r] + csq) - 2.0f * acc[r];
          knn_insert(bd[r], bi[r], d, cid);
        }
      }
      __syncthreads();
    }
    for (int m = 1; m <= 8; m <<= 1) {
#pragma unroll
      for (int r = 0; r < 4; ++r) {
        float od[5]; int oi[5];
#pragma unroll
        for (int k = 0; k < 5; ++k) {
          od[k] = __shfl_xor(bd[r][k], m);
          oi[k] = __shfl_xor(bi[r][k], m);
        }
#pragma unroll
        for (int k = 0; k < 5; ++k) knn_insert(bd[r], bi[r], od[k], oi[k]);
      }
    }
    if (lm == 0) {
#pragma unroll
      for (int r = 0; r < 4; ++r) {
        int qi = q0 + w * 16 + quad * 4 + r;
        int* op = idx2 + (bb + qi) * 5;
#pragma unroll
        for (int k = 0; k < 5; ++k) op[k] = bi[r][k];
      }
    }
  } else {
    // ----- pq_mfma: 4 chunks of 4 nb, immediate writes (low VGPR) -----
    __bf16* Wh = (__bf16*)smem;           // 4096 bf16 (2048 f)
    __bf16* Wl = (__bf16*)(smem + 2048);  // 4096 bf16
    int n0 = (blockIdx.x - 1024) * 64;
    const __bf16* ah = xh + (size_t)(n0 + w * 16 + lm) * 64 + quad * 8;
    const __bf16* al = xl + (size_t)(n0 + w * 16 + lm) * 64 + quad * 8;
    bf16x8 Ah0 = *(const bf16x8*)(ah);
    bf16x8 Ah1 = *(const bf16x8*)(ah + 32);
    bf16x8 Al0 = *(const bf16x8*)(al);
    bf16x8 Al1 = *(const bf16x8*)(al + 32);
    for (int chunk = 0; chunk < 4; ++chunk) {
      __syncthreads();  // protect previous chunk's frag reads
#pragma unroll
      for (int it = 0; it < 2; ++it) {
        int unit = it * 256 + tid;  // 0..511 (x8 bf16 = 4096)
        *(uint4*)(Wh + (size_t)unit * 8) =
            *(const uint4*)(wph + (size_t)chunk * 4096 + (size_t)unit * 8);
        *(uint4*)(Wl + (size_t)unit * 8) =
            *(const uint4*)(wpl + (size_t)chunk * 4096 + (size_t)unit * 8);
      }
      __syncthreads();
#pragma unroll
      for (int nb4 = 0; nb4 < 4; ++nb4) {
        int nb = chunk * 4 + nb4;
        bf16x8 Bh0 = *(const bf16x8*)(Wh + ((size_t)(nb4 * 2 + 0) * 64 + lane) * 8);
        bf16x8 Bh1 = *(const bf16x8*)(Wh + ((size_t)(nb4 * 2 + 1) * 64 + lane) * 8);
        bf16x8 Bl0 = *(const bf16x8*)(Wl + ((size_t)(nb4 * 2 + 0) * 64 + lane) * 8);
        bf16x8 Bl1 = *(const bf16x8*)(Wl + ((size_t)(nb4 * 2 + 1) * 64 + lane) * 8);
        f32x4 acc = {0.f, 0.f, 0.f, 0.f};
        acc = __builtin_amdgcn_mfma_f32_16x16x32_bf16(Ah0, Bh0, acc, 0, 0, 0);
        acc = __builtin_amdgcn_mfma_f32_16x16x32_bf16(Ah1, Bh1, acc, 0, 0, 0);
        acc = __builtin_amdgcn_mfma_f32_16x16x32_bf16(Ah0, Bl0, acc, 0, 0, 0);
        acc = __builtin_amdgcn_mfma_f32_16x16x32_bf16(Ah1, Bl1, acc, 0, 0, 0);
        acc = __builtin_amdgcn_mfma_f32_16x16x32_bf16(Al0, Bh0, acc, 0, 0, 0);
        acc = __builtin_amdgcn_mfma_f32_16x16x32_bf16(Al1, Bh1, acc, 0, 0, 0);
        bool isP = (nb < 8);
        __bf16* base = isP ? Pb : Qb;
        int col = (isP ? nb : nb - 8) * 16 + lm;
#pragma unroll
        for (int r = 0; r < 4; ++r) {
          int n = n0 + w * 16 + quad * 4 + r;
          base[(size_t)n * 128 + col] = (__bf16)acc[r];
        }
      }
    }
  }
}

// ---------------- Kernel 4b: gather-max + activation, 2 channels/lane ----------------
__global__ __launch_bounds__(256) void k_gmax(const __bf16* __restrict__ Pb,
                                              const __bf16* __restrict__ Qb,
                                              const int* __restrict__ idx2,
                                              const float* __restrict__ b2,
                                              const float* __restrict__ s2,
                                              const float* __restrict__ h2v,
                                              __bf16* __restrict__ xb) {
  int tid = threadIdx.x;
  int c2 = tid & 63, p = tid >> 6;
  int n = blockIdx.x * 4 + p;
  int b = n >> 11;
  const int* ip = idx2 + n * 5;
  int c0 = c2 * 2;
  float m0 = -3.4e38f, m1 = -3.4e38f;
#pragma unroll
  for (int k = 0; k < 5; ++k) {
    int j = ip[k];
    unsigned q = *(const unsigned*)(Qb + ((size_t)(b * 2048 + j)) * 128 + c0);
    m0 = fmaxf(m0, (float)bffrom((unsigned short)(q & 0xFFFFu)));
    m1 = fmaxf(m1, (float)bffrom((unsigned short)(q >> 16)));
  }
  unsigned pv = *(const unsigned*)(Pb + (size_t)n * 128 + c0);
  float v0 = (float)bffrom((unsigned short)(pv & 0xFFFFu)) + m0 + b2[c0];
  float v1 = (float)bffrom((unsigned short)(pv >> 16)) + m1 + b2[c0 + 1];
  __bf16 o0 = (__bf16)(relu_(v0) * s2[c0] + h2v[c0]);
  __bf16 o1 = (__bf16)(relu_(v1) * s2[c0 + 1] + h2v[c0 + 1]);
  unsigned ov = (unsigned)bfbits(o0) | ((unsigned)bfbits(o1) << 16);
  *(unsigned*)(xb + (size_t)n * 192 + 64 + c0) = ov;
}

// ---------------- Kernel 5: bf16 MFMA GEMM fused point-max, 64m x 256n tiles ----------------
__global__ __launch_bounds__(256) void k_linl_mfma(const __bf16* __restrict__ xb,
                                                   const __bf16* __restrict__ wlb,
                                                   float* __restrict__ pool_part) {
  __shared__ __align__(16) __bf16 Al[2048];
  __shared__ __align__(16) __bf16 Bl[8192];
  int tid = threadIdx.x;
  int w = tid >> 6, lane = tid & 63;
  int mg = blockIdx.x >> 2, ng = blockIdx.x & 3;
  int n0 = mg << 6;
  int quad = lane >> 4, lm = lane & 15;
  f32x4 acc[4][4];
#pragma unroll
  for (int i = 0; i < 4; ++i)
#pragma unroll
    for (int j = 0; j < 4; ++j) acc[i][j] = (f32x4){0.f, 0.f, 0.f, 0.f};
  for (int ks = 0; ks < 6; ++ks) {
    __syncthreads();
    {
      int mb = tid >> 6, ln = tid & 63;
      int lmm = ln & 15, qd = ln >> 4;
      const uint4* ga = (const uint4*)(xb + (size_t)(n0 + mb * 16 + lmm) * 192 + ks * 32 + qd * 8);
      *(uint4*)(Al + ((size_t)(mb * 64 + ln)) * 8) = *ga;
    }
#pragma unroll
    for (int nt2 = 0; nt2 < 2; ++nt2) {
#pragma unroll
      for (int u = 0; u < 2; ++u) {
        int unit = u * 256 + tid;
        const uint4* gb = (const uint4*)(wlb + ((size_t)((ng * 2 + nt2) * 6 + ks)) * 4096 + (size_t)unit * 8);
        *(uint4*)(Bl + (size_t)nt2 * 4096 + (size_t)unit * 8) = *gb;
      }
    }
    __syncthreads();
    bf16x8 af[4], bfr[4];
#pragma unroll
    for (int i = 0; i < 4; ++i)
      af[i] = *(const bf16x8*)(Al + ((size_t)(i * 64 + lane)) * 8);
    int nt2 = w >> 1, nbb = (w & 1) * 4;
#pragma unroll
    for (int j = 0; j < 4; ++j)
      bfr[j] = *(const bf16x8*)(Bl + (size_t)nt2 * 4096 + ((size_t)((nbb + j) * 64 + lane)) * 8);
#pragma unroll
    for (int i = 0; i < 4; ++i)
#pragma unroll
      for (int j = 0; j < 4; ++j)
        acc[i][j] = __builtin_amdgcn_mfma_f32_16x16x32_bf16(af[i], bfr[j], acc[i][j], 0, 0, 0);
  }
#pragma unroll
  for (int j = 0; j < 4; ++j) {
    float m = -3.4e38f;
#pragma unroll
    for (int i = 0; i < 4; ++i)
#pragma unroll
      for (int r = 0; r < 4; ++r) m = fmaxf(m, acc[i][j][r]);
    m = fmaxf(m, __shfl_xor(m, 16));
    m = fmaxf(m, __shfl_xor(m, 32));
    if (quad == 0) {
      int ch = ng * 256 + (w >> 1) * 128 + (w & 1) * 64 + j * 16 + lm;
      pool_part[(size_t)mg * 1024 + ch] = m;
    }
  }
}

// ---------------- Kernel 6: head MLP (32-way pool merge) ----------------
__global__ __launch_bounds__(256) void k_head(
    const float* __restrict__ pool_part, const float* __restrict__ bl,
    const float* __restrict__ sl, const float* __restrict__ hl,
    const float* __restrict__ wm1, const float* __restrict__ bm1,
    const float* __restrict__ sm1, const float* __restrict__ hm1,
    const float* __restrict__ wm2, const float* __restrict__ bm2,
    const float* __restrict__ sm2, const float* __restrict__ hm2,
    const float* __restrict__ wout, const float* __restrict__ bout,
    float* __restrict__ out) {
  __shared__ float p_s[1024], h1_s[512], h2_s[256];
  int b = blockIdx.x, tid = threadIdx.x;
  for (int c = tid; c < 1024; c += 256) {
    float m = -3.4e38f;
#pragma unroll 4
    for (int t = 0; t < 32; ++t)
      m = fmaxf(m, pool_part[(size_t)(b * 32 + t) * 1024 + c]);
    p_s[c] = relu_(m + bl[c]) * sl[c] + hl[c];
  }
  __syncthreads();
  for (int c = tid; c < 512; c += 256) {
    float a0 = 0, a1 = 0, a2 = 0, a3 = 0;
    for (int f = 0; f < 1024; f += 4) {
      a0 = fmaf(p_s[f], wm1[f * 512 + c], a0);
      a1 = fmaf(p_s[f + 1], wm1[(f + 1) * 512 + c], a1);
      a2 = fmaf(p_s[f + 2], wm1[(f + 2) * 512 + c], a2);
      a3 = fmaf(p_s[f + 3], wm1[(f + 3) * 512 + c], a3);
    }
    float a = (a0 + a1) + (a2 + a3);
    h1_s[c] = relu_(a + bm1[c]) * sm1[c] + hm1[c];
  }
  __syncthreads();
  if (tid < 256) {
    float a0 = 0, a1 = 0, a2 = 0, a3 = 0;
    for (int f = 0; f < 512; f += 4) {
      a0 = fmaf(h1_s[f], wm2[f * 256 + tid], a0);
      a1 = fmaf(h1_s[f + 1], wm2[(f + 1) * 256 + tid], a1);
      a2 = fmaf(h1_s[f + 2], wm2[(f + 2) * 256 + tid], a2);
      a3 = fmaf(h1_s[f + 3], wm2[(f + 3) * 256 + tid], a3);
    }
    float a = (a0 + a1) + (a2 + a3);
    h2_s[tid] = relu_(a + bm2[tid]) * sm2[tid] + hm2[tid];
  }
  __syncthreads();
  if (tid < 2) {
    float a0 = 0, a1 = 0;
    for (int f = 0; f < 256; f += 2) {
      a0 = fmaf(h2_s[f], wout[f * 2 + tid], a0);
      a1 = fmaf(h2_s[f + 1], wout[(f + 1) * 2 + tid], a1);
    }
    out[b * 2 + tid] = (a0 + a1) + bout[tid];
  }
}

extern "C" void kernel_launch(void* const* d_in, const int* in_sizes, int n_in,
                              void* d_out, int out_size, void* d_ws, size_t ws_size,
                              hipStream_t stream) {
  const float* pos = (const float*)d_in[0];
  const float* w1a = (const float*)d_in[1];
  const float* b1a = (const float*)d_in[2];
  const float* s1a = (const float*)d_in[3];
  const float* h1a = (const float*)d_in[4];
  const float* w1b = (const float*)d_in[5];
  const float* b1b = (const float*)d_in[6];
  const float* s1b = (const float*)d_in[7];
  const float* h1b = (const float*)d_in[8];
  const float* w1c = (const float*)d_in[9];
  const float* b1c = (const float*)d_in[10];
  const float* s1c = (const float*)d_in[11];
  const float* h1c = (const float*)d_in[12];
  const float* w2 = (const float*)d_in[13];
  const float* b2 = (const float*)d_in[14];
  const float* s2 = (const float*)d_in[15];
  const float* h2 = (const float*)d_in[16];
  const float* wl = (const float*)d_in[17];
  const float* bl = (const float*)d_in[18];
  const float* sl = (const float*)d_in[19];
  const float* hl = (const float*)d_in[20];
  const float* wm1 = (const float*)d_in[21];
  const float* bm1 = (const float*)d_in[22];
  const float* sm1 = (const float*)d_in[23];
  const float* hm1 = (const float*)d_in[24];
  const float* wm2 = (const float*)d_in[25];
  const float* bm2 = (const float*)d_in[26];
  const float* sm2 = (const float*)d_in[27];
  const float* hm2 = (const float*)d_in[28];
  const float* wout = (const float*)d_in[29];
  const float* bout = (const float*)d_in[30];
  float* out = (float*)d_out;

  // workspace: xh | xl | Pb | Qb | xb | idx | sq | wph/wpl/wfh/wfl | wlb (~77.6 MB)
  float* base = (float*)d_ws;
  __bf16* xh = (__bf16*)base;
  __bf16* xl = (__bf16*)(base + 2097152);
  float* PbF = base + 4194304;
  float* QbF = PbF + 4194304;
  float* xbF = QbF + 4194304;
  int* idx = (int*)(xbF + 6291456);
  float* sq = (float*)(idx + 327680);
  __bf16* wph = (__bf16*)(sq + 65536);
  __bf16* wpl = (__bf16*)(sq + 65536 + 8192);
  __bf16* wfh = (__bf16*)(sq + 65536 + 16384);
  __bf16* wfl = (__bf16*)(sq + 65536 + 20480);
  __bf16* wlb = (__bf16*)(sq + 65536 + 24576);
  __bf16* Pb = (__bf16*)PbF;
  __bf16* Qb = (__bf16*)QbF;
  __bf16* xb = (__bf16*)xbF;
  float* uR = PbF;                                // alias (dead until k_mid's pq)
  float* vR = QbF;
  float* pool_part = base + 131072;               // overlaps xl/Pb head: dead by linl

  k_front<<<3180, 256, 0, stream>>>(pos, w1a, b1a, w1b, w1c, w2, wl, idx, uR, vR,
                                    wfh, wfl, wph, wpl, wlb);
  k_edge1<<<1024, 256, 0, stream>>>(idx, uR, vR, s1a, h1a, b1b, s1b, h1b, b1c,
                                    s1c, h1c, wfh, wfl, xh, xl, sq, xb);
  k_mid<<<2048, 256, 0, stream>>>(xh, xl, sq, idx, wph, wpl, Pb, Qb);
  k_gmax<<<16384, 256, 0, stream>>>(Pb, Qb, idx, b2, s2, h2, xb);
  k_linl_mfma<<<4096, 256, 0, stream>>>(xb, wlb, pool_part);
  k_head<<<32, 256, 0, stream>>>(pool_part, bl, sl, hl, wm1, bm1, sm1, hm1, wm2,
                                 bm2, sm2, hm2, wout, bout, out);
}

// Round 18
// 524.680 us; speedup vs baseline: 1.5266x; 1.0199x over previous
//
#include <hip/hip_runtime.h>

#define DEV __device__ __forceinline__
DEV float relu_(float x) { return fmaxf(x, 0.0f); }

typedef __attribute__((ext_vector_type(4))) float f32x4;
typedef __attribute__((ext_vector_type(8))) __bf16 bf16x8;

DEV unsigned short bfbits(__bf16 b) { union { unsigned short s; __bf16 b; } x; x.b = b; return x.s; }
DEV __bf16 bffrom(unsigned short s) { union { unsigned short s; __bf16 b; } x; x.s = s; return x.b; }

// branchy top-5 insert (R6-measured best for knn2's wave-coherent stream)
DEV void knn_insert(float (&bd)[5], int (&bi)[5], float d, int j) {
  if (d >= bd[4]) return;
  bd[4] = d; bi[4] = j;
#pragma unroll
  for (int p = 4; p > 0; --p) {
    if (bd[p] < bd[p - 1]) {
      float td = bd[p]; bd[p] = bd[p - 1]; bd[p - 1] = td;
      int ti = bi[p]; bi[p] = bi[p - 1]; bi[p - 1] = ti;
    }
  }
}

// branchless EXACT top-5 insert (used in knn1)
DEV void knn_insert_bl(float (&bd)[5], int (&bi)[5], float d, int j) {
#pragma unroll
  for (int p = 0; p < 5; ++p) {
    bool lt = d < bd[p];
    float nd = lt ? d : bd[p];
    float cd = lt ? bd[p] : d;
    int ni = lt ? j : bi[p];
    int ci = lt ? bi[p] : j;
    bd[p] = nd; d = cd;
    bi[p] = ni; j = ci;
  }
}

// ---------------- Kernel FRONT: knn1 (blk<2048) + uv (2048..3071) + preps (3072..3179) ----------------
__global__ __launch_bounds__(256) void k_front(
    const float* __restrict__ pos, const float* __restrict__ w1a,
    const float* __restrict__ b1a, const float* __restrict__ w1b,
    const float* __restrict__ w1c, const float* __restrict__ w2,
    const float* __restrict__ wl,
    int* __restrict__ idx1, float* __restrict__ uR, float* __restrict__ vR,
    __bf16* __restrict__ wfh, __bf16* __restrict__ wfl,
    __bf16* __restrict__ wph, __bf16* __restrict__ wpl,
    __bf16* __restrict__ wlb) {
  __shared__ __align__(16) float smem[9472];
  int tid = threadIdx.x;
  int blk = blockIdx.x;
  if (blk < 2048) {
    float* ps = smem;
    float* sqs = smem + 6144;
    float* md = smem + 8192;
    int* mi = (int*)(smem + 8832);
    int b = blk >> 6, qc = blk & 63;
    const float* src = pos + b * 6144;
    for (int u = tid; u < 6144; u += 256) ps[u] = src[u];
    __syncthreads();
    for (int u = tid; u < 2048; u += 256) {
      float x = ps[u * 3], y = ps[u * 3 + 1], z = ps[u * 3 + 2];
      sqs[u] = fmaf(z, z, fmaf(y, y, x * x));
    }
    __syncthreads();
    int q = tid & 31, sub = tid >> 5;
    int qi = qc * 32 + q;
    float qx = ps[qi * 3], qy = ps[qi * 3 + 1], qz = ps[qi * 3 + 2];
    float qsq = sqs[qi];
    float bd[5] = {1e30f, 1e30f, 1e30f, 1e30f, 1e30f};
    int bi[5] = {0, 0, 0, 0, 0};
    int j0 = sub * 256;
    for (int j = j0; j < j0 + 256; ++j) {
      float px = ps[j * 3], py = ps[j * 3 + 1], pz = ps[j * 3 + 2];
      float dot = fmaf(qz, pz, fmaf(qy, py, qx * px));
      float d = (qsq + sqs[j]) - 2.0f * dot;
      knn_insert_bl(bd, bi, d, j);
    }
    for (int half = 4; half >= 1; half >>= 1) {
      __syncthreads();
      if (sub >= half && sub < 2 * half) {
        int slot = (q * 4 + (sub - half)) * 5;
#pragma unroll
        for (int k = 0; k < 5; ++k) { md[slot + k] = bd[k]; mi[slot + k] = bi[k]; }
      }
      __syncthreads();
      if (sub < half) {
        int slot = (q * 4 + sub) * 5;
#pragma unroll
        for (int k = 0; k < 5; ++k) knn_insert_bl(bd, bi, md[slot + k], mi[slot + k]);
      }
    }
    if (sub == 0) {
      int* op = idx1 + (b * 2048 + qi) * 5;
#pragma unroll
      for (int k = 0; k < 5; ++k) op[k] = bi[k];
    }
  } else if (blk < 3072) {
    float* wAs = smem;
    float* bs = smem + 384;
    float* uS = smem + 448;
    float* vS = smem + 4800;
    for (int u = tid; u < 384; u += 256) wAs[u] = w1a[u];
    if (tid < 64) bs[tid] = b1a[tid];
    __syncthreads();
    int lane = tid & 63, fq = tid >> 6;
    int p0 = (blk - 2048) * 64;
    int p = p0 + lane;
    float x0 = pos[p * 3], x1 = pos[p * 3 + 1], x2 = pos[p * 3 + 2];
#pragma unroll
    for (int m = 0; m < 16; ++m) {
      int f = fq * 16 + m;
      float wt0 = wAs[f], wt1 = wAs[64 + f], wt2 = wAs[128 + f];
      float wb0 = wAs[192 + f], wb1 = wAs[256 + f], wb2 = wAs[320 + f];
      float uval = bs[f];
      uval = fmaf(x0, wt0 - wb0, uval);
      uval = fmaf(x1, wt1 - wb1, uval);
      uval = fmaf(x2, wt2 - wb2, uval);
      uS[lane * 68 + f] = uval;
      vS[lane * 68 + f] = fmaf(x2, wb2, fmaf(x1, wb1, x0 * wb0));
    }
    __syncthreads();
#pragma unroll
    for (int it = 0; it < 4; ++it) {
      int g = it * 1024 + tid * 4;
      int pl = g >> 6, f = g & 63;
      float4 uu = *(const float4*)(uS + pl * 68 + f);
      float4 vv = *(const float4*)(vS + pl * 68 + f);
      *(float4*)(uR + (size_t)p0 * 64 + g) = uu;
      *(float4*)(vR + (size_t)p0 * 64 + g) = vv;
    }
  } else {
    int pblk = blk - 3072;
    if (pblk < 4) {
      int t = pblk * 256 + tid;
      int m = t >> 9;
      int rem = t & 511;
      int nb = rem >> 7;
      int rem2 = rem & 127;
      int s = rem2 >> 6, lane = rem2 & 63;
      int k0 = s * 32 + (lane >> 4) * 8;
      int c = nb * 16 + (lane & 15);
      const float* W = m ? w1c : w1b;
      __bf16 oh[8], ol[8];
#pragma unroll
      for (int j = 0; j < 8; ++j) {
        float val = W[(k0 + j) * 64 + c];
        __bf16 h = (__bf16)val;
        oh[j] = h;
        ol[j] = (__bf16)(val - (float)h);
      }
      size_t off = (size_t)m * 4096 + ((size_t)((nb * 2 + s) * 64 + lane)) * 8;
      *(uint4*)(wfh + off) = *(const uint4*)oh;
      *(uint4*)(wfl + off) = *(const uint4*)ol;
    } else if (pblk < 12) {
      int t = (pblk - 4) * 256 + tid;
      int nb = t >> 7;
      int rem = t & 127;
      int ks = rem >> 6, lane = rem & 63;
      int k0 = ks * 32 + (lane >> 4) * 8;
      int col16 = lane & 15;
      __bf16 oh[8], ol[8];
#pragma unroll
      for (int j = 0; j < 8; ++j) {
        int k = k0 + j;
        float val;
        if (nb < 8) {
          int c = nb * 16 + col16;
          val = w2[k * 128 + c] - w2[(64 + k) * 128 + c];
        } else {
          int c = (nb - 8) * 16 + col16;
          val = w2[(64 + k) * 128 + c];
        }
        __bf16 h = (__bf16)val;
        oh[j] = h;
        ol[j] = (__bf16)(val - (float)h);
      }
      *(uint4*)(wph + (size_t)t * 8) = *(const uint4*)oh;
      *(uint4*)(wpl + (size_t)t * 8) = *(const uint4*)ol;
    } else {
      int t = (pblk - 12) * 256 + tid;
      int nt = t / 3072;
      int rem = t - nt * 3072;
      int ks = rem / 512;
      int rem2 = rem - ks * 512;
      int nb = rem2 >> 6, lane = rem2 & 63;
      int k0 = ks * 32 + (lane >> 4) * 8;
      int n = nt * 128 + nb * 16 + (lane & 15);
      __bf16 o[8];
#pragma unroll
      for (int j = 0; j < 8; ++j) o[j] = (__bf16)wl[(k0 + j) * 1024 + n];
      *(uint4*)(wlb + (size_t)t * 8) = *(const uint4*)o;
    }
  }
}

// ---------------- Kernel 2: EdgeConv1 layers 2/3 via hi/lo MFMA, barrier-free k-loop ----------------
__global__ __launch_bounds__(256) void k_edge1(
    const int* __restrict__ idx1, const float* __restrict__ uR,
    const float* __restrict__ vR,
    const float* __restrict__ s1a, const float* __restrict__ h1a,
    const float* __restrict__ b1b, const float* __restrict__ s1b,
    const float* __restrict__ h1b,
    const float* __restrict__ b1c, const float* __restrict__ s1c,
    const float* __restrict__ h1c,
    const __bf16* __restrict__ wfh, const __bf16* __restrict__ wfl,
    __bf16* __restrict__ xh, __bf16* __restrict__ xl,
    float* __restrict__ sqo, __bf16* __restrict__ xb) {
  __shared__ __align__(16) __bf16 Wh[8192], Wl[8192];
  __shared__ __align__(16) unsigned h2b[4 * 1088];
  int tid = threadIdx.x;
  int w = tid >> 6, lane = tid & 63;
  int quad = lane >> 4, lm = lane & 15;
#pragma unroll
  for (int it = 0; it < 4; ++it) {
    int u4 = it * 256 + tid;
    *(uint4*)(Wh + (size_t)u4 * 8) = *(const uint4*)(wfh + (size_t)u4 * 8);
    *(uint4*)(Wl + (size_t)u4 * 8) = *(const uint4*)(wfl + (size_t)u4 * 8);
  }
  int p0 = blockIdx.x * 64;
  int b = p0 >> 11;
  size_t bb = (size_t)b * 2048;
  int edge = p0 + w * 16 + lm;
  float sA[2][8], hA[2][8];
#pragma unroll
  for (int s = 0; s < 2; ++s)
#pragma unroll
    for (int j = 0; j < 8; ++j) {
      int k = s * 32 + quad * 8 + j;
      sA[s][j] = s1a[k]; hA[s][j] = h1a[k];
    }
  float bB[4], sB[4], hB[4], bC[4], sC[4], hC[4];
#pragma unroll
  for (int nb = 0; nb < 4; ++nb) {
    int c = nb * 16 + lm;
    bB[nb] = b1b[c]; sB[nb] = s1b[c]; hB[nb] = h1b[c];
    bC[nb] = b1c[c]; sC[nb] = s1c[c]; hC[nb] = h1c[c];
  }
  unsigned* h2w = h2b + w * 1088;
  f32x4 mmax[4];
#pragma unroll
  for (int nb = 0; nb < 4; ++nb)
    mmax[nb] = (f32x4){-3.4e38f, -3.4e38f, -3.4e38f, -3.4e38f};
  __syncthreads();
  const float* urow = uR + (size_t)edge * 64;
  for (int kk = 0; kk < 5; ++kk) {
    int jn = idx1[edge * 5 + kk];
    const float* vrow = vR + (bb + jn) * 64;
    bf16x8 Ah[2], Al[2];
#pragma unroll
    for (int s = 0; s < 2; ++s) {
      int off = s * 32 + quad * 8;
      float4 u0 = *(const float4*)(urow + off);
      float4 u1 = *(const float4*)(urow + off + 4);
      float4 v0 = *(const float4*)(vrow + off);
      float4 v1 = *(const float4*)(vrow + off + 4);
      float uv[8] = {u0.x + v0.x, u0.y + v0.y, u0.z + v0.z, u0.w + v0.w,
                     u1.x + v1.x, u1.y + v1.y, u1.z + v1.z, u1.w + v1.w};
      __bf16 th[8], tl[8];
#pragma unroll
      for (int j = 0; j < 8; ++j) {
        float val = relu_(uv[j]) * sA[s][j] + hA[s][j];
        __bf16 hb = (__bf16)val;
        th[j] = hb;
        tl[j] = (__bf16)(val - (float)hb);
      }
      Ah[s] = *(const bf16x8*)th;
      Al[s] = *(const bf16x8*)tl;
    }
#pragma unroll
    for (int nb = 0; nb < 4; ++nb) {
      bf16x8 Bh0 = *(const bf16x8*)(Wh + ((size_t)((nb * 2 + 0) * 64 + lane)) * 8);
      bf16x8 Bh1 = *(const bf16x8*)(Wh + ((size_t)((nb * 2 + 1) * 64 + lane)) * 8);
      bf16x8 Bl0 = *(const bf16x8*)(Wl + ((size_t)((nb * 2 + 0) * 64 + lane)) * 8);
      bf16x8 Bl1 = *(const bf16x8*)(Wl + ((size_t)((nb * 2 + 1) * 64 + lane)) * 8);
      f32x4 a2 = {0.f, 0.f, 0.f, 0.f};
      a2 = __builtin_amdgcn_mfma_f32_16x16x32_bf16(Ah[0], Bh0, a2, 0, 0, 0);
      a2 = __builtin_amdgcn_mfma_f32_16x16x32_bf16(Ah[1], Bh1, a2, 0, 0, 0);
      a2 = __builtin_amdgcn_mfma_f32_16x16x32_bf16(Ah[0], Bl0, a2, 0, 0, 0);
      a2 = __builtin_amdgcn_mfma_f32_16x16x32_bf16(Ah[1], Bl1, a2, 0, 0, 0);
      a2 = __builtin_amdgcn_mfma_f32_16x16x32_bf16(Al[0], Bh0, a2, 0, 0, 0);
      a2 = __builtin_amdgcn_mfma_f32_16x16x32_bf16(Al[1], Bh1, a2, 0, 0, 0);
#pragma unroll
      for (int r = 0; r < 4; ++r) {
        float vv2 = relu_(a2[r] + bB[nb]) * sB[nb] + hB[nb];
        __bf16 hb = (__bf16)vv2;
        __bf16 lb = (__bf16)(vv2 - (float)hb);
        h2w[(quad * 4 + r) * 68 + nb * 16 + lm] =
            (unsigned)bfbits(hb) | ((unsigned)bfbits(lb) << 16);
      }
    }
    bf16x8 A3h[2], A3l[2];
#pragma unroll
    for (int s = 0; s < 2; ++s) {
      const unsigned* rp = h2w + lm * 68 + s * 32 + quad * 8;
      uint4 da = *(const uint4*)rp;
      uint4 db = *(const uint4*)(rp + 4);
      unsigned dw[8] = {da.x, da.y, da.z, da.w, db.x, db.y, db.z, db.w};
      __bf16 th[8], tl[8];
#pragma unroll
      for (int j = 0; j < 8; ++j) {
        th[j] = bffrom((unsigned short)(dw[j] & 0xFFFFu));
        tl[j] = bffrom((unsigned short)(dw[j] >> 16));
      }
      A3h[s] = *(const bf16x8*)th;
      A3l[s] = *(const bf16x8*)tl;
    }
#pragma unroll
    for (int nb = 0; nb < 4; ++nb) {
      bf16x8 Bh0 = *(const bf16x8*)(Wh + 4096 + ((size_t)((nb * 2 + 0) * 64 + lane)) * 8);
      bf16x8 Bh1 = *(const bf16x8*)(Wh + 4096 + ((size_t)((nb * 2 + 1) * 64 + lane)) * 8);
      bf16x8 Bl0 = *(const bf16x8*)(Wl + 4096 + ((size_t)((nb * 2 + 0) * 64 + lane)) * 8);
      bf16x8 Bl1 = *(const bf16x8*)(Wl + 4096 + ((size_t)((nb * 2 + 1) * 64 + lane)) * 8);
      f32x4 a3 = {0.f, 0.f, 0.f, 0.f};
      a3 = __builtin_amdgcn_mfma_f32_16x16x32_bf16(A3h[0], Bh0, a3, 0, 0, 0);
      a3 = __builtin_amdgcn_mfma_f32_16x16x32_bf16(A3h[1], Bh1, a3, 0, 0, 0);
      a3 = __builtin_amdgcn_mfma_f32_16x16x32_bf16(A3h[0], Bl0, a3, 0, 0, 0);
      a3 = __builtin_amdgcn_mfma_f32_16x16x32_bf16(A3h[1], Bl1, a3, 0, 0, 0);
      a3 = __builtin_amdgcn_mfma_f32_16x16x32_bf16(A3l[0], Bh0, a3, 0, 0, 0);
      a3 = __builtin_amdgcn_mfma_f32_16x16x32_bf16(A3l[1], Bh1, a3, 0, 0, 0);
#pragma unroll
      for (int r = 0; r < 4; ++r) mmax[nb][r] = fmaxf(mmax[nb][r], a3[r]);
    }
  }
  float sqp[4] = {0.f, 0.f, 0.f, 0.f};
#pragma unroll
  for (int nb = 0; nb < 4; ++nb) {
    int c = nb * 16 + lm;
#pragma unroll
    for (int r = 0; r < 4; ++r) {
      float vv3 = relu_(mmax[nb][r] + bC[nb]) * sC[nb] + hC[nb];
      sqp[r] = fmaf(vv3, vv3, sqp[r]);
      __bf16 hb = (__bf16)vv3;
      __bf16 lb = (__bf16)(vv3 - (float)hb);
      int n = p0 + w * 16 + quad * 4 + r;
      xh[(size_t)n * 64 + c] = hb;
      xl[(size_t)n * 64 + c] = lb;
      xb[(size_t)n * 192 + c] = hb;
    }
  }
#pragma unroll
  for (int r = 0; r < 4; ++r) {
    float s = sqp[r];
    s += __shfl_xor(s, 1);
    s += __shfl_xor(s, 2);
    s += __shfl_xor(s, 4);
    s += __shfl_xor(s, 8);
    if (lm == 0) sqo[p0 + w * 16 + quad * 4 + r] = s;
  }
}

// ---------------- Kernel MID: knn2 (blk<1024) + pq_mfma (1024..2047), 26.6KB LDS union ----------------
__global__ __launch_bounds__(256) void k_mid(const __bf16* __restrict__ xh,
                                             const __bf16* __restrict__ xl,
                                             const float* __restrict__ sq,
                                             int* __restrict__ idx2,
                                             const __bf16* __restrict__ wph,
                                             const __bf16* __restrict__ wpl,
                                             __bf16* __restrict__ Pb,
                                             __bf16* __restrict__ Qb) {
  __shared__ __align__(16) float smem[6656];
  int tid = threadIdx.x;
  int w = tid >> 6, lane = tid & 63;
  int quad = lane >> 4, lm = lane & 15;
  if (blockIdx.x < 1024) {
    __bf16* Bh = (__bf16*)smem;
    __bf16* Bl = (__bf16*)(smem + 2304);
    float* sqs = smem + 4608;
    int b = blockIdx.x >> 5, qc = blockIdx.x & 31;
    int q0 = qc * 64;
    size_t bb = (size_t)b * 2048;
    for (int u = tid; u < 512; u += 256)
      *(float4*)(sqs + u * 4) = *(const float4*)(sq + bb + u * 4);
    const __bf16* qh = xh + (bb + q0 + w * 16 + lm) * 64 + quad * 8;
    const __bf16* ql = xl + (bb + q0 + w * 16 + lm) * 64 + quad * 8;
    bf16x8 Ah0 = *(const bf16x8*)(qh);
    bf16x8 Ah1 = *(const bf16x8*)(qh + 32);
    bf16x8 Al0 = *(const bf16x8*)(ql);
    bf16x8 Al1 = *(const bf16x8*)(ql + 32);
    __syncthreads();
    float qsq[4];
#pragma unroll
    for (int r = 0; r < 4; ++r) qsq[r] = sqs[q0 + w * 16 + quad * 4 + r];
    float bd[4][5];
    int bi[4][5];
#pragma unroll
    for (int r = 0; r < 4; ++r)
#pragma unroll
      for (int k = 0; k < 5; ++k) { bd[r][k] = 1e30f; bi[r][k] = 0; }
    for (int ct = 0; ct < 32; ++ct) {
#pragma unroll
      for (int pass = 0; pass < 2; ++pass) {
        int unit = pass * 256 + tid;
        int n = unit >> 3, cc = unit & 7;
        const __bf16* gsrc = xh + (bb + ct * 64 + n) * 64 + cc * 8;
        const __bf16* gsrl = xl + (bb + ct * 64 + n) * 64 + cc * 8;
        *(uint4*)(Bh + n * 72 + cc * 8) = *(const uint4*)gsrc;
        *(uint4*)(Bl + n * 72 + cc * 8) = *(const uint4*)gsrl;
      }
      __syncthreads();
#pragma unroll
      for (int nt = 0; nt < 4; ++nt) {
        const __bf16* bph = Bh + (nt * 16 + lm) * 72 + quad * 8;
        const __bf16* bpl = Bl + (nt * 16 + lm) * 72 + quad * 8;
        bf16x8 Bh0 = *(const bf16x8*)(bph);
        bf16x8 Bh1 = *(const bf16x8*)(bph + 32);
        bf16x8 Bl0 = *(const bf16x8*)(bpl);
        bf16x8 Bl1 = *(const bf16x8*)(bpl + 32);
        f32x4 acc = {0.f, 0.f, 0.f, 0.f};
        acc = __builtin_amdgcn_mfma_f32_16x16x32_bf16(Ah0, Bh0, acc, 0, 0, 0);
        acc = __builtin_amdgcn_mfma_f32_16x16x32_bf16(Ah1, Bh1, acc, 0, 0, 0);
        acc = __builtin_amdgcn_mfma_f32_16x16x32_bf16(Ah0, Bl0, acc, 0, 0, 0);
        acc = __builtin_amdgcn_mfma_f32_16x16x32_bf16(Ah1, Bl1, acc, 0, 0, 0);
        acc = __builtin_amdgcn_mfma_f32_16x16x32_bf16(Al0, Bh0, acc, 0, 0, 0);
        acc = __builtin_amdgcn_mfma_f32_16x16x32_bf16(Al1, Bh1, acc, 0, 0, 0);
        int cid = ct * 64 + nt * 16 + lm;
        float csq = sqs[cid];
#pragma unroll
        for (int r = 0; r < 4; ++r) {
          float d = (qsq[r] + csq) - 2.0f * acc[r];
          knn_insert(bd[r], bi[r], d, cid);
        }
      }
      __syncthreads();
    }
    for (int m = 1; m <= 8; m <<= 1) {
#pragma unroll
      for (int r = 0; r < 4; ++r) {
        float od[5]; int oi[5];
#pragma unroll
        for (int k = 0; k < 5; ++k) {
          od[k] = __shfl_xor(bd[r][k], m);
          oi[k] = __shfl_xor(bi[r][k], m);
        }
#pragma unroll
        for (int k = 0; k < 5; ++k) knn_insert(bd[r], bi[r], od[k], oi[k]);
      }
    }
    if (lm == 0) {
#pragma unroll
      for (int r = 0; r < 4; ++r) {
        int qi = q0 + w * 16 + quad * 4 + r;
        int* op = idx2 + (bb + qi) * 5;
#pragma unroll
        for (int k = 0; k < 5; ++k) op[k] = bi[r][k];
      }
    }
  } else {
    __bf16* Wh = (__bf16*)smem;
    __bf16* Wl = (__bf16*)(smem + 2048);
    int n0 = (blockIdx.x - 1024) * 64;
    const __bf16* ah = xh + (size_t)(n0 + w * 16 + lm) * 64 + quad * 8;
    const __bf16* al = xl + (size_t)(n0 + w * 16 + lm) * 64 + quad * 8;
    bf16x8 Ah0 = *(const bf16x8*)(ah);
    bf16x8 Ah1 = *(const bf16x8*)(ah + 32);
    bf16x8 Al0 = *(const bf16x8*)(al);
    bf16x8 Al1 = *(const bf16x8*)(al + 32);
    for (int chunk = 0; chunk < 4; ++chunk) {
      __syncthreads();
#pragma unroll
      for (int it = 0; it < 2; ++it) {
        int unit = it * 256 + tid;
        *(uint4*)(Wh + (size_t)unit * 8) =
            *(const uint4*)(wph + (size_t)chunk * 4096 + (size_t)unit * 8);
        *(uint4*)(Wl + (size_t)unit * 8) =
            *(const uint4*)(wpl + (size_t)chunk * 4096 + (size_t)unit * 8);
      }
      __syncthreads();
#pragma unroll
      for (int nb4 = 0; nb4 < 4; ++nb4) {
        int nb = chunk * 4 + nb4;
        bf16x8 Bh0 = *(const bf16x8*)(Wh + ((size_t)(nb4 * 2 + 0) * 64 + lane) * 8);
        bf16x8 Bh1 = *(const bf16x8*)(Wh + ((size_t)(nb4 * 2 + 1) * 64 + lane) * 8);
        bf16x8 Bl0 = *(const bf16x8*)(Wl + ((size_t)(nb4 * 2 + 0) * 64 + lane) * 8);
        bf16x8 Bl1 = *(const bf16x8*)(Wl + ((size_t)(nb4 * 2 + 1) * 64 + lane) * 8);
        f32x4 acc = {0.f, 0.f, 0.f, 0.f};
        acc = __builtin_amdgcn_mfma_f32_16x16x32_bf16(Ah0, Bh0, acc, 0, 0, 0);
        acc = __builtin_amdgcn_mfma_f32_16x16x32_bf16(Ah1, Bh1, acc, 0, 0, 0);
        acc = __builtin_amdgcn_mfma_f32_16x16x32_bf16(Ah0, Bl0, acc, 0, 0, 0);
        acc = __builtin_amdgcn_mfma_f32_16x16x32_bf16(Ah1, Bl1, acc, 0, 0, 0);
        acc = __builtin_amdgcn_mfma_f32_16x16x32_bf16(Al0, Bh0, acc, 0, 0, 0);
        acc = __builtin_amdgcn_mfma_f32_16x16x32_bf16(Al1, Bh1, acc, 0, 0, 0);
        bool isP = (nb < 8);
        __bf16* base = isP ? Pb : Qb;
        int col = (isP ? nb : nb - 8) * 16 + lm;
#pragma unroll
        for (int r = 0; r < 4; ++r) {
          int n = n0 + w * 16 + quad * 4 + r;
          base[(size_t)n * 128 + col] = (__bf16)acc[r];
        }
      }
    }
  }
}

// ---------------- Kernel 4b: gather-max + activation, 4 channels/lane ----------------
// grid 8192 (8 points/block); per-channel math order identical (bit-exact)
__global__ __launch_bounds__(256) void k_gmax(const __bf16* __restrict__ Pb,
                                              const __bf16* __restrict__ Qb,
                                              const int* __restrict__ idx2,
                                              const float* __restrict__ b2,
                                              const float* __restrict__ s2,
                                              const float* __restrict__ h2v,
                                              __bf16* __restrict__ xb) {
  int tid = threadIdx.x;
  int c4 = tid & 31, p = tid >> 5;  // 32 lanes/point, 8 points/block
  int n = blockIdx.x * 8 + p;
  int b = n >> 11;
  const int* ip = idx2 + n * 5;
  int c0 = c4 * 4;
  float m[4] = {-3.4e38f, -3.4e38f, -3.4e38f, -3.4e38f};
#pragma unroll
  for (int k = 0; k < 5; ++k) {
    int j = ip[k];
    uint2 q = *(const uint2*)(Qb + ((size_t)(b * 2048 + j)) * 128 + c0);
    m[0] = fmaxf(m[0], (float)bffrom((unsigned short)(q.x & 0xFFFFu)));
    m[1] = fmaxf(m[1], (float)bffrom((unsigned short)(q.x >> 16)));
    m[2] = fmaxf(m[2], (float)bffrom((unsigned short)(q.y & 0xFFFFu)));
    m[3] = fmaxf(m[3], (float)bffrom((unsigned short)(q.y >> 16)));
  }
  uint2 pv = *(const uint2*)(Pb + (size_t)n * 128 + c0);
  float pvf[4] = {(float)bffrom((unsigned short)(pv.x & 0xFFFFu)),
                  (float)bffrom((unsigned short)(pv.x >> 16)),
                  (float)bffrom((unsigned short)(pv.y & 0xFFFFu)),
                  (float)bffrom((unsigned short)(pv.y >> 16))};
  __bf16 o[4];
#pragma unroll
  for (int i = 0; i < 4; ++i) {
    float v = pvf[i] + m[i] + b2[c0 + i];
    o[i] = (__bf16)(relu_(v) * s2[c0 + i] + h2v[c0 + i]);
  }
  uint2 ov;
  ov.x = (unsigned)bfbits(o[0]) | ((unsigned)bfbits(o[1]) << 16);
  ov.y = (unsigned)bfbits(o[2]) | ((unsigned)bfbits(o[3]) << 16);
  *(uint2*)(xb + (size_t)n * 192 + 64 + c0) = ov;
}

// ---------------- Kernel 5: bf16 MFMA GEMM fused point-max, A staged once, ng loop ----------------
// grid 1024 (mg); LDS: Aall 24KB + B chunk 16KB = 40KB -> 4 blocks/CU (= grid/256CU)
__global__ __launch_bounds__(256) void k_linl_mfma(const __bf16* __restrict__ xb,
                                                   const __bf16* __restrict__ wlb,
                                                   float* __restrict__ pool_part) {
  __shared__ __align__(16) __bf16 Aall[12288];  // [mb4][ks6][lane64][8]
  __shared__ __align__(16) __bf16 Bl[8192];     // [nt2][nb8][lane64][8]
  int tid = threadIdx.x;
  int w = tid >> 6, lane = tid & 63;
  int mg = blockIdx.x;
  int n0 = mg << 6;
  int quad = lane >> 4, lm = lane & 15;
  // stage ALL of this mg's A-tile once (1536 uint4)
#pragma unroll
  for (int it = 0; it < 6; ++it) {
    int unit = it * 256 + tid;           // 0..1535
    int mb = unit / 384;
    int rem = unit - mb * 384;
    int ks = rem >> 6, ln = rem & 63;
    int lmm = ln & 15, qd = ln >> 4;
    const uint4* ga = (const uint4*)(xb + (size_t)(n0 + mb * 16 + lmm) * 192 + ks * 32 + qd * 8);
    *(uint4*)(Aall + ((size_t)(mb * 6 + ks) * 64 + ln) * 8) = *ga;
  }
  for (int ng = 0; ng < 4; ++ng) {
    f32x4 acc[4][4];
#pragma unroll
    for (int i = 0; i < 4; ++i)
#pragma unroll
      for (int j = 0; j < 4; ++j) acc[i][j] = (f32x4){0.f, 0.f, 0.f, 0.f};
    for (int ks = 0; ks < 6; ++ks) {
      __syncthreads();  // protect prev B reads (and covers initial A staging)
#pragma unroll
      for (int nt2 = 0; nt2 < 2; ++nt2) {
#pragma unroll
        for (int u = 0; u < 2; ++u) {
          int unit = u * 256 + tid;
          const uint4* gb = (const uint4*)(wlb + ((size_t)((ng * 2 + nt2) * 6 + ks)) * 4096 + (size_t)unit * 8);
          *(uint4*)(Bl + (size_t)nt2 * 4096 + (size_t)unit * 8) = *gb;
        }
      }
      __syncthreads();
      bf16x8 af[4], bfr[4];
#pragma unroll
      for (int i = 0; i < 4; ++i)
        af[i] = *(const bf16x8*)(Aall + ((size_t)(i * 6 + ks) * 64 + lane) * 8);
      int nt2 = w >> 1, nbb = (w & 1) * 4;
#pragma unroll
      for (int j = 0; j < 4; ++j)
        bfr[j] = *(const bf16x8*)(Bl + (size_t)nt2 * 4096 + ((size_t)((nbb + j) * 64 + lane)) * 8);
#pragma unroll
      for (int i = 0; i < 4; ++i)
#pragma unroll
        for (int j = 0; j < 4; ++j)
          acc[i][j] = __builtin_amdgcn_mfma_f32_16x16x32_bf16(af[i], bfr[j], acc[i][j], 0, 0, 0);
    }
#pragma unroll
    for (int j = 0; j < 4; ++j) {
      float m = -3.4e38f;
#pragma unroll
      for (int i = 0; i < 4; ++i)
#pragma unroll
        for (int r = 0; r < 4; ++r) m = fmaxf(m, acc[i][j][r]);
      m = fmaxf(m, __shfl_xor(m, 16));
      m = fmaxf(m, __shfl_xor(m, 32));
      if (quad == 0) {
        int ch = ng * 256 + (w >> 1) * 128 + (w & 1) * 64 + j * 16 + lm;
        pool_part[(size_t)mg * 1024 + ch] = m;
      }
    }
  }
}

// ---------------- Kernel 6: head MLP (32-way pool merge) ----------------
__global__ __launch_bounds__(256) void k_head(
    const float* __restrict__ pool_part, const float* __restrict__ bl,
    const float* __restrict__ sl, const float* __restrict__ hl,
    const float* __restrict__ wm1, const float* __restrict__ bm1,
    const float* __restrict__ sm1, const float* __restrict__ hm1,
    const float* __restrict__ wm2, const float* __restrict__ bm2,
    const float* __restrict__ sm2, const float* __restrict__ hm2,
    const float* __restrict__ wout, const float* __restrict__ bout,
    float* __restrict__ out) {
  __shared__ float p_s[1024], h1_s[512], h2_s[256];
  int b = blockIdx.x, tid = threadIdx.x;
  for (int c = tid; c < 1024; c += 256) {
    float m = -3.4e38f;
#pragma unroll 4
    for (int t = 0; t < 32; ++t)
      m = fmaxf(m, pool_part[(size_t)(b * 32 + t) * 1024 + c]);
    p_s[c] = relu_(m + bl[c]) * sl[c] + hl[c];
  }
  __syncthreads();
  for (int c = tid; c < 512; c += 256) {
    float a0 = 0, a1 = 0, a2 = 0, a3 = 0;
    for (int f = 0; f < 1024; f += 4) {
      a0 = fmaf(p_s[f], wm1[f * 512 + c], a0);
      a1 = fmaf(p_s[f + 1], wm1[(f + 1) * 512 + c], a1);
      a2 = fmaf(p_s[f + 2], wm1[(f + 2) * 512 + c], a2);
      a3 = fmaf(p_s[f + 3], wm1[(f + 3) * 512 + c], a3);
    }
    float a = (a0 + a1) + (a2 + a3);
    h1_s[c] = relu_(a + bm1[c]) * sm1[c] + hm1[c];
  }
  __syncthreads();
  if (tid < 256) {
    float a0 = 0, a1 = 0, a2 = 0, a3 = 0;
    for (int f = 0; f < 512; f += 4) {
      a0 = fmaf(h1_s[f], wm2[f * 256 + tid], a0);
      a1 = fmaf(h1_s[f + 1], wm2[(f + 1) * 256 + tid], a1);
      a2 = fmaf(h1_s[f + 2], wm2[(f + 2) * 256 + tid], a2);
      a3 = fmaf(h1_s[f + 3], wm2[(f + 3) * 256 + tid], a3);
    }
    float a = (a0 + a1) + (a2 + a3);
    h2_s[tid] = relu_(a + bm2[tid]) * sm2[tid] + hm2[tid];
  }
  __syncthreads();
  if (tid < 2) {
    float a0 = 0, a1 = 0;
    for (int f = 0; f < 256; f += 2) {
      a0 = fmaf(h2_s[f], wout[f * 2 + tid], a0);
      a1 = fmaf(h2_s[f + 1], wout[(f + 1) * 2 + tid], a1);
    }
    out[b * 2 + tid] = (a0 + a1) + bout[tid];
  }
}

extern "C" void kernel_launch(void* const* d_in, const int* in_sizes, int n_in,
                              void* d_out, int out_size, void* d_ws, size_t ws_size,
                              hipStream_t stream) {
  const float* pos = (const float*)d_in[0];
  const float* w1a = (const float*)d_in[1];
  const float* b1a = (const float*)d_in[2];
  const float* s1a = (const float*)d_in[3];
  const float* h1a = (const float*)d_in[4];
  const float* w1b = (const float*)d_in[5];
  const float* b1b = (const float*)d_in[6];
  const float* s1b = (const float*)d_in[7];
  const float* h1b = (const float*)d_in[8];
  const float* w1c = (const float*)d_in[9];
  const float* b1c = (const float*)d_in[10];
  const float* s1c = (const float*)d_in[11];
  const float* h1c = (const float*)d_in[12];
  const float* w2 = (const float*)d_in[13];
  const float* b2 = (const float*)d_in[14];
  const float* s2 = (const float*)d_in[15];
  const float* h2 = (const float*)d_in[16];
  const float* wl = (const float*)d_in[17];
  const float* bl = (const float*)d_in[18];
  const float* sl = (const float*)d_in[19];
  const float* hl = (const float*)d_in[20];
  const float* wm1 = (const float*)d_in[21];
  const float* bm1 = (const float*)d_in[22];
  const float* sm1 = (const float*)d_in[23];
  const float* hm1 = (const float*)d_in[24];
  const float* wm2 = (const float*)d_in[25];
  const float* bm2 = (const float*)d_in[26];
  const float* sm2 = (const float*)d_in[27];
  const float* hm2 = (const float*)d_in[28];
  const float* wout = (const float*)d_in[29];
  const float* bout = (const float*)d_in[30];
  float* out = (float*)d_out;

  // workspace: xh | xl | Pb | Qb | xb | idx | sq | wph/wpl/wfh/wfl | wlb (~77.6 MB)
  float* base = (float*)d_ws;
  __bf16* xh = (__bf16*)base;
  __bf16* xl = (__bf16*)(base + 2097152);
  float* PbF = base + 4194304;
  float* QbF = PbF + 4194304;
  float* xbF = QbF + 4194304;
  int* idx = (int*)(xbF + 6291456);
  float* sq = (float*)(idx + 327680);
  __bf16* wph = (__bf16*)(sq + 65536);
  __bf16* wpl = (__bf16*)(sq + 65536 + 8192);
  __bf16* wfh = (__bf16*)(sq + 65536 + 16384);
  __bf16* wfl = (__bf16*)(sq + 65536 + 20480);
  __bf16* wlb = (__bf16*)(sq + 65536 + 24576);
  __bf16* Pb = (__bf16*)PbF;
  __bf16* Qb = (__bf16*)QbF;
  __bf16* xb = (__bf16*)xbF;
  float* uR = PbF;                                // alias (dead until k_mid's pq)
  float* vR = QbF;
  float* pool_part = base + 131072;               // overlaps xl/Pb head: dead by linl

  k_front<<<3180, 256, 0, stream>>>(pos, w1a, b1a, w1b, w1c, w2, wl, idx, uR, vR,
                                    wfh, wfl, wph, wpl, wlb);
  k_edge1<<<1024, 256, 0, stream>>>(idx, uR, vR, s1a, h1a, b1b, s1b, h1b, b1c,
                                    s1c, h1c, wfh, wfl, xh, xl, sq, xb);
  k_mid<<<2048, 256, 0, stream>>>(xh, xl, sq, idx, wph, wpl, Pb, Qb);
  k_gmax<<<8192, 256, 0, stream>>>(Pb, Qb, idx, b2, s2, h2, xb);
  k_linl_mfma<<<1024, 256, 0, stream>>>(xb, wlb, pool_part);
  k_head<<<32, 256, 0, stream>>>(pool_part, bl, sl, hl, wm1, bm1, sm1, hm1, wm2,
                                 bm2, sm2, hm2, wout, bout, out);
}